// Round 7
// baseline (373.638 us; speedup 1.0000x reference)
//
#include <hip/hip_runtime.h>
#include <math.h>

// Problem constants: B=1, T=384, C=512, H=8, D=64, E=16. Inputs/outputs f32.
// R18: proj GEMM fused into attn dispatch via LAST-CONTRIBUTOR counters
// (deadlock-free: no spin-waits, no co-residency assumption). Tests the
// ~10us/dispatch-boundary theory. attn core = R6-verified 2-row pairing.
#define TT 384
#define CC 512
#define HH 8
#define EE 16

typedef __bf16 bf16_t;
typedef __bf16 bf16x8 __attribute__((ext_vector_type(8)));
typedef __bf16 bf16x4v __attribute__((ext_vector_type(4)));
typedef float f32x4 __attribute__((ext_vector_type(4)));

__device__ __forceinline__ float wave_reduce_sum(float v) {
#pragma unroll
  for (int off = 32; off >= 1; off >>= 1) v += __shfl_xor(v, off, 64);
  return v;
}

// ---------------------------------------------------------------------------
// wrow_unit: one LN-folded weight row: W'[n]=g∘W[n] (bf16), s1[n]=Σ W'[n,k],
// c[n] = Σ b_k W[n,k] + extra
// ---------------------------------------------------------------------------
__device__ __forceinline__ void wrow_unit(const float* __restrict__ wr,
                                          const float* __restrict__ g,
                                          const float* __restrict__ bb,
                                          float extra_c, bf16_t* __restrict__ orow,
                                          float* __restrict__ s1p,
                                          float* __restrict__ cp, int lane) {
  const float* p = wr + lane * 8;
  f32x4 w0 = *(const f32x4*)p, w1 = *(const f32x4*)(p + 4);
  f32x4 g0 = *(const f32x4*)(g + lane * 8), g1 = *(const f32x4*)(g + lane * 8 + 4);
  f32x4 b0 = *(const f32x4*)(bb + lane * 8), b1 = *(const f32x4*)(bb + lane * 8 + 4);
  f32x4 p0 = w0 * g0, p1 = w1 * g1;
  bf16x8 o;
  o[0] = (bf16_t)p0.x; o[1] = (bf16_t)p0.y; o[2] = (bf16_t)p0.z; o[3] = (bf16_t)p0.w;
  o[4] = (bf16_t)p1.x; o[5] = (bf16_t)p1.y; o[6] = (bf16_t)p1.z; o[7] = (bf16_t)p1.w;
  *(bf16x8*)(orow + lane * 8) = o;
  float s1 = p0.x + p0.y + p0.z + p0.w + p1.x + p1.y + p1.z + p1.w;
  float c = w0.x * b0.x + w0.y * b0.y + w0.z * b0.z + w0.w * b0.w +
            w1.x * b1.x + w1.y * b1.y + w1.z * b1.z + w1.w * b1.w;
  s1 = wave_reduce_sum(s1);
  c = wave_reduce_sum(c);
  if (lane == 0) { *s1p = s1; *cp = c + extra_c; }
}

// ---------------------------------------------------------------------------
// Prep bundle (hidden in qkv dispatch rows by>=12; 1089 units):
// 0-255 edge tables; 256-767 wfc rows; 768-1023 wcproj conv; 1024-1087
// wproj conv; 1088 zero x1 stat accumulators + proj-tile counters.
// ---------------------------------------------------------------------------
struct PrepX {
  const float *eemb, *wekw, *wekb, *wevw, *wevb;
  const float *ln2w, *ln2b, *cfcw, *cfcb;
  const float *wproj, *wcproj;
  float *ektab, *evtab, *s1f, *cf, *x1s1, *x1s2;
  bf16_t *wfc_bf, *wproj_bf, *wcproj_bf;
  int *cnt;
};

__device__ void prep_unit(int u, const PrepX& X, int tid) {
  int lane = tid & 63, wave = tid >> 6;
  if (u < 256) {
    int wid = u * 4 + wave;
    int gbase = wid * 16;
    int table = gbase >> 13;
    int e = (gbase >> 9) & 15;
    int c0 = gbase & 511;
    const float* er = X.eemb + e * 512 + lane * 8;
    f32x4 ea = *(const f32x4*)er;
    f32x4 eb = *(const f32x4*)(er + 4);
    const float* wbase = table ? X.wevw : X.wekw;
    const float* bbase = table ? X.wevb : X.wekb;
    float* obase = (table ? X.evtab : X.ektab) + e * 512;
#pragma unroll
    for (int o = 0; o < 16; o++) {
      int c = c0 + o;
      const float* wr = wbase + (size_t)c * 512 + lane * 8;
      f32x4 wa = *(const f32x4*)wr;
      f32x4 wb = *(const f32x4*)(wr + 4);
      float acc = ea.x * wa.x + ea.y * wa.y + ea.z * wa.z + ea.w * wa.w +
                  eb.x * wb.x + eb.y * wb.y + eb.z * wb.z + eb.w * wb.w;
      acc = wave_reduce_sum(acc);
      if (lane == 0) obase[c] = acc + bbase[c];
    }
  } else if (u < 768) {
    int n = (u - 256) * 4 + wave;  // 0..2047
    wrow_unit(X.cfcw + (size_t)n * 512, X.ln2w, X.ln2b, X.cfcb[n],
              X.wfc_bf + (size_t)n * 512, X.s1f + n, X.cf + n, lane);
  } else if (u < 1024) {
    int base = (u - 768) * 1024;  // wcproj: 262144 f32x4
    for (int t = tid; t < 1024; t += 256) {
      f32x4 a = *((const f32x4*)X.wcproj + base + t);
      bf16x4v o;
      o[0] = (bf16_t)a.x; o[1] = (bf16_t)a.y; o[2] = (bf16_t)a.z; o[3] = (bf16_t)a.w;
      *((bf16x4v*)X.wcproj_bf + base + t) = o;
    }
  } else if (u < 1088) {
    int base = (u - 1024) * 1024;  // wproj: 65536 f32x4
    for (int t = tid; t < 1024; t += 256) {
      f32x4 a = *((const f32x4*)X.wproj + base + t);
      bf16x4v o;
      o[0] = (bf16_t)a.x; o[1] = (bf16_t)a.y; o[2] = (bf16_t)a.z; o[3] = (bf16_t)a.w;
      *((bf16x4v*)X.wproj_bf + base + t) = o;
    }
  } else if (u == 1088) {
    for (int i = tid; i < 384; i += 256) { X.x1s1[i] = 0.f; X.x1s2[i] = 0.f; }
    if (tid < 12) X.cnt[tid] = 0;
  }
}

// ---------------------------------------------------------------------------
// qkv_k: SELF-CONTAINED qkv GEMM — no pre-pass dependency. Each 32x32 tile:
//  - loads raw f32 x and wattn, folds g∘W inline into the B fragment
//  - accumulates per-wave partials of row Σx/Σx² and col Σ(gW)/Σ(bW)
//    alongside the MFMA loop (operands already in registers)
//  - quad-shuffle + LDS reduce, epilogue applies rs·(acc−mu·s1)+c+bias.
// by>=12 rows run prep units (tables, wfc, wproj/wcproj, stat zeroing).
// ---------------------------------------------------------------------------
__global__ __launch_bounds__(256) void qkv_k(
    const float* __restrict__ x, const float* __restrict__ wattn,
    const float* __restrict__ ln1w, const float* __restrict__ ln1b,
    const float* __restrict__ wattnb, bf16_t* __restrict__ out, PrepX X) {
  int tid = threadIdx.x;
  if (blockIdx.y >= 12) {
    prep_unit((blockIdx.y - 12) * gridDim.x + blockIdx.x, X, tid);
    return;
  }
  __shared__ float part[4][32][32];  // 16 KB
  __shared__ float rst[2][4][32];    // [sx|sxx][wave][row]  1 KB
  __shared__ float wst[2][4][32];    // [s1|c ][wave][col]  1 KB
  int lane = tid & 63, wave = tid >> 6;
  int m0 = blockIdx.y * 32, n0 = blockIdx.x * 32;
  int r16 = lane & 15, quad = lane >> 4;
  int k0 = wave * 128;  // K=512, kchunk=128

  f32x4 acc[2][2];
  f32x4 zero = {0.f, 0.f, 0.f, 0.f};
#pragma unroll
  for (int i = 0; i < 2; i++)
#pragma unroll
    for (int j = 0; j < 2; j++) acc[i][j] = zero;

  const float* Af = x + (size_t)(m0 + r16) * 512 + k0 + quad * 8;
  const float* Wf = wattn + (size_t)(n0 + r16) * 512 + k0 + quad * 8;
  const float* gp = ln1w + k0 + quad * 8;
  const float* bp = ln1b + k0 + quad * 8;

  float sx[2] = {0.f, 0.f}, sxx[2] = {0.f, 0.f};
  float s1[2] = {0.f, 0.f}, cc[2] = {0.f, 0.f};

  for (int kb0 = 0; kb0 < 128; kb0 += 64) {  // 2 k-steps hoisted
    uint4 araw[2][2][2], wraw[2][2][2];
#pragma unroll
    for (int u = 0; u < 2; u++) {
      int kb = kb0 + u * 32;
#pragma unroll
      for (int t = 0; t < 2; t++) {
        araw[u][t][0] = *(const uint4*)(Af + (size_t)t * 16 * 512 + kb);
        araw[u][t][1] = *(const uint4*)(Af + (size_t)t * 16 * 512 + kb + 4);
        wraw[u][t][0] = *(const uint4*)(Wf + (size_t)t * 16 * 512 + kb);
        wraw[u][t][1] = *(const uint4*)(Wf + (size_t)t * 16 * 512 + kb + 4);
      }
    }
#pragma unroll
    for (int u = 0; u < 2; u++) {
      int kb = kb0 + u * 32;
      f32x4 g0 = *(const f32x4*)(gp + kb), g1 = *(const f32x4*)(gp + kb + 4);
      f32x4 b0 = *(const f32x4*)(bp + kb), b1 = *(const f32x4*)(bp + kb + 4);
      bf16x8 af[2], bfr[2];
#pragma unroll
      for (int t = 0; t < 2; t++) {
        f32x4 a0 = *reinterpret_cast<const f32x4*>(&araw[u][t][0]);
        f32x4 a1 = *reinterpret_cast<const f32x4*>(&araw[u][t][1]);
        af[t][0] = (bf16_t)a0.x; af[t][1] = (bf16_t)a0.y;
        af[t][2] = (bf16_t)a0.z; af[t][3] = (bf16_t)a0.w;
        af[t][4] = (bf16_t)a1.x; af[t][5] = (bf16_t)a1.y;
        af[t][6] = (bf16_t)a1.z; af[t][7] = (bf16_t)a1.w;
        sx[t] += a0.x + a0.y + a0.z + a0.w + a1.x + a1.y + a1.z + a1.w;
        sxx[t] += a0.x * a0.x + a0.y * a0.y + a0.z * a0.z + a0.w * a0.w +
                  a1.x * a1.x + a1.y * a1.y + a1.z * a1.z + a1.w * a1.w;
        f32x4 w0 = *reinterpret_cast<const f32x4*>(&wraw[u][t][0]);
        f32x4 w1 = *reinterpret_cast<const f32x4*>(&wraw[u][t][1]);
        f32x4 p0 = w0 * g0, p1 = w1 * g1;
        bfr[t][0] = (bf16_t)p0.x; bfr[t][1] = (bf16_t)p0.y;
        bfr[t][2] = (bf16_t)p0.z; bfr[t][3] = (bf16_t)p0.w;
        bfr[t][4] = (bf16_t)p1.x; bfr[t][5] = (bf16_t)p1.y;
        bfr[t][6] = (bf16_t)p1.z; bfr[t][7] = (bf16_t)p1.w;
        s1[t] += p0.x + p0.y + p0.z + p0.w + p1.x + p1.y + p1.z + p1.w;
        cc[t] += w0.x * b0.x + w0.y * b0.y + w0.z * b0.z + w0.w * b0.w +
                 w1.x * b1.x + w1.y * b1.y + w1.z * b1.z + w1.w * b1.w;
      }
#pragma unroll
      for (int i = 0; i < 2; i++)
#pragma unroll
        for (int j = 0; j < 2; j++)
          acc[i][j] = __builtin_amdgcn_mfma_f32_16x16x32_bf16(af[i], bfr[j],
                                                              acc[i][j], 0, 0, 0);
    }
  }

  // quad-reduce stats (lanes r16, r16+16, r16+32, r16+48 → same value)
#pragma unroll
  for (int t = 0; t < 2; t++) {
    sx[t] += __shfl_xor(sx[t], 16, 64);  sx[t] += __shfl_xor(sx[t], 32, 64);
    sxx[t] += __shfl_xor(sxx[t], 16, 64); sxx[t] += __shfl_xor(sxx[t], 32, 64);
    s1[t] += __shfl_xor(s1[t], 16, 64);  s1[t] += __shfl_xor(s1[t], 32, 64);
    cc[t] += __shfl_xor(cc[t], 16, 64);  cc[t] += __shfl_xor(cc[t], 32, 64);
  }
  if (quad == 0) {
#pragma unroll
    for (int t = 0; t < 2; t++) {
      rst[0][wave][t * 16 + r16] = sx[t];
      rst[1][wave][t * 16 + r16] = sxx[t];
      wst[0][wave][t * 16 + r16] = s1[t];
      wst[1][wave][t * 16 + r16] = cc[t];
    }
  }
#pragma unroll
  for (int i = 0; i < 2; i++)
#pragma unroll
    for (int j = 0; j < 2; j++)
#pragma unroll
      for (int r = 0; r < 4; r++)
        part[wave][i * 16 + quad * 4 + r][j * 16 + r16] = acc[i][j][r];
  __syncthreads();

  int row = tid >> 3, c4 = (tid & 7) * 4;
  f32x4 v = *(const f32x4*)&part[0][row][c4];
  v += *(const f32x4*)&part[1][row][c4];
  v += *(const f32x4*)&part[2][row][c4];
  v += *(const f32x4*)&part[3][row][c4];
  float sxt = rst[0][0][row] + rst[0][1][row] + rst[0][2][row] + rst[0][3][row];
  float sxxt = rst[1][0][row] + rst[1][1][row] + rst[1][2][row] + rst[1][3][row];
  float mu = sxt * (1.0f / 512.0f);
  float var = sxxt * (1.0f / 512.0f) - mu * mu;
  float rs = rsqrtf(var + 1e-5f);
  int grow = m0 + row, gcol = n0 + c4;
  bf16x4v o;
#pragma unroll
  for (int t = 0; t < 4; t++) {
    int cl = c4 + t;
    float s1v = wst[0][0][cl] + wst[0][1][cl] + wst[0][2][cl] + wst[0][3][cl];
    float ccv = wst[1][0][cl] + wst[1][1][cl] + wst[1][2][cl] + wst[1][3][cl] +
                wattnb[n0 + cl];
    o[t] = (bf16_t)(rs * (v[t] - mu * s1v) + ccv);
  }
  *(bf16x4v*)(out + (size_t)grow * 1536 + gcol) = o;
}

// ---------------------------------------------------------------------------
// Split-K NT GEMM, 32x32 tile (R10 measured-best). 4 waves each K/4;
// K-loop hoists 4 k-steps of loads before MFMA.
// MODE 2 (FC):   A=x1 f32, row stats from S1/S2; fused-LN; gelu ->bf16
// MODE 3 (CPROJ):A bf16, +bias +res ->f32 (d_out)
// (MODE 1 proj now lives inside attn_k as the last-contributor executor.)
// ---------------------------------------------------------------------------
template <int MODE>
__global__ __launch_bounds__(256) void gemm_k(
    const void* __restrict__ Aptr, const bf16_t* __restrict__ Wb,
    const float* __restrict__ e0, const float* __restrict__ e1,
    const float* __restrict__ e2, const float* __restrict__ e3,
    const float* __restrict__ res, void* __restrict__ out,
    float* __restrict__ st1, float* __restrict__ st2, int N, int K) {
  constexpr bool AF32 = (MODE == 2);
  constexpr int AW = AF32 ? 2 : 1;
  __shared__ float part[4][32][32];
  int tid = threadIdx.x;
  int lane = tid & 63, wave = tid >> 6;
  int m0 = blockIdx.y * 32, n0 = blockIdx.x * 32;
  int r16 = lane & 15, quad = lane >> 4;
  int kchunk = K >> 2, k0 = wave * kchunk;

  f32x4 acc[2][2];
  f32x4 zero = {0.f, 0.f, 0.f, 0.f};
#pragma unroll
  for (int i = 0; i < 2; i++)
#pragma unroll
    for (int j = 0; j < 2; j++) acc[i][j] = zero;

  const float* Af = (const float*)Aptr + (size_t)(m0 + r16) * K + k0 + quad * 8;
  const bf16_t* Ab = (const bf16_t*)Aptr + (size_t)(m0 + r16) * K + k0 + quad * 8;
  const bf16_t* Wp = Wb + (size_t)(n0 + r16) * K + k0 + quad * 8;

  for (int kb0 = 0; kb0 < kchunk; kb0 += 128) {
    uint4 araw[4][2][AW];
    uint4 braw[4][2];
#pragma unroll
    for (int u = 0; u < 4; u++) {
      int kb = kb0 + u * 32;
#pragma unroll
      for (int t = 0; t < 2; t++) {
        if (AF32) {
          araw[u][t][0] = *(const uint4*)(Af + (size_t)t * 16 * K + kb);
          araw[u][t][1] = *(const uint4*)(Af + (size_t)t * 16 * K + kb + 4);
        } else {
          araw[u][t][0] = *(const uint4*)(Ab + (size_t)t * 16 * K + kb);
        }
        braw[u][t] = *(const uint4*)(Wp + (size_t)t * 16 * K + kb);
      }
    }
#pragma unroll
    for (int u = 0; u < 4; u++) {
      bf16x8 af[2], bfr[2];
#pragma unroll
      for (int t = 0; t < 2; t++) {
        if (AF32) {
          f32x4 a = *reinterpret_cast<const f32x4*>(&araw[u][t][0]);
          f32x4 c = *reinterpret_cast<const f32x4*>(&araw[u][t][1]);
          af[t][0] = (bf16_t)a.x; af[t][1] = (bf16_t)a.y;
          af[t][2] = (bf16_t)a.z; af[t][3] = (bf16_t)a.w;
          af[t][4] = (bf16_t)c.x; af[t][5] = (bf16_t)c.y;
          af[t][6] = (bf16_t)c.z; af[t][7] = (bf16_t)c.w;
        } else {
          af[t] = *reinterpret_cast<const bf16x8*>(&araw[u][t][0]);
        }
        bfr[t] = *reinterpret_cast<const bf16x8*>(&braw[u][t]);
      }
#pragma unroll
      for (int i = 0; i < 2; i++)
#pragma unroll
        for (int j = 0; j < 2; j++)
          acc[i][j] = __builtin_amdgcn_mfma_f32_16x16x32_bf16(af[i], bfr[j],
                                                              acc[i][j], 0, 0, 0);
    }
  }

#pragma unroll
  for (int i = 0; i < 2; i++)
#pragma unroll
    for (int j = 0; j < 2; j++)
#pragma unroll
      for (int r = 0; r < 4; r++)
        part[wave][i * 16 + quad * 4 + r][j * 16 + r16] = acc[i][j][r];
  __syncthreads();

  int row = tid >> 3, c4 = (tid & 7) * 4;
  f32x4 v = *(const f32x4*)&part[0][row][c4];
  v += *(const f32x4*)&part[1][row][c4];
  v += *(const f32x4*)&part[2][row][c4];
  v += *(const f32x4*)&part[3][row][c4];
  int grow = m0 + row, gcol = n0 + c4;

  if (MODE == 2) {
    float S = e0[grow], Q = e1[grow];
    float mu = S * (1.0f / 512.0f);
    float var = Q * (1.0f / 512.0f) - mu * mu;
    float rs = rsqrtf(var + 1e-5f);
    f32x4 s1v = *(const f32x4*)(e2 + gcol);
    f32x4 ccv = *(const f32x4*)(e3 + gcol);
    bf16x4v o;
#pragma unroll
    for (int t = 0; t < 4; t++) {
      float xg = rs * (v[t] - mu * s1v[t]) + ccv[t];
      xg = 0.5f * xg * (1.0f + erff(xg * 0.70710678118654752f));
      o[t] = (bf16_t)xg;
    }
    *(bf16x4v*)((bf16_t*)out + (size_t)grow * N + gcol) = o;
  } else {
    v += *(const f32x4*)(e2 + gcol);  // bias
    v += *(const f32x4*)(res + (size_t)grow * N + gcol);
    *(f32x4*)((float*)out + (size_t)grow * N + gcol) = v;
  }
}

// ---------------------------------------------------------------------------
// Attention R18 = R14 verified core (paired rows b / 383-b, grid 192x8)
// + fused proj executor. After a block's ybuf rows are written it does a
// device-scope release-increment on its two row-tile counters; the block
// observing prev==255 (all 256 contributions done: 32 row-pairs x 8 heads)
// has acquire ordering over every producer's writes and computes that
// 32-row proj tile: x1 = x + ybuf@wproj^T + b (+ row stats), identical
// split-K MFMA math to the old gemm_k<1>. part[] LDS aliases the dead attn
// arrays via a union, so occupancy is unchanged. No spin-waits anywhere.
// ---------------------------------------------------------------------------
__global__ __launch_bounds__(256) void attn_k(
    const bf16_t* __restrict__ qkv, const int* __restrict__ bias_matrix,
    const float* __restrict__ attn_bias_emb, const float* __restrict__ ek_tab,
    const float* __restrict__ ev_tab, bf16_t* __restrict__ ybuf,
    const bf16_t* __restrict__ wproj_bf, const float* __restrict__ wprojb,
    const float* __restrict__ x, float* __restrict__ x1,
    float* __restrict__ x1s1, float* __restrict__ x1s2,
    int* __restrict__ cnt) {
  __shared__ union {
    struct {
      uint2 ps1[TT], ps2[TT];      // {e, bits(p)} per j, per row
      float qe1[EE][68], qe2[EE][68];
      float evh[EE * 64];
    } a;
    float part[4][32][32];         // proj executor scratch (aliases a)
  } U;
  __shared__ float red[2][4 * 64];
  __shared__ float absh[EE];
  __shared__ float scr[2][4];
  __shared__ int exec_t[2];

  uint2* ps1 = U.a.ps1;
  uint2* ps2 = U.a.ps2;
  float(*qe1)[68] = U.a.qe1;
  float(*qe2)[68] = U.a.qe2;
  float* evh = U.a.evh;

  int b = blockIdx.x, h = blockIdx.y;
  int i1 = b, i2 = (TT - 1) - b;  // i1 < i2, n1 <= n2
  int n1 = i1 + 1, n2 = i2 + 1;
  int tid = threadIdx.x, lane = tid & 63, wave = tid >> 6;

  if (tid < EE) absh[tid] = attn_bias_emb[tid * HH + h];
  for (int idx = tid; idx < EE * 64; idx += 256) {
    int e = idx >> 6, d = idx & 63;
    float q1 = (float)qkv[(size_t)i1 * 1536 + h * 64 + d];
    float q2 = (float)qkv[(size_t)i2 * 1536 + h * 64 + d];
    float ek = ek_tab[e * 512 + h * 64 + d];
    qe1[e][d] = q1 * ek;
    qe2[e][d] = q2 * ek;
    evh[idx] = ev_tab[e * 512 + h * 64 + d];
  }
  __syncthreads();

  float ls1 = 0.0f, ls2 = 0.0f;
  const int* bm1 = bias_matrix + (size_t)i1 * TT;
  const int* bm2 = bias_matrix + (size_t)i2 * TT;
  for (int jl = tid; jl < n2; jl += 256) {
    int e2 = bm2[jl];
    const uint4* kp = (const uint4*)(qkv + (size_t)jl * 1536 + 512 + h * 64);
    uint4 kr[8];
#pragma unroll
    for (int dg = 0; dg < 8; dg++) kr[dg] = kp[dg];
    float a2 = 0.f;
#pragma unroll
    for (int dg = 0; dg < 8; dg++) {
      bf16x8 kv = *reinterpret_cast<const bf16x8*>(&kr[dg]);
      f32x4 qa = *(const f32x4*)&qe2[e2][dg * 8];
      f32x4 qb = *(const f32x4*)&qe2[e2][dg * 8 + 4];
      a2 += (float)kv[0] * qa.x + (float)kv[1] * qa.y + (float)kv[2] * qa.z +
            (float)kv[3] * qa.w + (float)kv[4] * qb.x + (float)kv[5] * qb.y +
            (float)kv[6] * qb.z + (float)kv[7] * qb.w;
    }
    float p2 = __expf(a2 * 0.125f + absh[e2]);
    uint2 pk2; pk2.x = (unsigned)e2; pk2.y = __float_as_uint(p2);
    ps2[jl] = pk2;
    ls2 += p2;
    if (jl < n1) {
      int e1 = bm1[jl];
      float a1 = 0.f;
#pragma unroll
      for (int dg = 0; dg < 8; dg++) {
        bf16x8 kv = *reinterpret_cast<const bf16x8*>(&kr[dg]);
        f32x4 qa = *(const f32x4*)&qe1[e1][dg * 8];
        f32x4 qb = *(const f32x4*)&qe1[e1][dg * 8 + 4];
        a1 += (float)kv[0] * qa.x + (float)kv[1] * qa.y + (float)kv[2] * qa.z +
              (float)kv[3] * qa.w + (float)kv[4] * qb.x + (float)kv[5] * qb.y +
              (float)kv[6] * qb.z + (float)kv[7] * qb.w;
      }
      float p1 = __expf(a1 * 0.125f + absh[e1]);
      uint2 pk1; pk1.x = (unsigned)e1; pk1.y = __float_as_uint(p1);
      ps1[jl] = pk1;
      ls1 += p1;
    }
  }
  ls1 = wave_reduce_sum(ls1);
  ls2 = wave_reduce_sum(ls2);
  if (lane == 0) { scr[0][wave] = ls1; scr[1][wave] = ls2; }
  __syncthreads();
  float inv1 = 1.0f / (scr[0][0] + scr[0][1] + scr[0][2] + scr[0][3]);
  float inv2 = 1.0f / (scr[1][0] + scr[1][1] + scr[1][2] + scr[1][3]);

  const bf16_t* vb = qkv + 1024 + h * 64 + lane;  // lane's d column of v rows
  float acc1 = 0.0f, acc2 = 0.0f;
  int j = wave;
  // shared region: both rows, 4-wide (v loads amortized 2x)
  for (; j + 12 < n1; j += 16) {
    float v0 = (float)vb[(size_t)j * 1536];
    float v1 = (float)vb[(size_t)(j + 4) * 1536];
    float v2 = (float)vb[(size_t)(j + 8) * 1536];
    float v3 = (float)vb[(size_t)(j + 12) * 1536];
    uint2 c0 = ps2[j], c1 = ps2[j + 4], c2 = ps2[j + 8], c3 = ps2[j + 12];
    uint2 d0 = ps1[j], d1 = ps1[j + 4], d2 = ps1[j + 8], d3 = ps1[j + 12];
    acc2 = fmaf(__uint_as_float(c0.y) * v0, evh[c0.x * 64 + lane], acc2);
    acc2 = fmaf(__uint_as_float(c1.y) * v1, evh[c1.x * 64 + lane], acc2);
    acc2 = fmaf(__uint_as_float(c2.y) * v2, evh[c2.x * 64 + lane], acc2);
    acc2 = fmaf(__uint_as_float(c3.y) * v3, evh[c3.x * 64 + lane], acc2);
    acc1 = fmaf(__uint_as_float(d0.y) * v0, evh[d0.x * 64 + lane], acc1);
    acc1 = fmaf(__uint_as_float(d1.y) * v1, evh[d1.x * 64 + lane], acc1);
    acc1 = fmaf(__uint_as_float(d2.y) * v2, evh[d2.x * 64 + lane], acc1);
    acc1 = fmaf(__uint_as_float(d3.y) * v3, evh[d3.x * 64 + lane], acc1);
  }
  for (; j < n1; j += 4) {
    float v0 = (float)vb[(size_t)j * 1536];
    uint2 c0 = ps2[j], d0 = ps1[j];
    acc2 = fmaf(__uint_as_float(c0.y) * v0, evh[c0.x * 64 + lane], acc2);
    acc1 = fmaf(__uint_as_float(d0.y) * v0, evh[d0.x * 64 + lane], acc1);
  }
  // tail region: row 2 only, 4-wide
  for (; j + 12 < n2; j += 16) {
    float v0 = (float)vb[(size_t)j * 1536];
    float v1 = (float)vb[(size_t)(j + 4) * 1536];
    float v2 = (float)vb[(size_t)(j + 8) * 1536];
    float v3 = (float)vb[(size_t)(j + 12) * 1536];
    uint2 c0 = ps2[j], c1 = ps2[j + 4], c2 = ps2[j + 8], c3 = ps2[j + 12];
    acc2 = fmaf(__uint_as_float(c0.y) * v0, evh[c0.x * 64 + lane], acc2);
    acc2 = fmaf(__uint_as_float(c1.y) * v1, evh[c1.x * 64 + lane], acc2);
    acc2 = fmaf(__uint_as_float(c2.y) * v2, evh[c2.x * 64 + lane], acc2);
    acc2 = fmaf(__uint_as_float(c3.y) * v3, evh[c3.x * 64 + lane], acc2);
  }
  for (; j < n2; j += 4) {
    float v0 = (float)vb[(size_t)j * 1536];
    uint2 c0 = ps2[j];
    acc2 = fmaf(__uint_as_float(c0.y) * v0, evh[c0.x * 64 + lane], acc2);
  }
  red[0][wave * 64 + lane] = acc1;
  red[1][wave * 64 + lane] = acc2;
  __syncthreads();
  if (tid < 64) {
    float y =
        (red[0][tid] + red[0][64 + tid] + red[0][128 + tid] + red[0][192 + tid]) *
        inv1;
    ybuf[(size_t)i1 * CC + h * 64 + tid] = (bf16_t)y;
  } else if (tid < 128) {
    int t = tid - 64;
    float y =
        (red[1][t] + red[1][64 + t] + red[1][128 + t] + red[1][192 + t]) * inv2;
    ybuf[(size_t)i2 * CC + h * 64 + t] = (bf16_t)y;
  }

  // ----- last-contributor proj: device-scope release increments; the block
  // seeing prev==255 acquires all producers' ybuf writes and runs the tile.
  __threadfence();
  __syncthreads();
  if (tid == 0) {
    int t1 = i1 >> 5, t2 = i2 >> 5;  // t1 in 0..5, t2 in 6..11 (disjoint)
    int p1 = __hip_atomic_fetch_add(cnt + t1, 1, __ATOMIC_ACQ_REL,
                                    __HIP_MEMORY_SCOPE_AGENT);
    int p2 = __hip_atomic_fetch_add(cnt + t2, 1, __ATOMIC_ACQ_REL,
                                    __HIP_MEMORY_SCOPE_AGENT);
    exec_t[0] = (p1 == 255) ? t1 : -1;
    exec_t[1] = (p2 == 255) ? t2 : -1;
  }
  __syncthreads();

#pragma unroll 1
  for (int s = 0; s < 2; s++) {
    int tt = exec_t[s];
    if (tt < 0) continue;
    int m0 = tt * 32;
    int r16 = lane & 15, quad = lane >> 4;
    int k0 = wave * 128;
    // A fragments for this wave's K-chunk, loaded ONCE (reused for all 16
    // col-tiles): rows (m0+r16, m0+r16+16), 4 k-steps of 8 bf16.
    uint4 areg[4][2];
    const bf16_t* Ab = ybuf + (size_t)(m0 + r16) * 512 + k0 + quad * 8;
#pragma unroll
    for (int u = 0; u < 4; u++)
#pragma unroll
      for (int t = 0; t < 2; t++)
        areg[u][t] = *(const uint4*)(Ab + (size_t)t * 16 * 512 + u * 32);
#pragma unroll 1
    for (int bx = 0; bx < 16; bx++) {
      int n0 = bx * 32;
      const bf16_t* Wp = wproj_bf + (size_t)(n0 + r16) * 512 + k0 + quad * 8;
      uint4 braw[4][2];
#pragma unroll
      for (int u = 0; u < 4; u++)
#pragma unroll
        for (int t = 0; t < 2; t++)
          braw[u][t] = *(const uint4*)(Wp + (size_t)t * 16 * 512 + u * 32);
      f32x4 acc[2][2];
      f32x4 zero = {0.f, 0.f, 0.f, 0.f};
#pragma unroll
      for (int i = 0; i < 2; i++)
#pragma unroll
        for (int jj = 0; jj < 2; jj++) acc[i][jj] = zero;
#pragma unroll
      for (int u = 0; u < 4; u++) {
        bf16x8 af[2], bfr[2];
#pragma unroll
        for (int t = 0; t < 2; t++) {
          af[t] = *reinterpret_cast<const bf16x8*>(&areg[u][t]);
          bfr[t] = *reinterpret_cast<const bf16x8*>(&braw[u][t]);
        }
#pragma unroll
        for (int i = 0; i < 2; i++)
#pragma unroll
          for (int jj = 0; jj < 2; jj++)
            acc[i][jj] = __builtin_amdgcn_mfma_f32_16x16x32_bf16(
                af[i], bfr[jj], acc[i][jj], 0, 0, 0);
      }
#pragma unroll
      for (int i = 0; i < 2; i++)
#pragma unroll
        for (int jj = 0; jj < 2; jj++)
#pragma unroll
          for (int r = 0; r < 4; r++)
            U.part[wave][i * 16 + quad * 4 + r][jj * 16 + r16] = acc[i][jj][r];
      __syncthreads();
      {
        int row = tid >> 3, c4 = (tid & 7) * 4;
        f32x4 v = *(const f32x4*)&U.part[0][row][c4];
        v += *(const f32x4*)&U.part[1][row][c4];
        v += *(const f32x4*)&U.part[2][row][c4];
        v += *(const f32x4*)&U.part[3][row][c4];
        int grow = m0 + row, gcol = n0 + c4;
        v += *(const f32x4*)(wprojb + gcol);
        v += *(const f32x4*)(x + (size_t)grow * 512 + gcol);
        *(f32x4*)(x1 + (size_t)grow * 512 + gcol) = v;
        float sv = v.x + v.y + v.z + v.w;
        float qv = v.x * v.x + v.y * v.y + v.z * v.z + v.w * v.w;
        sv += __shfl_down(sv, 4, 8); qv += __shfl_down(qv, 4, 8);
        sv += __shfl_down(sv, 2, 8); qv += __shfl_down(qv, 2, 8);
        sv += __shfl_down(sv, 1, 8); qv += __shfl_down(qv, 1, 8);
        if ((tid & 7) == 0) {
          atomicAdd(x1s1 + grow, sv);
          atomicAdd(x1s2 + grow, qv);
        }
      }
      __syncthreads();  // before next bx overwrites part
    }
  }
}

// ---------------------------------------------------------------------------
extern "C" void kernel_launch(void* const* d_in, const int* in_sizes, int n_in,
                              void* d_out, int out_size, void* d_ws,
                              size_t ws_size, hipStream_t stream) {
  const float* x = (const float*)d_in[0];
  const int* bias_mat = (const int*)d_in[1];

  char* wp = (char*)d_ws;
  float* ektab = (float*)wp;  wp += 16 * 512 * 4;
  float* evtab = (float*)wp;  wp += 16 * 512 * 4;
  float* x1s1 = (float*)wp;   wp += 384 * 4;
  float* x1s2 = (float*)wp;   wp += 384 * 4;
  float* s1f = (float*)wp;    wp += 2048 * 4;
  float* cf = (float*)wp;     wp += 2048 * 4;
  float* x1 = (float*)wp;     wp += 384 * 512 * 4;
  bf16_t* wfc_bf = (bf16_t*)wp;    wp += 2048 * 512 * 2;
  bf16_t* wproj_bf = (bf16_t*)wp;  wp += 512 * 512 * 2;
  bf16_t* wcproj_bf = (bf16_t*)wp; wp += 512 * 2048 * 2;
  bf16_t* qkv = (bf16_t*)wp;  wp += 384 * 1536 * 2;
  bf16_t* ybuf = (bf16_t*)wp; wp += 384 * 512 * 2;
  bf16_t* gbuf = (bf16_t*)wp; wp += 384 * 2048 * 2;
  int* cnt = (int*)wp;        wp += 16 * 4;

  PrepX X;
  X.eemb = (const float*)d_in[9];
  X.wekw = (const float*)d_in[10];
  X.wekb = (const float*)d_in[11];
  X.wevw = (const float*)d_in[12];
  X.wevb = (const float*)d_in[13];
  X.ln2w = (const float*)d_in[14];
  X.ln2b = (const float*)d_in[15];
  X.cfcw = (const float*)d_in[16];
  X.cfcb = (const float*)d_in[17];
  X.wproj = (const float*)d_in[6];
  X.wcproj = (const float*)d_in[18];
  X.ektab = ektab; X.evtab = evtab; X.s1f = s1f; X.cf = cf;
  X.x1s1 = x1s1; X.x1s2 = x1s2;
  X.wfc_bf = wfc_bf; X.wproj_bf = wproj_bf; X.wcproj_bf = wcproj_bf;
  X.cnt = cnt;

  // 1) self-contained qkv (576 gemm tiles, rows 0-11) + 1089 hidden prep
  //    units (rows 12-34): edge tables, wfc rows, wproj/wcproj, zeroing
  qkv_k<<<dim3(48, 35), 256, 0, stream>>>(
      x, (const float*)d_in[4], (const float*)d_in[2], (const float*)d_in[3],
      (const float*)d_in[5], qkv, X);
  // 2) attention (paired rows, 192x8) + fused last-contributor proj:
  //    x1 = x + y@wproj^T + b, row stats — no separate proj dispatch
  attn_k<<<dim3(TT / 2, HH), 256, 0, stream>>>(
      qkv, bias_mat, (const float*)d_in[8], ektab, evtab, ybuf, wproj_bf,
      (const float*)d_in[7], x, x1, x1s1, x1s2, cnt);
  // 3) g = gelu(LN2(x1) @ cfc^T + b)
  gemm_k<2><<<dim3(64, 12), 256, 0, stream>>>(x1, wfc_bf, x1s1, x1s2, s1f, cf,
                                              nullptr, gbuf, nullptr, nullptr,
                                              2048, 512);
  // 4) out = x1 + g @ cproj^T + b
  gemm_k<3><<<dim3(16, 12), 256, 0, stream>>>(
      gbuf, wcproj_bf, nullptr, nullptr, (const float*)d_in[19], nullptr, x1,
      d_out, nullptr, nullptr, 512, 2048);
}

// Round 8
// 185.973 us; speedup vs baseline: 2.0091x; 2.0091x over previous
//
#include <hip/hip_runtime.h>
#include <math.h>

// Problem constants: B=1, T=384, C=512, H=8, D=64, E=16. Inputs/outputs f32.
// R19 = R6-verified base + (a) 4-row balanced attn (R16, audited: no sync,
// bounded loops — retried on healthy infra after R7 showed R5's failure
// signature matches a wedged container) + (b) x1 LN-stats folded into
// gemm<2>'s own A-fragment reads (drops gemm<1> atomics + stat buffers).
// R7 lesson: NO in-kernel cross-block sync — device-scope ordered atomics
// cost ~70ns each serialized (+206us measured). 5 dispatches stay.
#define TT 384
#define CC 512
#define HH 8
#define EE 16

typedef __bf16 bf16_t;
typedef __bf16 bf16x8 __attribute__((ext_vector_type(8)));
typedef __bf16 bf16x4v __attribute__((ext_vector_type(4)));
typedef float f32x4 __attribute__((ext_vector_type(4)));

__device__ __forceinline__ float wave_reduce_sum(float v) {
#pragma unroll
  for (int off = 32; off >= 1; off >>= 1) v += __shfl_xor(v, off, 64);
  return v;
}

// ---------------------------------------------------------------------------
// wrow_unit: one LN-folded weight row: W'[n]=g∘W[n] (bf16), s1[n]=Σ W'[n,k],
// c[n] = Σ b_k W[n,k] + extra
// ---------------------------------------------------------------------------
__device__ __forceinline__ void wrow_unit(const float* __restrict__ wr,
                                          const float* __restrict__ g,
                                          const float* __restrict__ bb,
                                          float extra_c, bf16_t* __restrict__ orow,
                                          float* __restrict__ s1p,
                                          float* __restrict__ cp, int lane) {
  const float* p = wr + lane * 8;
  f32x4 w0 = *(const f32x4*)p, w1 = *(const f32x4*)(p + 4);
  f32x4 g0 = *(const f32x4*)(g + lane * 8), g1 = *(const f32x4*)(g + lane * 8 + 4);
  f32x4 b0 = *(const f32x4*)(bb + lane * 8), b1 = *(const f32x4*)(bb + lane * 8 + 4);
  f32x4 p0 = w0 * g0, p1 = w1 * g1;
  bf16x8 o;
  o[0] = (bf16_t)p0.x; o[1] = (bf16_t)p0.y; o[2] = (bf16_t)p0.z; o[3] = (bf16_t)p0.w;
  o[4] = (bf16_t)p1.x; o[5] = (bf16_t)p1.y; o[6] = (bf16_t)p1.z; o[7] = (bf16_t)p1.w;
  *(bf16x8*)(orow + lane * 8) = o;
  float s1 = p0.x + p0.y + p0.z + p0.w + p1.x + p1.y + p1.z + p1.w;
  float c = w0.x * b0.x + w0.y * b0.y + w0.z * b0.z + w0.w * b0.w +
            w1.x * b1.x + w1.y * b1.y + w1.z * b1.z + w1.w * b1.w;
  s1 = wave_reduce_sum(s1);
  c = wave_reduce_sum(c);
  if (lane == 0) { *s1p = s1; *cp = c + extra_c; }
}

// ---------------------------------------------------------------------------
// Prep bundle (hidden in qkv dispatch rows by>=12; 1088 units):
// 0-255 edge tables; 256-767 wfc rows; 768-1023 wcproj conv; 1024-1087
// wproj conv. (x1-stat zeroing dropped: stats now live in gemm<2>.)
// ---------------------------------------------------------------------------
struct PrepX {
  const float *eemb, *wekw, *wekb, *wevw, *wevb;
  const float *ln2w, *ln2b, *cfcw, *cfcb;
  const float *wproj, *wcproj;
  float *ektab, *evtab, *s1f, *cf;
  bf16_t *wfc_bf, *wproj_bf, *wcproj_bf;
};

__device__ void prep_unit(int u, const PrepX& X, int tid) {
  int lane = tid & 63, wave = tid >> 6;
  if (u < 256) {
    int wid = u * 4 + wave;
    int gbase = wid * 16;
    int table = gbase >> 13;
    int e = (gbase >> 9) & 15;
    int c0 = gbase & 511;
    const float* er = X.eemb + e * 512 + lane * 8;
    f32x4 ea = *(const f32x4*)er;
    f32x4 eb = *(const f32x4*)(er + 4);
    const float* wbase = table ? X.wevw : X.wekw;
    const float* bbase = table ? X.wevb : X.wekb;
    float* obase = (table ? X.evtab : X.ektab) + e * 512;
#pragma unroll
    for (int o = 0; o < 16; o++) {
      int c = c0 + o;
      const float* wr = wbase + (size_t)c * 512 + lane * 8;
      f32x4 wa = *(const f32x4*)wr;
      f32x4 wb = *(const f32x4*)(wr + 4);
      float acc = ea.x * wa.x + ea.y * wa.y + ea.z * wa.z + ea.w * wa.w +
                  eb.x * wb.x + eb.y * wb.y + eb.z * wb.z + eb.w * wb.w;
      acc = wave_reduce_sum(acc);
      if (lane == 0) obase[c] = acc + bbase[c];
    }
  } else if (u < 768) {
    int n = (u - 256) * 4 + wave;  // 0..2047
    wrow_unit(X.cfcw + (size_t)n * 512, X.ln2w, X.ln2b, X.cfcb[n],
              X.wfc_bf + (size_t)n * 512, X.s1f + n, X.cf + n, lane);
  } else if (u < 1024) {
    int base = (u - 768) * 1024;  // wcproj: 262144 f32x4
    for (int t = tid; t < 1024; t += 256) {
      f32x4 a = *((const f32x4*)X.wcproj + base + t);
      bf16x4v o;
      o[0] = (bf16_t)a.x; o[1] = (bf16_t)a.y; o[2] = (bf16_t)a.z; o[3] = (bf16_t)a.w;
      *((bf16x4v*)X.wcproj_bf + base + t) = o;
    }
  } else if (u < 1088) {
    int base = (u - 1024) * 1024;  // wproj: 65536 f32x4
    for (int t = tid; t < 1024; t += 256) {
      f32x4 a = *((const f32x4*)X.wproj + base + t);
      bf16x4v o;
      o[0] = (bf16_t)a.x; o[1] = (bf16_t)a.y; o[2] = (bf16_t)a.z; o[3] = (bf16_t)a.w;
      *((bf16x4v*)X.wproj_bf + base + t) = o;
    }
  }
}

// ---------------------------------------------------------------------------
// qkv_k: SELF-CONTAINED qkv GEMM — no pre-pass dependency. Each 32x32 tile:
//  - loads raw f32 x and wattn, folds g∘W inline into the B fragment
//  - accumulates per-wave partials of row Σx/Σx² and col Σ(gW)/Σ(bW)
//    alongside the MFMA loop (operands already in registers)
//  - quad-shuffle + LDS reduce, epilogue applies rs·(acc−mu·s1)+c+bias.
// by>=12 rows run prep units (tables, wfc, wproj/wcproj).
// ---------------------------------------------------------------------------
__global__ __launch_bounds__(256) void qkv_k(
    const float* __restrict__ x, const float* __restrict__ wattn,
    const float* __restrict__ ln1w, const float* __restrict__ ln1b,
    const float* __restrict__ wattnb, bf16_t* __restrict__ out, PrepX X) {
  int tid = threadIdx.x;
  if (blockIdx.y >= 12) {
    prep_unit((blockIdx.y - 12) * gridDim.x + blockIdx.x, X, tid);
    return;
  }
  __shared__ float part[4][32][32];  // 16 KB
  __shared__ float rst[2][4][32];    // [sx|sxx][wave][row]  1 KB
  __shared__ float wst[2][4][32];    // [s1|c ][wave][col]  1 KB
  int lane = tid & 63, wave = tid >> 6;
  int m0 = blockIdx.y * 32, n0 = blockIdx.x * 32;
  int r16 = lane & 15, quad = lane >> 4;
  int k0 = wave * 128;  // K=512, kchunk=128

  f32x4 acc[2][2];
  f32x4 zero = {0.f, 0.f, 0.f, 0.f};
#pragma unroll
  for (int i = 0; i < 2; i++)
#pragma unroll
    for (int j = 0; j < 2; j++) acc[i][j] = zero;

  const float* Af = x + (size_t)(m0 + r16) * 512 + k0 + quad * 8;
  const float* Wf = wattn + (size_t)(n0 + r16) * 512 + k0 + quad * 8;
  const float* gp = ln1w + k0 + quad * 8;
  const float* bp = ln1b + k0 + quad * 8;

  float sx[2] = {0.f, 0.f}, sxx[2] = {0.f, 0.f};
  float s1[2] = {0.f, 0.f}, cc[2] = {0.f, 0.f};

  for (int kb0 = 0; kb0 < 128; kb0 += 64) {  // 2 k-steps hoisted
    uint4 araw[2][2][2], wraw[2][2][2];
#pragma unroll
    for (int u = 0; u < 2; u++) {
      int kb = kb0 + u * 32;
#pragma unroll
      for (int t = 0; t < 2; t++) {
        araw[u][t][0] = *(const uint4*)(Af + (size_t)t * 16 * 512 + kb);
        araw[u][t][1] = *(const uint4*)(Af + (size_t)t * 16 * 512 + kb + 4);
        wraw[u][t][0] = *(const uint4*)(Wf + (size_t)t * 16 * 512 + kb);
        wraw[u][t][1] = *(const uint4*)(Wf + (size_t)t * 16 * 512 + kb + 4);
      }
    }
#pragma unroll
    for (int u = 0; u < 2; u++) {
      int kb = kb0 + u * 32;
      f32x4 g0 = *(const f32x4*)(gp + kb), g1 = *(const f32x4*)(gp + kb + 4);
      f32x4 b0 = *(const f32x4*)(bp + kb), b1 = *(const f32x4*)(bp + kb + 4);
      bf16x8 af[2], bfr[2];
#pragma unroll
      for (int t = 0; t < 2; t++) {
        f32x4 a0 = *reinterpret_cast<const f32x4*>(&araw[u][t][0]);
        f32x4 a1 = *reinterpret_cast<const f32x4*>(&araw[u][t][1]);
        af[t][0] = (bf16_t)a0.x; af[t][1] = (bf16_t)a0.y;
        af[t][2] = (bf16_t)a0.z; af[t][3] = (bf16_t)a0.w;
        af[t][4] = (bf16_t)a1.x; af[t][5] = (bf16_t)a1.y;
        af[t][6] = (bf16_t)a1.z; af[t][7] = (bf16_t)a1.w;
        sx[t] += a0.x + a0.y + a0.z + a0.w + a1.x + a1.y + a1.z + a1.w;
        sxx[t] += a0.x * a0.x + a0.y * a0.y + a0.z * a0.z + a0.w * a0.w +
                  a1.x * a1.x + a1.y * a1.y + a1.z * a1.z + a1.w * a1.w;
        f32x4 w0 = *reinterpret_cast<const f32x4*>(&wraw[u][t][0]);
        f32x4 w1 = *reinterpret_cast<const f32x4*>(&wraw[u][t][1]);
        f32x4 p0 = w0 * g0, p1 = w1 * g1;
        bfr[t][0] = (bf16_t)p0.x; bfr[t][1] = (bf16_t)p0.y;
        bfr[t][2] = (bf16_t)p0.z; bfr[t][3] = (bf16_t)p0.w;
        bfr[t][4] = (bf16_t)p1.x; bfr[t][5] = (bf16_t)p1.y;
        bfr[t][6] = (bf16_t)p1.z; bfr[t][7] = (bf16_t)p1.w;
        s1[t] += p0.x + p0.y + p0.z + p0.w + p1.x + p1.y + p1.z + p1.w;
        cc[t] += w0.x * b0.x + w0.y * b0.y + w0.z * b0.z + w0.w * b0.w +
                 w1.x * b1.x + w1.y * b1.y + w1.z * b1.z + w1.w * b1.w;
      }
#pragma unroll
      for (int i = 0; i < 2; i++)
#pragma unroll
        for (int j = 0; j < 2; j++)
          acc[i][j] = __builtin_amdgcn_mfma_f32_16x16x32_bf16(af[i], bfr[j],
                                                              acc[i][j], 0, 0, 0);
    }
  }

  // quad-reduce stats (lanes r16, r16+16, r16+32, r16+48 → same value)
#pragma unroll
  for (int t = 0; t < 2; t++) {
    sx[t] += __shfl_xor(sx[t], 16, 64);  sx[t] += __shfl_xor(sx[t], 32, 64);
    sxx[t] += __shfl_xor(sxx[t], 16, 64); sxx[t] += __shfl_xor(sxx[t], 32, 64);
    s1[t] += __shfl_xor(s1[t], 16, 64);  s1[t] += __shfl_xor(s1[t], 32, 64);
    cc[t] += __shfl_xor(cc[t], 16, 64);  cc[t] += __shfl_xor(cc[t], 32, 64);
  }
  if (quad == 0) {
#pragma unroll
    for (int t = 0; t < 2; t++) {
      rst[0][wave][t * 16 + r16] = sx[t];
      rst[1][wave][t * 16 + r16] = sxx[t];
      wst[0][wave][t * 16 + r16] = s1[t];
      wst[1][wave][t * 16 + r16] = cc[t];
    }
  }
#pragma unroll
  for (int i = 0; i < 2; i++)
#pragma unroll
    for (int j = 0; j < 2; j++)
#pragma unroll
      for (int r = 0; r < 4; r++)
        part[wave][i * 16 + quad * 4 + r][j * 16 + r16] = acc[i][j][r];
  __syncthreads();

  int row = tid >> 3, c4 = (tid & 7) * 4;
  f32x4 v = *(const f32x4*)&part[0][row][c4];
  v += *(const f32x4*)&part[1][row][c4];
  v += *(const f32x4*)&part[2][row][c4];
  v += *(const f32x4*)&part[3][row][c4];
  float sxt = rst[0][0][row] + rst[0][1][row] + rst[0][2][row] + rst[0][3][row];
  float sxxt = rst[1][0][row] + rst[1][1][row] + rst[1][2][row] + rst[1][3][row];
  float mu = sxt * (1.0f / 512.0f);
  float var = sxxt * (1.0f / 512.0f) - mu * mu;
  float rs = rsqrtf(var + 1e-5f);
  int grow = m0 + row, gcol = n0 + c4;
  bf16x4v o;
#pragma unroll
  for (int t = 0; t < 4; t++) {
    int cl = c4 + t;
    float s1v = wst[0][0][cl] + wst[0][1][cl] + wst[0][2][cl] + wst[0][3][cl];
    float ccv = wst[1][0][cl] + wst[1][1][cl] + wst[1][2][cl] + wst[1][3][cl] +
                wattnb[n0 + cl];
    o[t] = (bf16_t)(rs * (v[t] - mu * s1v) + ccv);
  }
  *(bf16x4v*)(out + (size_t)grow * 1536 + gcol) = o;
}

// ---------------------------------------------------------------------------
// Split-K NT GEMM, 32x32 tile (R10 measured-best). 4 waves each K/4;
// K-loop hoists 4 k-steps of loads before MFMA.
// MODE 1 (PROJ): A bf16, +bias +res ->f32  (stat atomics REMOVED — R19)
// MODE 2 (FC):   A=x1 f32; row stats computed FROM OWN A-FRAGMENTS (R19,
//                qkv_k pattern: per-wave partials + quad shuffle + LDS);
//                fused-LN; gelu ->bf16
// MODE 3 (CPROJ):A bf16, +bias +res ->f32 (d_out)
// ---------------------------------------------------------------------------
template <int MODE>
__global__ __launch_bounds__(256) void gemm_k(
    const void* __restrict__ Aptr, const bf16_t* __restrict__ Wb,
    const float* __restrict__ e2, const float* __restrict__ e3,
    const float* __restrict__ res, void* __restrict__ out, int N, int K) {
  constexpr bool AF32 = (MODE == 2);
  constexpr int AW = AF32 ? 2 : 1;
  __shared__ float part[4][32][32];
  __shared__ float rst[2][4][32];  // MODE 2 row stats (1 KB, else unused)
  int tid = threadIdx.x;
  int lane = tid & 63, wave = tid >> 6;
  int m0 = blockIdx.y * 32, n0 = blockIdx.x * 32;
  int r16 = lane & 15, quad = lane >> 4;
  int kchunk = K >> 2, k0 = wave * kchunk;

  f32x4 acc[2][2];
  f32x4 zero = {0.f, 0.f, 0.f, 0.f};
#pragma unroll
  for (int i = 0; i < 2; i++)
#pragma unroll
    for (int j = 0; j < 2; j++) acc[i][j] = zero;

  const float* Af = (const float*)Aptr + (size_t)(m0 + r16) * K + k0 + quad * 8;
  const bf16_t* Ab = (const bf16_t*)Aptr + (size_t)(m0 + r16) * K + k0 + quad * 8;
  const bf16_t* Wp = Wb + (size_t)(n0 + r16) * K + k0 + quad * 8;

  float sx[2] = {0.f, 0.f}, sxx[2] = {0.f, 0.f};

  for (int kb0 = 0; kb0 < kchunk; kb0 += 128) {
    uint4 araw[4][2][AW];
    uint4 braw[4][2];
#pragma unroll
    for (int u = 0; u < 4; u++) {
      int kb = kb0 + u * 32;
#pragma unroll
      for (int t = 0; t < 2; t++) {
        if (AF32) {
          araw[u][t][0] = *(const uint4*)(Af + (size_t)t * 16 * K + kb);
          araw[u][t][1] = *(const uint4*)(Af + (size_t)t * 16 * K + kb + 4);
        } else {
          araw[u][t][0] = *(const uint4*)(Ab + (size_t)t * 16 * K + kb);
        }
        braw[u][t] = *(const uint4*)(Wp + (size_t)t * 16 * K + kb);
      }
    }
#pragma unroll
    for (int u = 0; u < 4; u++) {
      bf16x8 af[2], bfr[2];
#pragma unroll
      for (int t = 0; t < 2; t++) {
        if (AF32) {
          f32x4 a = *reinterpret_cast<const f32x4*>(&araw[u][t][0]);
          f32x4 c = *reinterpret_cast<const f32x4*>(&araw[u][t][1]);
          af[t][0] = (bf16_t)a.x; af[t][1] = (bf16_t)a.y;
          af[t][2] = (bf16_t)a.z; af[t][3] = (bf16_t)a.w;
          af[t][4] = (bf16_t)c.x; af[t][5] = (bf16_t)c.y;
          af[t][6] = (bf16_t)c.z; af[t][7] = (bf16_t)c.w;
          sx[t] += a.x + a.y + a.z + a.w + c.x + c.y + c.z + c.w;
          sxx[t] += a.x * a.x + a.y * a.y + a.z * a.z + a.w * a.w +
                    c.x * c.x + c.y * c.y + c.z * c.z + c.w * c.w;
        } else {
          af[t] = *reinterpret_cast<const bf16x8*>(&araw[u][t][0]);
        }
        bfr[t] = *reinterpret_cast<const bf16x8*>(&braw[u][t]);
      }
#pragma unroll
      for (int i = 0; i < 2; i++)
#pragma unroll
        for (int j = 0; j < 2; j++)
          acc[i][j] = __builtin_amdgcn_mfma_f32_16x16x32_bf16(af[i], bfr[j],
                                                              acc[i][j], 0, 0, 0);
    }
  }

  if (MODE == 2) {  // quad-reduce row stats, store per-wave partials
#pragma unroll
    for (int t = 0; t < 2; t++) {
      sx[t] += __shfl_xor(sx[t], 16, 64);  sx[t] += __shfl_xor(sx[t], 32, 64);
      sxx[t] += __shfl_xor(sxx[t], 16, 64); sxx[t] += __shfl_xor(sxx[t], 32, 64);
    }
    if (quad == 0) {
#pragma unroll
      for (int t = 0; t < 2; t++) {
        rst[0][wave][t * 16 + r16] = sx[t];
        rst[1][wave][t * 16 + r16] = sxx[t];
      }
    }
  }
#pragma unroll
  for (int i = 0; i < 2; i++)
#pragma unroll
    for (int j = 0; j < 2; j++)
#pragma unroll
      for (int r = 0; r < 4; r++)
        part[wave][i * 16 + quad * 4 + r][j * 16 + r16] = acc[i][j][r];
  __syncthreads();

  int row = tid >> 3, c4 = (tid & 7) * 4;
  f32x4 v = *(const f32x4*)&part[0][row][c4];
  v += *(const f32x4*)&part[1][row][c4];
  v += *(const f32x4*)&part[2][row][c4];
  v += *(const f32x4*)&part[3][row][c4];
  int grow = m0 + row, gcol = n0 + c4;

  if (MODE == 2) {
    float S = rst[0][0][row] + rst[0][1][row] + rst[0][2][row] + rst[0][3][row];
    float Q = rst[1][0][row] + rst[1][1][row] + rst[1][2][row] + rst[1][3][row];
    float mu = S * (1.0f / 512.0f);
    float var = Q * (1.0f / 512.0f) - mu * mu;
    float rs = rsqrtf(var + 1e-5f);
    f32x4 s1v = *(const f32x4*)(e2 + gcol);
    f32x4 ccv = *(const f32x4*)(e3 + gcol);
    bf16x4v o;
#pragma unroll
    for (int t = 0; t < 4; t++) {
      float xg = rs * (v[t] - mu * s1v[t]) + ccv[t];
      xg = 0.5f * xg * (1.0f + erff(xg * 0.70710678118654752f));
      o[t] = (bf16_t)xg;
    }
    *(bf16x4v*)((bf16_t*)out + (size_t)grow * N + gcol) = o;
  } else {
    v += *(const f32x4*)(e2 + gcol);  // bias
    v += *(const f32x4*)(res + (size_t)grow * N + gcol);
    *(f32x4*)((float*)out + (size_t)grow * N + gcol) = v;
  }
}

// ---------------------------------------------------------------------------
// Attention R19 (= R16, audited): FOUR balanced rows per block:
// (383-b, 192+b, 191-b, b), n-sum = 770 constant; grid (96,8). Extends the
// twice-verified pairing mechanism: each K-row load feeds up to 4 dots, each
// V load up to 4 fma chains. ps-packed {e,p} + 4-wide PV kept. LDS ~38 KB.
// No cross-block sync; all loops bounded; all indices statically in range.
// ---------------------------------------------------------------------------
template <int RC>
__device__ __forceinline__ void pv_region(int& j, int jend,
                                          const bf16_t* __restrict__ vb,
                                          uint2 (*ps)[TT],
                                          const float* __restrict__ evh,
                                          int lane, float (&acc)[4]) {
  for (; j + 12 < jend; j += 16) {
    float v0 = (float)vb[(size_t)j * 1536];
    float v1 = (float)vb[(size_t)(j + 4) * 1536];
    float v2 = (float)vb[(size_t)(j + 8) * 1536];
    float v3 = (float)vb[(size_t)(j + 12) * 1536];
#pragma unroll
    for (int r = 0; r < RC; r++) {
      uint2 c0 = ps[r][j], c1 = ps[r][j + 4];
      uint2 c2 = ps[r][j + 8], c3 = ps[r][j + 12];
      acc[r] = fmaf(__uint_as_float(c0.y) * v0, evh[c0.x * 64 + lane], acc[r]);
      acc[r] = fmaf(__uint_as_float(c1.y) * v1, evh[c1.x * 64 + lane], acc[r]);
      acc[r] = fmaf(__uint_as_float(c2.y) * v2, evh[c2.x * 64 + lane], acc[r]);
      acc[r] = fmaf(__uint_as_float(c3.y) * v3, evh[c3.x * 64 + lane], acc[r]);
    }
  }
  for (; j < jend; j += 4) {
    float v0 = (float)vb[(size_t)j * 1536];
#pragma unroll
    for (int r = 0; r < RC; r++) {
      uint2 c0 = ps[r][j];
      acc[r] = fmaf(__uint_as_float(c0.y) * v0, evh[c0.x * 64 + lane], acc[r]);
    }
  }
}

__global__ __launch_bounds__(256) void attn_k(
    const bf16_t* __restrict__ qkv, const int* __restrict__ bias_matrix,
    const float* __restrict__ attn_bias_emb, const float* __restrict__ ek_tab,
    const float* __restrict__ ev_tab, bf16_t* __restrict__ ybuf) {
  __shared__ uint2 ps[4][TT];      // {e, bits(p)} per row
  __shared__ float qe[4][EE][68];
  __shared__ float evh[EE * 64];
  __shared__ float red[4][256];
  __shared__ float absh[EE];
  __shared__ float scr[4][4];

  int b = blockIdx.x, h = blockIdx.y;
  int tid = threadIdx.x, lane = tid & 63, wave = tid >> 6;
  // rows descending by n: nn[0] >= nn[1] >= nn[2] >= nn[3]
  int rows[4] = {(TT - 1) - b, 192 + b, 191 - b, b};
  int nn[4] = {TT - b, 193 + b, 192 - b, b + 1};

  if (tid < EE) absh[tid] = attn_bias_emb[tid * HH + h];
  for (int idx = tid; idx < EE * 64; idx += 256) {
    int e = idx >> 6, d = idx & 63;
    float ek = ek_tab[e * 512 + h * 64 + d];
#pragma unroll
    for (int r = 0; r < 4; r++) {
      float q = (float)qkv[(size_t)rows[r] * 1536 + h * 64 + d];
      qe[r][e][d] = q * ek;
    }
    evh[idx] = ev_tab[e * 512 + h * 64 + d];
  }
  __syncthreads();

  float ls[4] = {0.f, 0.f, 0.f, 0.f};
  for (int jl = tid; jl < nn[0]; jl += 256) {
    const uint4* kp = (const uint4*)(qkv + (size_t)jl * 1536 + 512 + h * 64);
    uint4 kr[8];
#pragma unroll
    for (int dg = 0; dg < 8; dg++) kr[dg] = kp[dg];
    int ee[4];
    float ac[4] = {0.f, 0.f, 0.f, 0.f};
#pragma unroll
    for (int r = 0; r < 4; r++)
      ee[r] = (jl < nn[r]) ? bias_matrix[(size_t)rows[r] * TT + jl] : 0;
#pragma unroll
    for (int dg = 0; dg < 8; dg++) {
      bf16x8 kv = *reinterpret_cast<const bf16x8*>(&kr[dg]);
      float kf[8];
#pragma unroll
      for (int t = 0; t < 8; t++) kf[t] = (float)kv[t];
#pragma unroll
      for (int r = 0; r < 4; r++) {
        f32x4 qa = *(const f32x4*)&qe[r][ee[r]][dg * 8];
        f32x4 qb = *(const f32x4*)&qe[r][ee[r]][dg * 8 + 4];
        ac[r] += kf[0] * qa.x + kf[1] * qa.y + kf[2] * qa.z + kf[3] * qa.w +
                 kf[4] * qb.x + kf[5] * qb.y + kf[6] * qb.z + kf[7] * qb.w;
      }
    }
#pragma unroll
    for (int r = 0; r < 4; r++) {
      if (jl < nn[r]) {
        float p = __expf(ac[r] * 0.125f + absh[ee[r]]);
        uint2 pk;
        pk.x = (unsigned)ee[r];
        pk.y = __float_as_uint(p);
        ps[r][jl] = pk;
        ls[r] += p;
      }
    }
  }
#pragma unroll
  for (int r = 0; r < 4; r++) {
    ls[r] = wave_reduce_sum(ls[r]);
    if (lane == 0) scr[r][wave] = ls[r];
  }
  __syncthreads();

  const bf16_t* vb = qkv + 1024 + h * 64 + lane;  // lane's d column of v rows
  float acc[4] = {0.f, 0.f, 0.f, 0.f};
  int j = wave;
  pv_region<4>(j, nn[3], vb, ps, evh, lane, acc);
  pv_region<3>(j, nn[2], vb, ps, evh, lane, acc);
  pv_region<2>(j, nn[1], vb, ps, evh, lane, acc);
  pv_region<1>(j, nn[0], vb, ps, evh, lane, acc);
#pragma unroll
  for (int r = 0; r < 4; r++) red[r][wave * 64 + lane] = acc[r];
  __syncthreads();

  {
    int r = tid >> 6, t = tid & 63;
    int ir = (r == 0) ? (TT - 1 - b) : (r == 1) ? (192 + b)
             : (r == 2) ? (191 - b) : b;
    float iv = 1.0f / (scr[r][0] + scr[r][1] + scr[r][2] + scr[r][3]);
    float y =
        (red[r][t] + red[r][64 + t] + red[r][128 + t] + red[r][192 + t]) * iv;
    ybuf[(size_t)ir * CC + h * 64 + t] = (bf16_t)y;
  }
}

// ---------------------------------------------------------------------------
extern "C" void kernel_launch(void* const* d_in, const int* in_sizes, int n_in,
                              void* d_out, int out_size, void* d_ws,
                              size_t ws_size, hipStream_t stream) {
  const float* x = (const float*)d_in[0];
  const int* bias_mat = (const int*)d_in[1];

  char* wp = (char*)d_ws;
  float* ektab = (float*)wp;  wp += 16 * 512 * 4;
  float* evtab = (float*)wp;  wp += 16 * 512 * 4;
  float* s1f = (float*)wp;    wp += 2048 * 4;
  float* cf = (float*)wp;     wp += 2048 * 4;
  float* x1 = (float*)wp;     wp += 384 * 512 * 4;
  bf16_t* wfc_bf = (bf16_t*)wp;    wp += 2048 * 512 * 2;
  bf16_t* wproj_bf = (bf16_t*)wp;  wp += 512 * 512 * 2;
  bf16_t* wcproj_bf = (bf16_t*)wp; wp += 512 * 2048 * 2;
  bf16_t* qkv = (bf16_t*)wp;  wp += 384 * 1536 * 2;
  bf16_t* ybuf = (bf16_t*)wp; wp += 384 * 512 * 2;
  bf16_t* gbuf = (bf16_t*)wp; wp += 384 * 2048 * 2;

  PrepX X;
  X.eemb = (const float*)d_in[9];
  X.wekw = (const float*)d_in[10];
  X.wekb = (const float*)d_in[11];
  X.wevw = (const float*)d_in[12];
  X.wevb = (const float*)d_in[13];
  X.ln2w = (const float*)d_in[14];
  X.ln2b = (const float*)d_in[15];
  X.cfcw = (const float*)d_in[16];
  X.cfcb = (const float*)d_in[17];
  X.wproj = (const float*)d_in[6];
  X.wcproj = (const float*)d_in[18];
  X.ektab = ektab; X.evtab = evtab; X.s1f = s1f; X.cf = cf;
  X.wfc_bf = wfc_bf; X.wproj_bf = wproj_bf; X.wcproj_bf = wcproj_bf;

  // 1) self-contained qkv (576 gemm tiles, rows 0-11) + 1088 hidden prep
  //    units (rows 12-34): edge tables, wfc rows, wproj/wcproj conversion
  qkv_k<<<dim3(48, 35), 256, 0, stream>>>(
      x, (const float*)d_in[4], (const float*)d_in[2], (const float*)d_in[3],
      (const float*)d_in[5], qkv, X);
  // 2) attention (4 balanced rows/block, 96x8 grid)
  attn_k<<<dim3(TT / 4, HH), 256, 0, stream>>>(qkv, bias_mat,
                                               (const float*)d_in[8], ektab,
                                               evtab, ybuf);
  // 3) x1 = x + y @ wproj^T + b  (no stat atomics)
  gemm_k<1><<<dim3(16, 12), 256, 0, stream>>>(
      ybuf, wproj_bf, (const float*)d_in[7], nullptr, x, x1, 512, 512);
  // 4) g = gelu(LN2(x1) @ cfc^T + b)  (row stats from own A reads)
  gemm_k<2><<<dim3(64, 12), 256, 0, stream>>>(x1, wfc_bf, s1f, cf, nullptr,
                                              gbuf, 2048, 512);
  // 5) out = x1 + g @ cproj^T + b
  gemm_k<3><<<dim3(16, 12), 256, 0, stream>>>(
      gbuf, wcproj_bf, (const float*)d_in[19], nullptr, x1, d_out, 512, 2048);
}

// Round 9
// 167.915 us; speedup vs baseline: 2.2252x; 1.1075x over previous
//
#include <hip/hip_runtime.h>
#include <math.h>

// Problem constants: B=1, T=384, C=512, H=8, D=64, E=16. Inputs/outputs f32.
// R20 = R8 base (stats-fold kept: gemm<2> computes own row stats, no
// atomics) + attn reverted to the twice-verified 2-ROW pairing (R14:
// 36 VGPR, 46% occ) — R8 showed 4-row blows VGPR to 144 / occ to 9% and
// costs +19us. New micro-opt inside the 2-row structure: per-j softmax
// state of BOTH rows packed in one uint4 -> PV shared region does one
// ds_read_b128 per j instead of two ds_read_b64.
// R7 lesson kept: NO in-kernel cross-block sync. 5 dispatches.
#define TT 384
#define CC 512
#define HH 8
#define EE 16

typedef __bf16 bf16_t;
typedef __bf16 bf16x8 __attribute__((ext_vector_type(8)));
typedef __bf16 bf16x4v __attribute__((ext_vector_type(4)));
typedef float f32x4 __attribute__((ext_vector_type(4)));

__device__ __forceinline__ float wave_reduce_sum(float v) {
#pragma unroll
  for (int off = 32; off >= 1; off >>= 1) v += __shfl_xor(v, off, 64);
  return v;
}

// ---------------------------------------------------------------------------
// wrow_unit: one LN-folded weight row: W'[n]=g∘W[n] (bf16), s1[n]=Σ W'[n,k],
// c[n] = Σ b_k W[n,k] + extra
// ---------------------------------------------------------------------------
__device__ __forceinline__ void wrow_unit(const float* __restrict__ wr,
                                          const float* __restrict__ g,
                                          const float* __restrict__ bb,
                                          float extra_c, bf16_t* __restrict__ orow,
                                          float* __restrict__ s1p,
                                          float* __restrict__ cp, int lane) {
  const float* p = wr + lane * 8;
  f32x4 w0 = *(const f32x4*)p, w1 = *(const f32x4*)(p + 4);
  f32x4 g0 = *(const f32x4*)(g + lane * 8), g1 = *(const f32x4*)(g + lane * 8 + 4);
  f32x4 b0 = *(const f32x4*)(bb + lane * 8), b1 = *(const f32x4*)(bb + lane * 8 + 4);
  f32x4 p0 = w0 * g0, p1 = w1 * g1;
  bf16x8 o;
  o[0] = (bf16_t)p0.x; o[1] = (bf16_t)p0.y; o[2] = (bf16_t)p0.z; o[3] = (bf16_t)p0.w;
  o[4] = (bf16_t)p1.x; o[5] = (bf16_t)p1.y; o[6] = (bf16_t)p1.z; o[7] = (bf16_t)p1.w;
  *(bf16x8*)(orow + lane * 8) = o;
  float s1 = p0.x + p0.y + p0.z + p0.w + p1.x + p1.y + p1.z + p1.w;
  float c = w0.x * b0.x + w0.y * b0.y + w0.z * b0.z + w0.w * b0.w +
            w1.x * b1.x + w1.y * b1.y + w1.z * b1.z + w1.w * b1.w;
  s1 = wave_reduce_sum(s1);
  c = wave_reduce_sum(c);
  if (lane == 0) { *s1p = s1; *cp = c + extra_c; }
}

// ---------------------------------------------------------------------------
// Prep bundle (hidden in qkv dispatch rows by>=12; 1088 units):
// 0-255 edge tables; 256-767 wfc rows; 768-1023 wcproj conv; 1024-1087
// wproj conv.
// ---------------------------------------------------------------------------
struct PrepX {
  const float *eemb, *wekw, *wekb, *wevw, *wevb;
  const float *ln2w, *ln2b, *cfcw, *cfcb;
  const float *wproj, *wcproj;
  float *ektab, *evtab, *s1f, *cf;
  bf16_t *wfc_bf, *wproj_bf, *wcproj_bf;
};

__device__ void prep_unit(int u, const PrepX& X, int tid) {
  int lane = tid & 63, wave = tid >> 6;
  if (u < 256) {
    int wid = u * 4 + wave;
    int gbase = wid * 16;
    int table = gbase >> 13;
    int e = (gbase >> 9) & 15;
    int c0 = gbase & 511;
    const float* er = X.eemb + e * 512 + lane * 8;
    f32x4 ea = *(const f32x4*)er;
    f32x4 eb = *(const f32x4*)(er + 4);
    const float* wbase = table ? X.wevw : X.wekw;
    const float* bbase = table ? X.wevb : X.wekb;
    float* obase = (table ? X.evtab : X.ektab) + e * 512;
#pragma unroll
    for (int o = 0; o < 16; o++) {
      int c = c0 + o;
      const float* wr = wbase + (size_t)c * 512 + lane * 8;
      f32x4 wa = *(const f32x4*)wr;
      f32x4 wb = *(const f32x4*)(wr + 4);
      float acc = ea.x * wa.x + ea.y * wa.y + ea.z * wa.z + ea.w * wa.w +
                  eb.x * wb.x + eb.y * wb.y + eb.z * wb.z + eb.w * wb.w;
      acc = wave_reduce_sum(acc);
      if (lane == 0) obase[c] = acc + bbase[c];
    }
  } else if (u < 768) {
    int n = (u - 256) * 4 + wave;  // 0..2047
    wrow_unit(X.cfcw + (size_t)n * 512, X.ln2w, X.ln2b, X.cfcb[n],
              X.wfc_bf + (size_t)n * 512, X.s1f + n, X.cf + n, lane);
  } else if (u < 1024) {
    int base = (u - 768) * 1024;  // wcproj: 262144 f32x4
    for (int t = tid; t < 1024; t += 256) {
      f32x4 a = *((const f32x4*)X.wcproj + base + t);
      bf16x4v o;
      o[0] = (bf16_t)a.x; o[1] = (bf16_t)a.y; o[2] = (bf16_t)a.z; o[3] = (bf16_t)a.w;
      *((bf16x4v*)X.wcproj_bf + base + t) = o;
    }
  } else if (u < 1088) {
    int base = (u - 1024) * 1024;  // wproj: 65536 f32x4
    for (int t = tid; t < 1024; t += 256) {
      f32x4 a = *((const f32x4*)X.wproj + base + t);
      bf16x4v o;
      o[0] = (bf16_t)a.x; o[1] = (bf16_t)a.y; o[2] = (bf16_t)a.z; o[3] = (bf16_t)a.w;
      *((bf16x4v*)X.wproj_bf + base + t) = o;
    }
  }
}

// ---------------------------------------------------------------------------
// qkv_k: SELF-CONTAINED qkv GEMM — no pre-pass dependency. Each 32x32 tile:
//  - loads raw f32 x and wattn, folds g∘W inline into the B fragment
//  - accumulates per-wave partials of row Σx/Σx² and col Σ(gW)/Σ(bW)
//    alongside the MFMA loop (operands already in registers)
//  - quad-shuffle + LDS reduce, epilogue applies rs·(acc−mu·s1)+c+bias.
// by>=12 rows run prep units (tables, wfc, wproj/wcproj).
// ---------------------------------------------------------------------------
__global__ __launch_bounds__(256) void qkv_k(
    const float* __restrict__ x, const float* __restrict__ wattn,
    const float* __restrict__ ln1w, const float* __restrict__ ln1b,
    const float* __restrict__ wattnb, bf16_t* __restrict__ out, PrepX X) {
  int tid = threadIdx.x;
  if (blockIdx.y >= 12) {
    prep_unit((blockIdx.y - 12) * gridDim.x + blockIdx.x, X, tid);
    return;
  }
  __shared__ float part[4][32][32];  // 16 KB
  __shared__ float rst[2][4][32];    // [sx|sxx][wave][row]  1 KB
  __shared__ float wst[2][4][32];    // [s1|c ][wave][col]  1 KB
  int lane = tid & 63, wave = tid >> 6;
  int m0 = blockIdx.y * 32, n0 = blockIdx.x * 32;
  int r16 = lane & 15, quad = lane >> 4;
  int k0 = wave * 128;  // K=512, kchunk=128

  f32x4 acc[2][2];
  f32x4 zero = {0.f, 0.f, 0.f, 0.f};
#pragma unroll
  for (int i = 0; i < 2; i++)
#pragma unroll
    for (int j = 0; j < 2; j++) acc[i][j] = zero;

  const float* Af = x + (size_t)(m0 + r16) * 512 + k0 + quad * 8;
  const float* Wf = wattn + (size_t)(n0 + r16) * 512 + k0 + quad * 8;
  const float* gp = ln1w + k0 + quad * 8;
  const float* bp = ln1b + k0 + quad * 8;

  float sx[2] = {0.f, 0.f}, sxx[2] = {0.f, 0.f};
  float s1[2] = {0.f, 0.f}, cc[2] = {0.f, 0.f};

  for (int kb0 = 0; kb0 < 128; kb0 += 64) {  // 2 k-steps hoisted
    uint4 araw[2][2][2], wraw[2][2][2];
#pragma unroll
    for (int u = 0; u < 2; u++) {
      int kb = kb0 + u * 32;
#pragma unroll
      for (int t = 0; t < 2; t++) {
        araw[u][t][0] = *(const uint4*)(Af + (size_t)t * 16 * 512 + kb);
        araw[u][t][1] = *(const uint4*)(Af + (size_t)t * 16 * 512 + kb + 4);
        wraw[u][t][0] = *(const uint4*)(Wf + (size_t)t * 16 * 512 + kb);
        wraw[u][t][1] = *(const uint4*)(Wf + (size_t)t * 16 * 512 + kb + 4);
      }
    }
#pragma unroll
    for (int u = 0; u < 2; u++) {
      int kb = kb0 + u * 32;
      f32x4 g0 = *(const f32x4*)(gp + kb), g1 = *(const f32x4*)(gp + kb + 4);
      f32x4 b0 = *(const f32x4*)(bp + kb), b1 = *(const f32x4*)(bp + kb + 4);
      bf16x8 af[2], bfr[2];
#pragma unroll
      for (int t = 0; t < 2; t++) {
        f32x4 a0 = *reinterpret_cast<const f32x4*>(&araw[u][t][0]);
        f32x4 a1 = *reinterpret_cast<const f32x4*>(&araw[u][t][1]);
        af[t][0] = (bf16_t)a0.x; af[t][1] = (bf16_t)a0.y;
        af[t][2] = (bf16_t)a0.z; af[t][3] = (bf16_t)a0.w;
        af[t][4] = (bf16_t)a1.x; af[t][5] = (bf16_t)a1.y;
        af[t][6] = (bf16_t)a1.z; af[t][7] = (bf16_t)a1.w;
        sx[t] += a0.x + a0.y + a0.z + a0.w + a1.x + a1.y + a1.z + a1.w;
        sxx[t] += a0.x * a0.x + a0.y * a0.y + a0.z * a0.z + a0.w * a0.w +
                  a1.x * a1.x + a1.y * a1.y + a1.z * a1.z + a1.w * a1.w;
        f32x4 w0 = *reinterpret_cast<const f32x4*>(&wraw[u][t][0]);
        f32x4 w1 = *reinterpret_cast<const f32x4*>(&wraw[u][t][1]);
        f32x4 p0 = w0 * g0, p1 = w1 * g1;
        bfr[t][0] = (bf16_t)p0.x; bfr[t][1] = (bf16_t)p0.y;
        bfr[t][2] = (bf16_t)p0.z; bfr[t][3] = (bf16_t)p0.w;
        bfr[t][4] = (bf16_t)p1.x; bfr[t][5] = (bf16_t)p1.y;
        bfr[t][6] = (bf16_t)p1.z; bfr[t][7] = (bf16_t)p1.w;
        s1[t] += p0.x + p0.y + p0.z + p0.w + p1.x + p1.y + p1.z + p1.w;
        cc[t] += w0.x * b0.x + w0.y * b0.y + w0.z * b0.z + w0.w * b0.w +
                 w1.x * b1.x + w1.y * b1.y + w1.z * b1.z + w1.w * b1.w;
      }
#pragma unroll
      for (int i = 0; i < 2; i++)
#pragma unroll
        for (int j = 0; j < 2; j++)
          acc[i][j] = __builtin_amdgcn_mfma_f32_16x16x32_bf16(af[i], bfr[j],
                                                              acc[i][j], 0, 0, 0);
    }
  }

  // quad-reduce stats (lanes r16, r16+16, r16+32, r16+48 → same value)
#pragma unroll
  for (int t = 0; t < 2; t++) {
    sx[t] += __shfl_xor(sx[t], 16, 64);  sx[t] += __shfl_xor(sx[t], 32, 64);
    sxx[t] += __shfl_xor(sxx[t], 16, 64); sxx[t] += __shfl_xor(sxx[t], 32, 64);
    s1[t] += __shfl_xor(s1[t], 16, 64);  s1[t] += __shfl_xor(s1[t], 32, 64);
    cc[t] += __shfl_xor(cc[t], 16, 64);  cc[t] += __shfl_xor(cc[t], 32, 64);
  }
  if (quad == 0) {
#pragma unroll
    for (int t = 0; t < 2; t++) {
      rst[0][wave][t * 16 + r16] = sx[t];
      rst[1][wave][t * 16 + r16] = sxx[t];
      wst[0][wave][t * 16 + r16] = s1[t];
      wst[1][wave][t * 16 + r16] = cc[t];
    }
  }
#pragma unroll
  for (int i = 0; i < 2; i++)
#pragma unroll
    for (int j = 0; j < 2; j++)
#pragma unroll
      for (int r = 0; r < 4; r++)
        part[wave][i * 16 + quad * 4 + r][j * 16 + r16] = acc[i][j][r];
  __syncthreads();

  int row = tid >> 3, c4 = (tid & 7) * 4;
  f32x4 v = *(const f32x4*)&part[0][row][c4];
  v += *(const f32x4*)&part[1][row][c4];
  v += *(const f32x4*)&part[2][row][c4];
  v += *(const f32x4*)&part[3][row][c4];
  float sxt = rst[0][0][row] + rst[0][1][row] + rst[0][2][row] + rst[0][3][row];
  float sxxt = rst[1][0][row] + rst[1][1][row] + rst[1][2][row] + rst[1][3][row];
  float mu = sxt * (1.0f / 512.0f);
  float var = sxxt * (1.0f / 512.0f) - mu * mu;
  float rs = rsqrtf(var + 1e-5f);
  int grow = m0 + row, gcol = n0 + c4;
  bf16x4v o;
#pragma unroll
  for (int t = 0; t < 4; t++) {
    int cl = c4 + t;
    float s1v = wst[0][0][cl] + wst[0][1][cl] + wst[0][2][cl] + wst[0][3][cl];
    float ccv = wst[1][0][cl] + wst[1][1][cl] + wst[1][2][cl] + wst[1][3][cl] +
                wattnb[n0 + cl];
    o[t] = (bf16_t)(rs * (v[t] - mu * s1v) + ccv);
  }
  *(bf16x4v*)(out + (size_t)grow * 1536 + gcol) = o;
}

// ---------------------------------------------------------------------------
// Split-K NT GEMM, 32x32 tile (R10 measured-best). 4 waves each K/4;
// K-loop hoists 4 k-steps of loads before MFMA.
// MODE 1 (PROJ): A bf16, +bias +res ->f32
// MODE 2 (FC):   A=x1 f32; row stats computed FROM OWN A-FRAGMENTS
//                (qkv_k pattern); fused-LN; gelu ->bf16
// MODE 3 (CPROJ):A bf16, +bias +res ->f32 (d_out)
// ---------------------------------------------------------------------------
template <int MODE>
__global__ __launch_bounds__(256) void gemm_k(
    const void* __restrict__ Aptr, const bf16_t* __restrict__ Wb,
    const float* __restrict__ e2, const float* __restrict__ e3,
    const float* __restrict__ res, void* __restrict__ out, int N, int K) {
  constexpr bool AF32 = (MODE == 2);
  constexpr int AW = AF32 ? 2 : 1;
  __shared__ float part[4][32][32];
  __shared__ float rst[2][4][32];  // MODE 2 row stats (1 KB, else unused)
  int tid = threadIdx.x;
  int lane = tid & 63, wave = tid >> 6;
  int m0 = blockIdx.y * 32, n0 = blockIdx.x * 32;
  int r16 = lane & 15, quad = lane >> 4;
  int kchunk = K >> 2, k0 = wave * kchunk;

  f32x4 acc[2][2];
  f32x4 zero = {0.f, 0.f, 0.f, 0.f};
#pragma unroll
  for (int i = 0; i < 2; i++)
#pragma unroll
    for (int j = 0; j < 2; j++) acc[i][j] = zero;

  const float* Af = (const float*)Aptr + (size_t)(m0 + r16) * K + k0 + quad * 8;
  const bf16_t* Ab = (const bf16_t*)Aptr + (size_t)(m0 + r16) * K + k0 + quad * 8;
  const bf16_t* Wp = Wb + (size_t)(n0 + r16) * K + k0 + quad * 8;

  float sx[2] = {0.f, 0.f}, sxx[2] = {0.f, 0.f};

  for (int kb0 = 0; kb0 < kchunk; kb0 += 128) {
    uint4 araw[4][2][AW];
    uint4 braw[4][2];
#pragma unroll
    for (int u = 0; u < 4; u++) {
      int kb = kb0 + u * 32;
#pragma unroll
      for (int t = 0; t < 2; t++) {
        if (AF32) {
          araw[u][t][0] = *(const uint4*)(Af + (size_t)t * 16 * K + kb);
          araw[u][t][1] = *(const uint4*)(Af + (size_t)t * 16 * K + kb + 4);
        } else {
          araw[u][t][0] = *(const uint4*)(Ab + (size_t)t * 16 * K + kb);
        }
        braw[u][t] = *(const uint4*)(Wp + (size_t)t * 16 * K + kb);
      }
    }
#pragma unroll
    for (int u = 0; u < 4; u++) {
      bf16x8 af[2], bfr[2];
#pragma unroll
      for (int t = 0; t < 2; t++) {
        if (AF32) {
          f32x4 a = *reinterpret_cast<const f32x4*>(&araw[u][t][0]);
          f32x4 c = *reinterpret_cast<const f32x4*>(&araw[u][t][1]);
          af[t][0] = (bf16_t)a.x; af[t][1] = (bf16_t)a.y;
          af[t][2] = (bf16_t)a.z; af[t][3] = (bf16_t)a.w;
          af[t][4] = (bf16_t)c.x; af[t][5] = (bf16_t)c.y;
          af[t][6] = (bf16_t)c.z; af[t][7] = (bf16_t)c.w;
          sx[t] += a.x + a.y + a.z + a.w + c.x + c.y + c.z + c.w;
          sxx[t] += a.x * a.x + a.y * a.y + a.z * a.z + a.w * a.w +
                    c.x * c.x + c.y * c.y + c.z * c.z + c.w * c.w;
        } else {
          af[t] = *reinterpret_cast<const bf16x8*>(&araw[u][t][0]);
        }
        bfr[t] = *reinterpret_cast<const bf16x8*>(&braw[u][t]);
      }
#pragma unroll
      for (int i = 0; i < 2; i++)
#pragma unroll
        for (int j = 0; j < 2; j++)
          acc[i][j] = __builtin_amdgcn_mfma_f32_16x16x32_bf16(af[i], bfr[j],
                                                              acc[i][j], 0, 0, 0);
    }
  }

  if (MODE == 2) {  // quad-reduce row stats, store per-wave partials
#pragma unroll
    for (int t = 0; t < 2; t++) {
      sx[t] += __shfl_xor(sx[t], 16, 64);  sx[t] += __shfl_xor(sx[t], 32, 64);
      sxx[t] += __shfl_xor(sxx[t], 16, 64); sxx[t] += __shfl_xor(sxx[t], 32, 64);
    }
    if (quad == 0) {
#pragma unroll
      for (int t = 0; t < 2; t++) {
        rst[0][wave][t * 16 + r16] = sx[t];
        rst[1][wave][t * 16 + r16] = sxx[t];
      }
    }
  }
#pragma unroll
  for (int i = 0; i < 2; i++)
#pragma unroll
    for (int j = 0; j < 2; j++)
#pragma unroll
      for (int r = 0; r < 4; r++)
        part[wave][i * 16 + quad * 4 + r][j * 16 + r16] = acc[i][j][r];
  __syncthreads();

  int row = tid >> 3, c4 = (tid & 7) * 4;
  f32x4 v = *(const f32x4*)&part[0][row][c4];
  v += *(const f32x4*)&part[1][row][c4];
  v += *(const f32x4*)&part[2][row][c4];
  v += *(const f32x4*)&part[3][row][c4];
  int grow = m0 + row, gcol = n0 + c4;

  if (MODE == 2) {
    float S = rst[0][0][row] + rst[0][1][row] + rst[0][2][row] + rst[0][3][row];
    float Q = rst[1][0][row] + rst[1][1][row] + rst[1][2][row] + rst[1][3][row];
    float mu = S * (1.0f / 512.0f);
    float var = Q * (1.0f / 512.0f) - mu * mu;
    float rs = rsqrtf(var + 1e-5f);
    f32x4 s1v = *(const f32x4*)(e2 + gcol);
    f32x4 ccv = *(const f32x4*)(e3 + gcol);
    bf16x4v o;
#pragma unroll
    for (int t = 0; t < 4; t++) {
      float xg = rs * (v[t] - mu * s1v[t]) + ccv[t];
      xg = 0.5f * xg * (1.0f + erff(xg * 0.70710678118654752f));
      o[t] = (bf16_t)xg;
    }
    *(bf16x4v*)((bf16_t*)out + (size_t)grow * N + gcol) = o;
  } else {
    v += *(const f32x4*)(e2 + gcol);  // bias
    v += *(const f32x4*)(res + (size_t)grow * N + gcol);
    *(f32x4*)((float*)out + (size_t)grow * N + gcol) = v;
  }
}

// ---------------------------------------------------------------------------
// Attention R20: PAIRED query rows (i1=b, i2=383-b), grid (192,8) — the
// twice-verified R14 structure (36 VGPR, 46% occ). One change: per-j state
// of both rows packed as uint4 {e1,p1,e2,p2} -> PV shared region does one
// ds_read_b128 per j (was two ds_read_b64); tail reads the row-2 half.
// ---------------------------------------------------------------------------
__global__ __launch_bounds__(256) void attn_k(
    const bf16_t* __restrict__ qkv, const int* __restrict__ bias_matrix,
    const float* __restrict__ attn_bias_emb, const float* __restrict__ ek_tab,
    const float* __restrict__ ev_tab, bf16_t* __restrict__ ybuf) {
  __shared__ uint4 psv[TT];            // {e1, bits(p1), e2, bits(p2)} per j
  __shared__ float qe1[EE][68], qe2[EE][68];
  __shared__ float evh[EE * 64];
  __shared__ float red[2][4 * 64];
  __shared__ float absh[EE];
  __shared__ float scr[2][4];

  int b = blockIdx.x, h = blockIdx.y;
  int i1 = b, i2 = (TT - 1) - b;  // i1 < i2, n1 <= n2
  int n1 = i1 + 1, n2 = i2 + 1;
  int tid = threadIdx.x, lane = tid & 63, wave = tid >> 6;

  if (tid < EE) absh[tid] = attn_bias_emb[tid * HH + h];
  for (int idx = tid; idx < EE * 64; idx += 256) {
    int e = idx >> 6, d = idx & 63;
    float q1 = (float)qkv[(size_t)i1 * 1536 + h * 64 + d];
    float q2 = (float)qkv[(size_t)i2 * 1536 + h * 64 + d];
    float ek = ek_tab[e * 512 + h * 64 + d];
    qe1[e][d] = q1 * ek;
    qe2[e][d] = q2 * ek;
    evh[idx] = ev_tab[e * 512 + h * 64 + d];
  }
  __syncthreads();

  float ls1 = 0.0f, ls2 = 0.0f;
  const int* bm1 = bias_matrix + (size_t)i1 * TT;
  const int* bm2 = bias_matrix + (size_t)i2 * TT;
  for (int jl = tid; jl < n2; jl += 256) {
    int e2 = bm2[jl];
    const uint4* kp = (const uint4*)(qkv + (size_t)jl * 1536 + 512 + h * 64);
    uint4 kr[8];
#pragma unroll
    for (int dg = 0; dg < 8; dg++) kr[dg] = kp[dg];
    float a2 = 0.f;
#pragma unroll
    for (int dg = 0; dg < 8; dg++) {
      bf16x8 kv = *reinterpret_cast<const bf16x8*>(&kr[dg]);
      f32x4 qa = *(const f32x4*)&qe2[e2][dg * 8];
      f32x4 qb = *(const f32x4*)&qe2[e2][dg * 8 + 4];
      a2 += (float)kv[0] * qa.x + (float)kv[1] * qa.y + (float)kv[2] * qa.z +
            (float)kv[3] * qa.w + (float)kv[4] * qb.x + (float)kv[5] * qb.y +
            (float)kv[6] * qb.z + (float)kv[7] * qb.w;
    }
    float p2 = __expf(a2 * 0.125f + absh[e2]);
    uint4 pk;
    pk.x = 0u; pk.y = 0u;
    pk.z = (unsigned)e2; pk.w = __float_as_uint(p2);
    ls2 += p2;
    if (jl < n1) {
      int e1 = bm1[jl];
      float a1 = 0.f;
#pragma unroll
      for (int dg = 0; dg < 8; dg++) {
        bf16x8 kv = *reinterpret_cast<const bf16x8*>(&kr[dg]);
        f32x4 qa = *(const f32x4*)&qe1[e1][dg * 8];
        f32x4 qb = *(const f32x4*)&qe1[e1][dg * 8 + 4];
        a1 += (float)kv[0] * qa.x + (float)kv[1] * qa.y + (float)kv[2] * qa.z +
              (float)kv[3] * qa.w + (float)kv[4] * qb.x + (float)kv[5] * qb.y +
              (float)kv[6] * qb.z + (float)kv[7] * qb.w;
      }
      float p1 = __expf(a1 * 0.125f + absh[e1]);
      pk.x = (unsigned)e1;
      pk.y = __float_as_uint(p1);
      ls1 += p1;
    }
    psv[jl] = pk;
  }
  ls1 = wave_reduce_sum(ls1);
  ls2 = wave_reduce_sum(ls2);
  if (lane == 0) { scr[0][wave] = ls1; scr[1][wave] = ls2; }
  __syncthreads();
  float inv1 = 1.0f / (scr[0][0] + scr[0][1] + scr[0][2] + scr[0][3]);
  float inv2 = 1.0f / (scr[1][0] + scr[1][1] + scr[1][2] + scr[1][3]);

  const bf16_t* vb = qkv + 1024 + h * 64 + lane;  // lane's d column of v rows
  float acc1 = 0.0f, acc2 = 0.0f;
  int j = wave;
  // shared region: both rows, 4-wide, one b128 read per j
  for (; j + 12 < n1; j += 16) {
    float v0 = (float)vb[(size_t)j * 1536];
    float v1 = (float)vb[(size_t)(j + 4) * 1536];
    float v2 = (float)vb[(size_t)(j + 8) * 1536];
    float v3 = (float)vb[(size_t)(j + 12) * 1536];
    uint4 q0 = psv[j], q1 = psv[j + 4], q2 = psv[j + 8], q3 = psv[j + 12];
    acc2 = fmaf(__uint_as_float(q0.w) * v0, evh[q0.z * 64 + lane], acc2);
    acc2 = fmaf(__uint_as_float(q1.w) * v1, evh[q1.z * 64 + lane], acc2);
    acc2 = fmaf(__uint_as_float(q2.w) * v2, evh[q2.z * 64 + lane], acc2);
    acc2 = fmaf(__uint_as_float(q3.w) * v3, evh[q3.z * 64 + lane], acc2);
    acc1 = fmaf(__uint_as_float(q0.y) * v0, evh[q0.x * 64 + lane], acc1);
    acc1 = fmaf(__uint_as_float(q1.y) * v1, evh[q1.x * 64 + lane], acc1);
    acc1 = fmaf(__uint_as_float(q2.y) * v2, evh[q2.x * 64 + lane], acc1);
    acc1 = fmaf(__uint_as_float(q3.y) * v3, evh[q3.x * 64 + lane], acc1);
  }
  for (; j < n1; j += 4) {
    float v0 = (float)vb[(size_t)j * 1536];
    uint4 q0 = psv[j];
    acc2 = fmaf(__uint_as_float(q0.w) * v0, evh[q0.z * 64 + lane], acc2);
    acc1 = fmaf(__uint_as_float(q0.y) * v0, evh[q0.x * 64 + lane], acc1);
  }
  // tail region: row 2 only, 4-wide, b64 reads of the row-2 halves
  const uint2* ps2h = (const uint2*)((const char*)psv + 8);  // psv[j].zw
  for (; j + 12 < n2; j += 16) {
    float v0 = (float)vb[(size_t)j * 1536];
    float v1 = (float)vb[(size_t)(j + 4) * 1536];
    float v2 = (float)vb[(size_t)(j + 8) * 1536];
    float v3 = (float)vb[(size_t)(j + 12) * 1536];
    uint2 c0 = ps2h[j * 2], c1 = ps2h[(j + 4) * 2];
    uint2 c2 = ps2h[(j + 8) * 2], c3 = ps2h[(j + 12) * 2];
    acc2 = fmaf(__uint_as_float(c0.y) * v0, evh[c0.x * 64 + lane], acc2);
    acc2 = fmaf(__uint_as_float(c1.y) * v1, evh[c1.x * 64 + lane], acc2);
    acc2 = fmaf(__uint_as_float(c2.y) * v2, evh[c2.x * 64 + lane], acc2);
    acc2 = fmaf(__uint_as_float(c3.y) * v3, evh[c3.x * 64 + lane], acc2);
  }
  for (; j < n2; j += 4) {
    float v0 = (float)vb[(size_t)j * 1536];
    uint2 c0 = ps2h[j * 2];
    acc2 = fmaf(__uint_as_float(c0.y) * v0, evh[c0.x * 64 + lane], acc2);
  }
  red[0][wave * 64 + lane] = acc1;
  red[1][wave * 64 + lane] = acc2;
  __syncthreads();
  if (tid < 64) {
    float y =
        (red[0][tid] + red[0][64 + tid] + red[0][128 + tid] + red[0][192 + tid]) *
        inv1;
    ybuf[(size_t)i1 * CC + h * 64 + tid] = (bf16_t)y;
  } else if (tid < 128) {
    int t = tid - 64;
    float y =
        (red[1][t] + red[1][64 + t] + red[1][128 + t] + red[1][192 + t]) * inv2;
    ybuf[(size_t)i2 * CC + h * 64 + t] = (bf16_t)y;
  }
}

// ---------------------------------------------------------------------------
extern "C" void kernel_launch(void* const* d_in, const int* in_sizes, int n_in,
                              void* d_out, int out_size, void* d_ws,
                              size_t ws_size, hipStream_t stream) {
  const float* x = (const float*)d_in[0];
  const int* bias_mat = (const int*)d_in[1];

  char* wp = (char*)d_ws;
  float* ektab = (float*)wp;  wp += 16 * 512 * 4;
  float* evtab = (float*)wp;  wp += 16 * 512 * 4;
  float* s1f = (float*)wp;    wp += 2048 * 4;
  float* cf = (float*)wp;     wp += 2048 * 4;
  float* x1 = (float*)wp;     wp += 384 * 512 * 4;
  bf16_t* wfc_bf = (bf16_t*)wp;    wp += 2048 * 512 * 2;
  bf16_t* wproj_bf = (bf16_t*)wp;  wp += 512 * 512 * 2;
  bf16_t* wcproj_bf = (bf16_t*)wp; wp += 512 * 2048 * 2;
  bf16_t* qkv = (bf16_t*)wp;  wp += 384 * 1536 * 2;
  bf16_t* ybuf = (bf16_t*)wp; wp += 384 * 512 * 2;
  bf16_t* gbuf = (bf16_t*)wp; wp += 384 * 2048 * 2;

  PrepX X;
  X.eemb = (const float*)d_in[9];
  X.wekw = (const float*)d_in[10];
  X.wekb = (const float*)d_in[11];
  X.wevw = (const float*)d_in[12];
  X.wevb = (const float*)d_in[13];
  X.ln2w = (const float*)d_in[14];
  X.ln2b = (const float*)d_in[15];
  X.cfcw = (const float*)d_in[16];
  X.cfcb = (const float*)d_in[17];
  X.wproj = (const float*)d_in[6];
  X.wcproj = (const float*)d_in[18];
  X.ektab = ektab; X.evtab = evtab; X.s1f = s1f; X.cf = cf;
  X.wfc_bf = wfc_bf; X.wproj_bf = wproj_bf; X.wcproj_bf = wcproj_bf;

  // 1) self-contained qkv (576 gemm tiles, rows 0-11) + 1088 hidden prep
  //    units (rows 12-34): edge tables, wfc rows, wproj/wcproj conversion
  qkv_k<<<dim3(48, 35), 256, 0, stream>>>(
      x, (const float*)d_in[4], (const float*)d_in[2], (const float*)d_in[3],
      (const float*)d_in[5], qkv, X);
  // 2) attention (paired rows (b, 383-b), 192x8 grid, uint4-packed PV)
  attn_k<<<dim3(TT / 2, HH), 256, 0, stream>>>(qkv, bias_mat,
                                               (const float*)d_in[8], ektab,
                                               evtab, ybuf);
  // 3) x1 = x + y @ wproj^T + b  (no stat atomics)
  gemm_k<1><<<dim3(16, 12), 256, 0, stream>>>(
      ybuf, wproj_bf, (const float*)d_in[7], nullptr, x, x1, 512, 512);
  // 4) g = gelu(LN2(x1) @ cfc^T + b)  (row stats from own A reads)
  gemm_k<2><<<dim3(64, 12), 256, 0, stream>>>(x1, wfc_bf, s1f, cf, nullptr,
                                              gbuf, 2048, 512);
  // 5) out = x1 + g @ cproj^T + b
  gemm_k<3><<<dim3(16, 12), 256, 0, stream>>>(
      gbuf, wcproj_bf, (const float*)d_in[19], nullptr, x1, d_out, 512, 2048);
}

// Round 10
// 166.582 us; speedup vs baseline: 2.2430x; 1.0080x over previous
//
#include <hip/hip_runtime.h>
#include <math.h>

// Problem constants: B=1, T=384, C=512, H=8, D=64, E=16. Inputs/outputs f32.
// R21 = R9 base + TRANSPOSED-K path: qkv_k's K-tile blocks (n0 in [512,1024))
// also write their register outputs to kT[h][dg][j][8] (384 KB); attn's QK
// loop reads kT fully coalesced (64 lanes x consecutive 16B = 1KB/inst)
// instead of the old 3072B-stride scatter (64 cache lines/inst).
// Kept: 2-row paired attn (36 VGPR / 46% occ), uint4-packed PV, stats-fold
// in gemm<2>, no atomics, no cross-block sync (R7 lesson), 5 dispatches.
#define TT 384
#define CC 512
#define HH 8
#define EE 16

typedef __bf16 bf16_t;
typedef __bf16 bf16x8 __attribute__((ext_vector_type(8)));
typedef __bf16 bf16x4v __attribute__((ext_vector_type(4)));
typedef float f32x4 __attribute__((ext_vector_type(4)));

__device__ __forceinline__ float wave_reduce_sum(float v) {
#pragma unroll
  for (int off = 32; off >= 1; off >>= 1) v += __shfl_xor(v, off, 64);
  return v;
}

// ---------------------------------------------------------------------------
// wrow_unit: one LN-folded weight row: W'[n]=g∘W[n] (bf16), s1[n]=Σ W'[n,k],
// c[n] = Σ b_k W[n,k] + extra
// ---------------------------------------------------------------------------
__device__ __forceinline__ void wrow_unit(const float* __restrict__ wr,
                                          const float* __restrict__ g,
                                          const float* __restrict__ bb,
                                          float extra_c, bf16_t* __restrict__ orow,
                                          float* __restrict__ s1p,
                                          float* __restrict__ cp, int lane) {
  const float* p = wr + lane * 8;
  f32x4 w0 = *(const f32x4*)p, w1 = *(const f32x4*)(p + 4);
  f32x4 g0 = *(const f32x4*)(g + lane * 8), g1 = *(const f32x4*)(g + lane * 8 + 4);
  f32x4 b0 = *(const f32x4*)(bb + lane * 8), b1 = *(const f32x4*)(bb + lane * 8 + 4);
  f32x4 p0 = w0 * g0, p1 = w1 * g1;
  bf16x8 o;
  o[0] = (bf16_t)p0.x; o[1] = (bf16_t)p0.y; o[2] = (bf16_t)p0.z; o[3] = (bf16_t)p0.w;
  o[4] = (bf16_t)p1.x; o[5] = (bf16_t)p1.y; o[6] = (bf16_t)p1.z; o[7] = (bf16_t)p1.w;
  *(bf16x8*)(orow + lane * 8) = o;
  float s1 = p0.x + p0.y + p0.z + p0.w + p1.x + p1.y + p1.z + p1.w;
  float c = w0.x * b0.x + w0.y * b0.y + w0.z * b0.z + w0.w * b0.w +
            w1.x * b1.x + w1.y * b1.y + w1.z * b1.z + w1.w * b1.w;
  s1 = wave_reduce_sum(s1);
  c = wave_reduce_sum(c);
  if (lane == 0) { *s1p = s1; *cp = c + extra_c; }
}

// ---------------------------------------------------------------------------
// Prep bundle (hidden in qkv dispatch rows by>=12; 1088 units):
// 0-255 edge tables; 256-767 wfc rows; 768-1023 wcproj conv; 1024-1087
// wproj conv.
// ---------------------------------------------------------------------------
struct PrepX {
  const float *eemb, *wekw, *wekb, *wevw, *wevb;
  const float *ln2w, *ln2b, *cfcw, *cfcb;
  const float *wproj, *wcproj;
  float *ektab, *evtab, *s1f, *cf;
  bf16_t *wfc_bf, *wproj_bf, *wcproj_bf;
};

__device__ void prep_unit(int u, const PrepX& X, int tid) {
  int lane = tid & 63, wave = tid >> 6;
  if (u < 256) {
    int wid = u * 4 + wave;
    int gbase = wid * 16;
    int table = gbase >> 13;
    int e = (gbase >> 9) & 15;
    int c0 = gbase & 511;
    const float* er = X.eemb + e * 512 + lane * 8;
    f32x4 ea = *(const f32x4*)er;
    f32x4 eb = *(const f32x4*)(er + 4);
    const float* wbase = table ? X.wevw : X.wekw;
    const float* bbase = table ? X.wevb : X.wekb;
    float* obase = (table ? X.evtab : X.ektab) + e * 512;
#pragma unroll
    for (int o = 0; o < 16; o++) {
      int c = c0 + o;
      const float* wr = wbase + (size_t)c * 512 + lane * 8;
      f32x4 wa = *(const f32x4*)wr;
      f32x4 wb = *(const f32x4*)(wr + 4);
      float acc = ea.x * wa.x + ea.y * wa.y + ea.z * wa.z + ea.w * wa.w +
                  eb.x * wb.x + eb.y * wb.y + eb.z * wb.z + eb.w * wb.w;
      acc = wave_reduce_sum(acc);
      if (lane == 0) obase[c] = acc + bbase[c];
    }
  } else if (u < 768) {
    int n = (u - 256) * 4 + wave;  // 0..2047
    wrow_unit(X.cfcw + (size_t)n * 512, X.ln2w, X.ln2b, X.cfcb[n],
              X.wfc_bf + (size_t)n * 512, X.s1f + n, X.cf + n, lane);
  } else if (u < 1024) {
    int base = (u - 768) * 1024;  // wcproj: 262144 f32x4
    for (int t = tid; t < 1024; t += 256) {
      f32x4 a = *((const f32x4*)X.wcproj + base + t);
      bf16x4v o;
      o[0] = (bf16_t)a.x; o[1] = (bf16_t)a.y; o[2] = (bf16_t)a.z; o[3] = (bf16_t)a.w;
      *((bf16x4v*)X.wcproj_bf + base + t) = o;
    }
  } else if (u < 1088) {
    int base = (u - 1024) * 1024;  // wproj: 65536 f32x4
    for (int t = tid; t < 1024; t += 256) {
      f32x4 a = *((const f32x4*)X.wproj + base + t);
      bf16x4v o;
      o[0] = (bf16_t)a.x; o[1] = (bf16_t)a.y; o[2] = (bf16_t)a.z; o[3] = (bf16_t)a.w;
      *((bf16x4v*)X.wproj_bf + base + t) = o;
    }
  }
}

// ---------------------------------------------------------------------------
// qkv_k: SELF-CONTAINED qkv GEMM — no pre-pass dependency. Each 32x32 tile:
//  - loads raw f32 x and wattn, folds g∘W inline into the B fragment
//  - accumulates per-wave partials of row Σx/Σx² and col Σ(gW)/Σ(bW)
//    alongside the MFMA loop (operands already in registers)
//  - quad-shuffle + LDS reduce, epilogue applies rs·(acc−mu·s1)+c+bias.
//  - R21: K-tile blocks (n0 in [512,1024)) also store the same bf16 values
//    transposed into kT[h][dg][j][8] for coalesced attn QK reads.
// by>=12 rows run prep units (tables, wfc, wproj/wcproj).
// ---------------------------------------------------------------------------
__global__ __launch_bounds__(256) void qkv_k(
    const float* __restrict__ x, const float* __restrict__ wattn,
    const float* __restrict__ ln1w, const float* __restrict__ ln1b,
    const float* __restrict__ wattnb, bf16_t* __restrict__ out,
    bf16_t* __restrict__ kT, PrepX X) {
  int tid = threadIdx.x;
  if (blockIdx.y >= 12) {
    prep_unit((blockIdx.y - 12) * gridDim.x + blockIdx.x, X, tid);
    return;
  }
  __shared__ float part[4][32][32];  // 16 KB
  __shared__ float rst[2][4][32];    // [sx|sxx][wave][row]  1 KB
  __shared__ float wst[2][4][32];    // [s1|c ][wave][col]  1 KB
  int lane = tid & 63, wave = tid >> 6;
  int m0 = blockIdx.y * 32, n0 = blockIdx.x * 32;
  int r16 = lane & 15, quad = lane >> 4;
  int k0 = wave * 128;  // K=512, kchunk=128

  f32x4 acc[2][2];
  f32x4 zero = {0.f, 0.f, 0.f, 0.f};
#pragma unroll
  for (int i = 0; i < 2; i++)
#pragma unroll
    for (int j = 0; j < 2; j++) acc[i][j] = zero;

  const float* Af = x + (size_t)(m0 + r16) * 512 + k0 + quad * 8;
  const float* Wf = wattn + (size_t)(n0 + r16) * 512 + k0 + quad * 8;
  const float* gp = ln1w + k0 + quad * 8;
  const float* bp = ln1b + k0 + quad * 8;

  float sx[2] = {0.f, 0.f}, sxx[2] = {0.f, 0.f};
  float s1[2] = {0.f, 0.f}, cc[2] = {0.f, 0.f};

  for (int kb0 = 0; kb0 < 128; kb0 += 64) {  // 2 k-steps hoisted
    uint4 araw[2][2][2], wraw[2][2][2];
#pragma unroll
    for (int u = 0; u < 2; u++) {
      int kb = kb0 + u * 32;
#pragma unroll
      for (int t = 0; t < 2; t++) {
        araw[u][t][0] = *(const uint4*)(Af + (size_t)t * 16 * 512 + kb);
        araw[u][t][1] = *(const uint4*)(Af + (size_t)t * 16 * 512 + kb + 4);
        wraw[u][t][0] = *(const uint4*)(Wf + (size_t)t * 16 * 512 + kb);
        wraw[u][t][1] = *(const uint4*)(Wf + (size_t)t * 16 * 512 + kb + 4);
      }
    }
#pragma unroll
    for (int u = 0; u < 2; u++) {
      int kb = kb0 + u * 32;
      f32x4 g0 = *(const f32x4*)(gp + kb), g1 = *(const f32x4*)(gp + kb + 4);
      f32x4 b0 = *(const f32x4*)(bp + kb), b1 = *(const f32x4*)(bp + kb + 4);
      bf16x8 af[2], bfr[2];
#pragma unroll
      for (int t = 0; t < 2; t++) {
        f32x4 a0 = *reinterpret_cast<const f32x4*>(&araw[u][t][0]);
        f32x4 a1 = *reinterpret_cast<const f32x4*>(&araw[u][t][1]);
        af[t][0] = (bf16_t)a0.x; af[t][1] = (bf16_t)a0.y;
        af[t][2] = (bf16_t)a0.z; af[t][3] = (bf16_t)a0.w;
        af[t][4] = (bf16_t)a1.x; af[t][5] = (bf16_t)a1.y;
        af[t][6] = (bf16_t)a1.z; af[t][7] = (bf16_t)a1.w;
        sx[t] += a0.x + a0.y + a0.z + a0.w + a1.x + a1.y + a1.z + a1.w;
        sxx[t] += a0.x * a0.x + a0.y * a0.y + a0.z * a0.z + a0.w * a0.w +
                  a1.x * a1.x + a1.y * a1.y + a1.z * a1.z + a1.w * a1.w;
        f32x4 w0 = *reinterpret_cast<const f32x4*>(&wraw[u][t][0]);
        f32x4 w1 = *reinterpret_cast<const f32x4*>(&wraw[u][t][1]);
        f32x4 p0 = w0 * g0, p1 = w1 * g1;
        bfr[t][0] = (bf16_t)p0.x; bfr[t][1] = (bf16_t)p0.y;
        bfr[t][2] = (bf16_t)p0.z; bfr[t][3] = (bf16_t)p0.w;
        bfr[t][4] = (bf16_t)p1.x; bfr[t][5] = (bf16_t)p1.y;
        bfr[t][6] = (bf16_t)p1.z; bfr[t][7] = (bf16_t)p1.w;
        s1[t] += p0.x + p0.y + p0.z + p0.w + p1.x + p1.y + p1.z + p1.w;
        cc[t] += w0.x * b0.x + w0.y * b0.y + w0.z * b0.z + w0.w * b0.w +
                 w1.x * b1.x + w1.y * b1.y + w1.z * b1.z + w1.w * b1.w;
      }
#pragma unroll
      for (int i = 0; i < 2; i++)
#pragma unroll
        for (int j = 0; j < 2; j++)
          acc[i][j] = __builtin_amdgcn_mfma_f32_16x16x32_bf16(af[i], bfr[j],
                                                              acc[i][j], 0, 0, 0);
    }
  }

  // quad-reduce stats (lanes r16, r16+16, r16+32, r16+48 → same value)
#pragma unroll
  for (int t = 0; t < 2; t++) {
    sx[t] += __shfl_xor(sx[t], 16, 64);  sx[t] += __shfl_xor(sx[t], 32, 64);
    sxx[t] += __shfl_xor(sxx[t], 16, 64); sxx[t] += __shfl_xor(sxx[t], 32, 64);
    s1[t] += __shfl_xor(s1[t], 16, 64);  s1[t] += __shfl_xor(s1[t], 32, 64);
    cc[t] += __shfl_xor(cc[t], 16, 64);  cc[t] += __shfl_xor(cc[t], 32, 64);
  }
  if (quad == 0) {
#pragma unroll
    for (int t = 0; t < 2; t++) {
      rst[0][wave][t * 16 + r16] = sx[t];
      rst[1][wave][t * 16 + r16] = sxx[t];
      wst[0][wave][t * 16 + r16] = s1[t];
      wst[1][wave][t * 16 + r16] = cc[t];
    }
  }
#pragma unroll
  for (int i = 0; i < 2; i++)
#pragma unroll
    for (int j = 0; j < 2; j++)
#pragma unroll
      for (int r = 0; r < 4; r++)
        part[wave][i * 16 + quad * 4 + r][j * 16 + r16] = acc[i][j][r];
  __syncthreads();

  int row = tid >> 3, c4 = (tid & 7) * 4;
  f32x4 v = *(const f32x4*)&part[0][row][c4];
  v += *(const f32x4*)&part[1][row][c4];
  v += *(const f32x4*)&part[2][row][c4];
  v += *(const f32x4*)&part[3][row][c4];
  float sxt = rst[0][0][row] + rst[0][1][row] + rst[0][2][row] + rst[0][3][row];
  float sxxt = rst[1][0][row] + rst[1][1][row] + rst[1][2][row] + rst[1][3][row];
  float mu = sxt * (1.0f / 512.0f);
  float var = sxxt * (1.0f / 512.0f) - mu * mu;
  float rs = rsqrtf(var + 1e-5f);
  int grow = m0 + row, gcol = n0 + c4;
  bf16x4v o;
#pragma unroll
  for (int t = 0; t < 4; t++) {
    int cl = c4 + t;
    float s1v = wst[0][0][cl] + wst[0][1][cl] + wst[0][2][cl] + wst[0][3][cl];
    float ccv = wst[1][0][cl] + wst[1][1][cl] + wst[1][2][cl] + wst[1][3][cl] +
                wattnb[n0 + cl];
    o[t] = (bf16_t)(rs * (v[t] - mu * s1v) + ccv);
  }
  *(bf16x4v*)(out + (size_t)grow * 1536 + gcol) = o;
  // R21: K tiles also write transposed copy for coalesced attn QK reads.
  // gcol in [512,1024): h=(gcol-512)>>6, d=(gcol-512)&63 (mult of 4, so the
  // 4 values stay inside one [j][8] block half: di in {0,4}).
  if (n0 >= 512 && n0 < 1024) {
    int kd = gcol - 512;
    int h = kd >> 6, d = kd & 63;
    int dg = d >> 3, di = d & 7;
    *(bf16x4v*)(kT + (((size_t)(h * 8 + dg) * TT) + grow) * 8 + di) = o;
  }
}

// ---------------------------------------------------------------------------
// Split-K NT GEMM, 32x32 tile (R10 measured-best). 4 waves each K/4;
// K-loop hoists 4 k-steps of loads before MFMA.
// MODE 1 (PROJ): A bf16, +bias +res ->f32
// MODE 2 (FC):   A=x1 f32; row stats computed FROM OWN A-FRAGMENTS
//                (qkv_k pattern); fused-LN; gelu ->bf16
// MODE 3 (CPROJ):A bf16, +bias +res ->f32 (d_out)
// ---------------------------------------------------------------------------
template <int MODE>
__global__ __launch_bounds__(256) void gemm_k(
    const void* __restrict__ Aptr, const bf16_t* __restrict__ Wb,
    const float* __restrict__ e2, const float* __restrict__ e3,
    const float* __restrict__ res, void* __restrict__ out, int N, int K) {
  constexpr bool AF32 = (MODE == 2);
  constexpr int AW = AF32 ? 2 : 1;
  __shared__ float part[4][32][32];
  __shared__ float rst[2][4][32];  // MODE 2 row stats (1 KB, else unused)
  int tid = threadIdx.x;
  int lane = tid & 63, wave = tid >> 6;
  int m0 = blockIdx.y * 32, n0 = blockIdx.x * 32;
  int r16 = lane & 15, quad = lane >> 4;
  int kchunk = K >> 2, k0 = wave * kchunk;

  f32x4 acc[2][2];
  f32x4 zero = {0.f, 0.f, 0.f, 0.f};
#pragma unroll
  for (int i = 0; i < 2; i++)
#pragma unroll
    for (int j = 0; j < 2; j++) acc[i][j] = zero;

  const float* Af = (const float*)Aptr + (size_t)(m0 + r16) * K + k0 + quad * 8;
  const bf16_t* Ab = (const bf16_t*)Aptr + (size_t)(m0 + r16) * K + k0 + quad * 8;
  const bf16_t* Wp = Wb + (size_t)(n0 + r16) * K + k0 + quad * 8;

  float sx[2] = {0.f, 0.f}, sxx[2] = {0.f, 0.f};

  for (int kb0 = 0; kb0 < kchunk; kb0 += 128) {
    uint4 araw[4][2][AW];
    uint4 braw[4][2];
#pragma unroll
    for (int u = 0; u < 4; u++) {
      int kb = kb0 + u * 32;
#pragma unroll
      for (int t = 0; t < 2; t++) {
        if (AF32) {
          araw[u][t][0] = *(const uint4*)(Af + (size_t)t * 16 * K + kb);
          araw[u][t][1] = *(const uint4*)(Af + (size_t)t * 16 * K + kb + 4);
        } else {
          araw[u][t][0] = *(const uint4*)(Ab + (size_t)t * 16 * K + kb);
        }
        braw[u][t] = *(const uint4*)(Wp + (size_t)t * 16 * K + kb);
      }
    }
#pragma unroll
    for (int u = 0; u < 4; u++) {
      bf16x8 af[2], bfr[2];
#pragma unroll
      for (int t = 0; t < 2; t++) {
        if (AF32) {
          f32x4 a = *reinterpret_cast<const f32x4*>(&araw[u][t][0]);
          f32x4 c = *reinterpret_cast<const f32x4*>(&araw[u][t][1]);
          af[t][0] = (bf16_t)a.x; af[t][1] = (bf16_t)a.y;
          af[t][2] = (bf16_t)a.z; af[t][3] = (bf16_t)a.w;
          af[t][4] = (bf16_t)c.x; af[t][5] = (bf16_t)c.y;
          af[t][6] = (bf16_t)c.z; af[t][7] = (bf16_t)c.w;
          sx[t] += a.x + a.y + a.z + a.w + c.x + c.y + c.z + c.w;
          sxx[t] += a.x * a.x + a.y * a.y + a.z * a.z + a.w * a.w +
                    c.x * c.x + c.y * c.y + c.z * c.z + c.w * c.w;
        } else {
          af[t] = *reinterpret_cast<const bf16x8*>(&araw[u][t][0]);
        }
        bfr[t] = *reinterpret_cast<const bf16x8*>(&braw[u][t]);
      }
#pragma unroll
      for (int i = 0; i < 2; i++)
#pragma unroll
        for (int j = 0; j < 2; j++)
          acc[i][j] = __builtin_amdgcn_mfma_f32_16x16x32_bf16(af[i], bfr[j],
                                                              acc[i][j], 0, 0, 0);
    }
  }

  if (MODE == 2) {  // quad-reduce row stats, store per-wave partials
#pragma unroll
    for (int t = 0; t < 2; t++) {
      sx[t] += __shfl_xor(sx[t], 16, 64);  sx[t] += __shfl_xor(sx[t], 32, 64);
      sxx[t] += __shfl_xor(sxx[t], 16, 64); sxx[t] += __shfl_xor(sxx[t], 32, 64);
    }
    if (quad == 0) {
#pragma unroll
      for (int t = 0; t < 2; t++) {
        rst[0][wave][t * 16 + r16] = sx[t];
        rst[1][wave][t * 16 + r16] = sxx[t];
      }
    }
  }
#pragma unroll
  for (int i = 0; i < 2; i++)
#pragma unroll
    for (int j = 0; j < 2; j++)
#pragma unroll
      for (int r = 0; r < 4; r++)
        part[wave][i * 16 + quad * 4 + r][j * 16 + r16] = acc[i][j][r];
  __syncthreads();

  int row = tid >> 3, c4 = (tid & 7) * 4;
  f32x4 v = *(const f32x4*)&part[0][row][c4];
  v += *(const f32x4*)&part[1][row][c4];
  v += *(const f32x4*)&part[2][row][c4];
  v += *(const f32x4*)&part[3][row][c4];
  int grow = m0 + row, gcol = n0 + c4;

  if (MODE == 2) {
    float S = rst[0][0][row] + rst[0][1][row] + rst[0][2][row] + rst[0][3][row];
    float Q = rst[1][0][row] + rst[1][1][row] + rst[1][2][row] + rst[1][3][row];
    float mu = S * (1.0f / 512.0f);
    float var = Q * (1.0f / 512.0f) - mu * mu;
    float rs = rsqrtf(var + 1e-5f);
    f32x4 s1v = *(const f32x4*)(e2 + gcol);
    f32x4 ccv = *(const f32x4*)(e3 + gcol);
    bf16x4v o;
#pragma unroll
    for (int t = 0; t < 4; t++) {
      float xg = rs * (v[t] - mu * s1v[t]) + ccv[t];
      xg = 0.5f * xg * (1.0f + erff(xg * 0.70710678118654752f));
      o[t] = (bf16_t)xg;
    }
    *(bf16x4v*)((bf16_t*)out + (size_t)grow * N + gcol) = o;
  } else {
    v += *(const f32x4*)(e2 + gcol);  // bias
    v += *(const f32x4*)(res + (size_t)grow * N + gcol);
    *(f32x4*)((float*)out + (size_t)grow * N + gcol) = v;
  }
}

// ---------------------------------------------------------------------------
// Attention R21: PAIRED query rows (i1=b, i2=383-b), grid (192,8), uint4-
// packed PV (R9 structure). ONE change: QK reads K from the transposed
// kT[h][dg][j][8] buffer — lane jl reads kT[h][dg][jl][:] so 64 lanes fetch
// consecutive 16B chunks (1KB coalesced/inst) instead of 3072B-stride
// scatter (64 cache lines/inst).
// ---------------------------------------------------------------------------
__global__ __launch_bounds__(256) void attn_k(
    const bf16_t* __restrict__ qkv, const bf16_t* __restrict__ kT,
    const int* __restrict__ bias_matrix,
    const float* __restrict__ attn_bias_emb, const float* __restrict__ ek_tab,
    const float* __restrict__ ev_tab, bf16_t* __restrict__ ybuf) {
  __shared__ uint4 psv[TT];            // {e1, bits(p1), e2, bits(p2)} per j
  __shared__ float qe1[EE][68], qe2[EE][68];
  __shared__ float evh[EE * 64];
  __shared__ float red[2][4 * 64];
  __shared__ float absh[EE];
  __shared__ float scr[2][4];

  int b = blockIdx.x, h = blockIdx.y;
  int i1 = b, i2 = (TT - 1) - b;  // i1 < i2, n1 <= n2
  int n1 = i1 + 1, n2 = i2 + 1;
  int tid = threadIdx.x, lane = tid & 63, wave = tid >> 6;

  if (tid < EE) absh[tid] = attn_bias_emb[tid * HH + h];
  for (int idx = tid; idx < EE * 64; idx += 256) {
    int e = idx >> 6, d = idx & 63;
    float q1 = (float)qkv[(size_t)i1 * 1536 + h * 64 + d];
    float q2 = (float)qkv[(size_t)i2 * 1536 + h * 64 + d];
    float ek = ek_tab[e * 512 + h * 64 + d];
    qe1[e][d] = q1 * ek;
    qe2[e][d] = q2 * ek;
    evh[idx] = ev_tab[e * 512 + h * 64 + d];
  }
  __syncthreads();

  float ls1 = 0.0f, ls2 = 0.0f;
  const int* bm1 = bias_matrix + (size_t)i1 * TT;
  const int* bm2 = bias_matrix + (size_t)i2 * TT;
  const uint4* kTh = (const uint4*)(kT + (size_t)h * 8 * TT * 8);
  for (int jl = tid; jl < n2; jl += 256) {
    int e2 = bm2[jl];
    uint4 kr[8];
#pragma unroll
    for (int dg = 0; dg < 8; dg++) kr[dg] = kTh[dg * TT + jl];
    float a2 = 0.f;
#pragma unroll
    for (int dg = 0; dg < 8; dg++) {
      bf16x8 kv = *reinterpret_cast<const bf16x8*>(&kr[dg]);
      f32x4 qa = *(const f32x4*)&qe2[e2][dg * 8];
      f32x4 qb = *(const f32x4*)&qe2[e2][dg * 8 + 4];
      a2 += (float)kv[0] * qa.x + (float)kv[1] * qa.y + (float)kv[2] * qa.z +
            (float)kv[3] * qa.w + (float)kv[4] * qb.x + (float)kv[5] * qb.y +
            (float)kv[6] * qb.z + (float)kv[7] * qb.w;
    }
    float p2 = __expf(a2 * 0.125f + absh[e2]);
    uint4 pk;
    pk.x = 0u; pk.y = 0u;
    pk.z = (unsigned)e2; pk.w = __float_as_uint(p2);
    ls2 += p2;
    if (jl < n1) {
      int e1 = bm1[jl];
      float a1 = 0.f;
#pragma unroll
      for (int dg = 0; dg < 8; dg++) {
        bf16x8 kv = *reinterpret_cast<const bf16x8*>(&kr[dg]);
        f32x4 qa = *(const f32x4*)&qe1[e1][dg * 8];
        f32x4 qb = *(const f32x4*)&qe1[e1][dg * 8 + 4];
        a1 += (float)kv[0] * qa.x + (float)kv[1] * qa.y + (float)kv[2] * qa.z +
              (float)kv[3] * qa.w + (float)kv[4] * qb.x + (float)kv[5] * qb.y +
              (float)kv[6] * qb.z + (float)kv[7] * qb.w;
      }
      float p1 = __expf(a1 * 0.125f + absh[e1]);
      pk.x = (unsigned)e1;
      pk.y = __float_as_uint(p1);
      ls1 += p1;
    }
    psv[jl] = pk;
  }
  ls1 = wave_reduce_sum(ls1);
  ls2 = wave_reduce_sum(ls2);
  if (lane == 0) { scr[0][wave] = ls1; scr[1][wave] = ls2; }
  __syncthreads();
  float inv1 = 1.0f / (scr[0][0] + scr[0][1] + scr[0][2] + scr[0][3]);
  float inv2 = 1.0f / (scr[1][0] + scr[1][1] + scr[1][2] + scr[1][3]);

  const bf16_t* vb = qkv + 1024 + h * 64 + lane;  // lane's d column of v rows
  float acc1 = 0.0f, acc2 = 0.0f;
  int j = wave;
  // shared region: both rows, 4-wide, one b128 read per j
  for (; j + 12 < n1; j += 16) {
    float v0 = (float)vb[(size_t)j * 1536];
    float v1 = (float)vb[(size_t)(j + 4) * 1536];
    float v2 = (float)vb[(size_t)(j + 8) * 1536];
    float v3 = (float)vb[(size_t)(j + 12) * 1536];
    uint4 q0 = psv[j], q1 = psv[j + 4], q2 = psv[j + 8], q3 = psv[j + 12];
    acc2 = fmaf(__uint_as_float(q0.w) * v0, evh[q0.z * 64 + lane], acc2);
    acc2 = fmaf(__uint_as_float(q1.w) * v1, evh[q1.z * 64 + lane], acc2);
    acc2 = fmaf(__uint_as_float(q2.w) * v2, evh[q2.z * 64 + lane], acc2);
    acc2 = fmaf(__uint_as_float(q3.w) * v3, evh[q3.z * 64 + lane], acc2);
    acc1 = fmaf(__uint_as_float(q0.y) * v0, evh[q0.x * 64 + lane], acc1);
    acc1 = fmaf(__uint_as_float(q1.y) * v1, evh[q1.x * 64 + lane], acc1);
    acc1 = fmaf(__uint_as_float(q2.y) * v2, evh[q2.x * 64 + lane], acc1);
    acc1 = fmaf(__uint_as_float(q3.y) * v3, evh[q3.x * 64 + lane], acc1);
  }
  for (; j < n1; j += 4) {
    float v0 = (float)vb[(size_t)j * 1536];
    uint4 q0 = psv[j];
    acc2 = fmaf(__uint_as_float(q0.w) * v0, evh[q0.z * 64 + lane], acc2);
    acc1 = fmaf(__uint_as_float(q0.y) * v0, evh[q0.x * 64 + lane], acc1);
  }
  // tail region: row 2 only, 4-wide, b64 reads of the row-2 halves
  const uint2* ps2h = (const uint2*)((const char*)psv + 8);  // psv[j].zw
  for (; j + 12 < n2; j += 16) {
    float v0 = (float)vb[(size_t)j * 1536];
    float v1 = (float)vb[(size_t)(j + 4) * 1536];
    float v2 = (float)vb[(size_t)(j + 8) * 1536];
    float v3 = (float)vb[(size_t)(j + 12) * 1536];
    uint2 c0 = ps2h[j * 2], c1 = ps2h[(j + 4) * 2];
    uint2 c2 = ps2h[(j + 8) * 2], c3 = ps2h[(j + 12) * 2];
    acc2 = fmaf(__uint_as_float(c0.y) * v0, evh[c0.x * 64 + lane], acc2);
    acc2 = fmaf(__uint_as_float(c1.y) * v1, evh[c1.x * 64 + lane], acc2);
    acc2 = fmaf(__uint_as_float(c2.y) * v2, evh[c2.x * 64 + lane], acc2);
    acc2 = fmaf(__uint_as_float(c3.y) * v3, evh[c3.x * 64 + lane], acc2);
  }
  for (; j < n2; j += 4) {
    float v0 = (float)vb[(size_t)j * 1536];
    uint2 c0 = ps2h[j * 2];
    acc2 = fmaf(__uint_as_float(c0.y) * v0, evh[c0.x * 64 + lane], acc2);
  }
  red[0][wave * 64 + lane] = acc1;
  red[1][wave * 64 + lane] = acc2;
  __syncthreads();
  if (tid < 64) {
    float y =
        (red[0][tid] + red[0][64 + tid] + red[0][128 + tid] + red[0][192 + tid]) *
        inv1;
    ybuf[(size_t)i1 * CC + h * 64 + tid] = (bf16_t)y;
  } else if (tid < 128) {
    int t = tid - 64;
    float y =
        (red[1][t] + red[1][64 + t] + red[1][128 + t] + red[1][192 + t]) * inv2;
    ybuf[(size_t)i2 * CC + h * 64 + t] = (bf16_t)y;
  }
}

// ---------------------------------------------------------------------------
extern "C" void kernel_launch(void* const* d_in, const int* in_sizes, int n_in,
                              void* d_out, int out_size, void* d_ws,
                              size_t ws_size, hipStream_t stream) {
  const float* x = (const float*)d_in[0];
  const int* bias_mat = (const int*)d_in[1];

  char* wp = (char*)d_ws;
  float* ektab = (float*)wp;  wp += 16 * 512 * 4;
  float* evtab = (float*)wp;  wp += 16 * 512 * 4;
  float* s1f = (float*)wp;    wp += 2048 * 4;
  float* cf = (float*)wp;     wp += 2048 * 4;
  float* x1 = (float*)wp;     wp += 384 * 512 * 4;
  bf16_t* wfc_bf = (bf16_t*)wp;    wp += 2048 * 512 * 2;
  bf16_t* wproj_bf = (bf16_t*)wp;  wp += 512 * 512 * 2;
  bf16_t* wcproj_bf = (bf16_t*)wp; wp += 512 * 2048 * 2;
  bf16_t* qkv = (bf16_t*)wp;  wp += 384 * 1536 * 2;
  bf16_t* kT = (bf16_t*)wp;   wp += 8 * 64 * 384 * 2;  // [h][dg][j][8]
  bf16_t* ybuf = (bf16_t*)wp; wp += 384 * 512 * 2;
  bf16_t* gbuf = (bf16_t*)wp; wp += 384 * 2048 * 2;

  PrepX X;
  X.eemb = (const float*)d_in[9];
  X.wekw = (const float*)d_in[10];
  X.wekb = (const float*)d_in[11];
  X.wevw = (const float*)d_in[12];
  X.wevb = (const float*)d_in[13];
  X.ln2w = (const float*)d_in[14];
  X.ln2b = (const float*)d_in[15];
  X.cfcw = (const float*)d_in[16];
  X.cfcb = (const float*)d_in[17];
  X.wproj = (const float*)d_in[6];
  X.wcproj = (const float*)d_in[18];
  X.ektab = ektab; X.evtab = evtab; X.s1f = s1f; X.cf = cf;
  X.wfc_bf = wfc_bf; X.wproj_bf = wproj_bf; X.wcproj_bf = wcproj_bf;

  // 1) self-contained qkv (576 gemm tiles, rows 0-11; K tiles also fill kT)
  //    + 1088 hidden prep units (rows 12-34)
  qkv_k<<<dim3(48, 35), 256, 0, stream>>>(
      x, (const float*)d_in[4], (const float*)d_in[2], (const float*)d_in[3],
      (const float*)d_in[5], qkv, kT, X);
  // 2) attention (paired rows (b, 383-b), 192x8, coalesced kT QK reads)
  attn_k<<<dim3(TT / 2, HH), 256, 0, stream>>>(qkv, kT, bias_mat,
                                               (const float*)d_in[8], ektab,
                                               evtab, ybuf);
  // 3) x1 = x + y @ wproj^T + b
  gemm_k<1><<<dim3(16, 12), 256, 0, stream>>>(
      ybuf, wproj_bf, (const float*)d_in[7], nullptr, x, x1, 512, 512);
  // 4) g = gelu(LN2(x1) @ cfc^T + b)  (row stats from own A reads)
  gemm_k<2><<<dim3(64, 12), 256, 0, stream>>>(x1, wfc_bf, s1f, cf, nullptr,
                                              gbuf, 2048, 512);
  // 5) out = x1 + g @ cproj^T + b
  gemm_k<3><<<dim3(16, 12), 256, 0, stream>>>(
      gbuf, wcproj_bf, (const float*)d_in[19], nullptr, x1, d_out, 512, 2048);
}

// Round 11
// 161.943 us; speedup vs baseline: 2.3072x; 1.0286x over previous
//
#include <hip/hip_runtime.h>
#include <math.h>

// Problem constants: B=1, T=384, C=512, H=8, D=64, E=16. Inputs/outputs f32.
// R22 = R10 base (kT transposed-K QK reads — best measured, 166.6us) +
// 8-DEEP v-load batching in PV: each outer iteration issues 8 independent
// v loads (j..j+28) before consuming them in two 4-wide psv groups.
// Rationale: PV is the dominant modeled stall (96 iters/thread x ~250cy
// L2 latency, only 4 loads in flight; 6 waves/SIMD can't hide it).
// psv reads stay 4-wide so live uint4 state doesn't double: VGPR ~60,
// below the 64-VGPR occupancy cliff (R8 lesson).
// Kept: 2-row paired attn, uint4-packed PV, stats-fold in gemm<2>,
// no atomics, no cross-block sync (R7 lesson), 5 dispatches.
#define TT 384
#define CC 512
#define HH 8
#define EE 16

typedef __bf16 bf16_t;
typedef __bf16 bf16x8 __attribute__((ext_vector_type(8)));
typedef __bf16 bf16x4v __attribute__((ext_vector_type(4)));
typedef float f32x4 __attribute__((ext_vector_type(4)));

__device__ __forceinline__ float wave_reduce_sum(float v) {
#pragma unroll
  for (int off = 32; off >= 1; off >>= 1) v += __shfl_xor(v, off, 64);
  return v;
}

// ---------------------------------------------------------------------------
// wrow_unit: one LN-folded weight row: W'[n]=g∘W[n] (bf16), s1[n]=Σ W'[n,k],
// c[n] = Σ b_k W[n,k] + extra
// ---------------------------------------------------------------------------
__device__ __forceinline__ void wrow_unit(const float* __restrict__ wr,
                                          const float* __restrict__ g,
                                          const float* __restrict__ bb,
                                          float extra_c, bf16_t* __restrict__ orow,
                                          float* __restrict__ s1p,
                                          float* __restrict__ cp, int lane) {
  const float* p = wr + lane * 8;
  f32x4 w0 = *(const f32x4*)p, w1 = *(const f32x4*)(p + 4);
  f32x4 g0 = *(const f32x4*)(g + lane * 8), g1 = *(const f32x4*)(g + lane * 8 + 4);
  f32x4 b0 = *(const f32x4*)(bb + lane * 8), b1 = *(const f32x4*)(bb + lane * 8 + 4);
  f32x4 p0 = w0 * g0, p1 = w1 * g1;
  bf16x8 o;
  o[0] = (bf16_t)p0.x; o[1] = (bf16_t)p0.y; o[2] = (bf16_t)p0.z; o[3] = (bf16_t)p0.w;
  o[4] = (bf16_t)p1.x; o[5] = (bf16_t)p1.y; o[6] = (bf16_t)p1.z; o[7] = (bf16_t)p1.w;
  *(bf16x8*)(orow + lane * 8) = o;
  float s1 = p0.x + p0.y + p0.z + p0.w + p1.x + p1.y + p1.z + p1.w;
  float c = w0.x * b0.x + w0.y * b0.y + w0.z * b0.z + w0.w * b0.w +
            w1.x * b1.x + w1.y * b1.y + w1.z * b1.z + w1.w * b1.w;
  s1 = wave_reduce_sum(s1);
  c = wave_reduce_sum(c);
  if (lane == 0) { *s1p = s1; *cp = c + extra_c; }
}

// ---------------------------------------------------------------------------
// Prep bundle (hidden in qkv dispatch rows by>=12; 1088 units):
// 0-255 edge tables; 256-767 wfc rows; 768-1023 wcproj conv; 1024-1087
// wproj conv.
// ---------------------------------------------------------------------------
struct PrepX {
  const float *eemb, *wekw, *wekb, *wevw, *wevb;
  const float *ln2w, *ln2b, *cfcw, *cfcb;
  const float *wproj, *wcproj;
  float *ektab, *evtab, *s1f, *cf;
  bf16_t *wfc_bf, *wproj_bf, *wcproj_bf;
};

__device__ void prep_unit(int u, const PrepX& X, int tid) {
  int lane = tid & 63, wave = tid >> 6;
  if (u < 256) {
    int wid = u * 4 + wave;
    int gbase = wid * 16;
    int table = gbase >> 13;
    int e = (gbase >> 9) & 15;
    int c0 = gbase & 511;
    const float* er = X.eemb + e * 512 + lane * 8;
    f32x4 ea = *(const f32x4*)er;
    f32x4 eb = *(const f32x4*)(er + 4);
    const float* wbase = table ? X.wevw : X.wekw;
    const float* bbase = table ? X.wevb : X.wekb;
    float* obase = (table ? X.evtab : X.ektab) + e * 512;
#pragma unroll
    for (int o = 0; o < 16; o++) {
      int c = c0 + o;
      const float* wr = wbase + (size_t)c * 512 + lane * 8;
      f32x4 wa = *(const f32x4*)wr;
      f32x4 wb = *(const f32x4*)(wr + 4);
      float acc = ea.x * wa.x + ea.y * wa.y + ea.z * wa.z + ea.w * wa.w +
                  eb.x * wb.x + eb.y * wb.y + eb.z * wb.z + eb.w * wb.w;
      acc = wave_reduce_sum(acc);
      if (lane == 0) obase[c] = acc + bbase[c];
    }
  } else if (u < 768) {
    int n = (u - 256) * 4 + wave;  // 0..2047
    wrow_unit(X.cfcw + (size_t)n * 512, X.ln2w, X.ln2b, X.cfcb[n],
              X.wfc_bf + (size_t)n * 512, X.s1f + n, X.cf + n, lane);
  } else if (u < 1024) {
    int base = (u - 768) * 1024;  // wcproj: 262144 f32x4
    for (int t = tid; t < 1024; t += 256) {
      f32x4 a = *((const f32x4*)X.wcproj + base + t);
      bf16x4v o;
      o[0] = (bf16_t)a.x; o[1] = (bf16_t)a.y; o[2] = (bf16_t)a.z; o[3] = (bf16_t)a.w;
      *((bf16x4v*)X.wcproj_bf + base + t) = o;
    }
  } else if (u < 1088) {
    int base = (u - 1024) * 1024;  // wproj: 65536 f32x4
    for (int t = tid; t < 1024; t += 256) {
      f32x4 a = *((const f32x4*)X.wproj + base + t);
      bf16x4v o;
      o[0] = (bf16_t)a.x; o[1] = (bf16_t)a.y; o[2] = (bf16_t)a.z; o[3] = (bf16_t)a.w;
      *((bf16x4v*)X.wproj_bf + base + t) = o;
    }
  }
}

// ---------------------------------------------------------------------------
// qkv_k: SELF-CONTAINED qkv GEMM — no pre-pass dependency. Each 32x32 tile:
//  - loads raw f32 x and wattn, folds g∘W inline into the B fragment
//  - accumulates per-wave partials of row Σx/Σx² and col Σ(gW)/Σ(bW)
//    alongside the MFMA loop (operands already in registers)
//  - quad-shuffle + LDS reduce, epilogue applies rs·(acc−mu·s1)+c+bias.
//  - K-tile blocks (n0 in [512,1024)) also store the same bf16 values
//    transposed into kT[h][dg][j][8] for coalesced attn QK reads.
// by>=12 rows run prep units (tables, wfc, wproj/wcproj).
// ---------------------------------------------------------------------------
__global__ __launch_bounds__(256) void qkv_k(
    const float* __restrict__ x, const float* __restrict__ wattn,
    const float* __restrict__ ln1w, const float* __restrict__ ln1b,
    const float* __restrict__ wattnb, bf16_t* __restrict__ out,
    bf16_t* __restrict__ kT, PrepX X) {
  int tid = threadIdx.x;
  if (blockIdx.y >= 12) {
    prep_unit((blockIdx.y - 12) * gridDim.x + blockIdx.x, X, tid);
    return;
  }
  __shared__ float part[4][32][32];  // 16 KB
  __shared__ float rst[2][4][32];    // [sx|sxx][wave][row]  1 KB
  __shared__ float wst[2][4][32];    // [s1|c ][wave][col]  1 KB
  int lane = tid & 63, wave = tid >> 6;
  int m0 = blockIdx.y * 32, n0 = blockIdx.x * 32;
  int r16 = lane & 15, quad = lane >> 4;
  int k0 = wave * 128;  // K=512, kchunk=128

  f32x4 acc[2][2];
  f32x4 zero = {0.f, 0.f, 0.f, 0.f};
#pragma unroll
  for (int i = 0; i < 2; i++)
#pragma unroll
    for (int j = 0; j < 2; j++) acc[i][j] = zero;

  const float* Af = x + (size_t)(m0 + r16) * 512 + k0 + quad * 8;
  const float* Wf = wattn + (size_t)(n0 + r16) * 512 + k0 + quad * 8;
  const float* gp = ln1w + k0 + quad * 8;
  const float* bp = ln1b + k0 + quad * 8;

  float sx[2] = {0.f, 0.f}, sxx[2] = {0.f, 0.f};
  float s1[2] = {0.f, 0.f}, cc[2] = {0.f, 0.f};

  for (int kb0 = 0; kb0 < 128; kb0 += 64) {  // 2 k-steps hoisted
    uint4 araw[2][2][2], wraw[2][2][2];
#pragma unroll
    for (int u = 0; u < 2; u++) {
      int kb = kb0 + u * 32;
#pragma unroll
      for (int t = 0; t < 2; t++) {
        araw[u][t][0] = *(const uint4*)(Af + (size_t)t * 16 * 512 + kb);
        araw[u][t][1] = *(const uint4*)(Af + (size_t)t * 16 * 512 + kb + 4);
        wraw[u][t][0] = *(const uint4*)(Wf + (size_t)t * 16 * 512 + kb);
        wraw[u][t][1] = *(const uint4*)(Wf + (size_t)t * 16 * 512 + kb + 4);
      }
    }
#pragma unroll
    for (int u = 0; u < 2; u++) {
      int kb = kb0 + u * 32;
      f32x4 g0 = *(const f32x4*)(gp + kb), g1 = *(const f32x4*)(gp + kb + 4);
      f32x4 b0 = *(const f32x4*)(bp + kb), b1 = *(const f32x4*)(bp + kb + 4);
      bf16x8 af[2], bfr[2];
#pragma unroll
      for (int t = 0; t < 2; t++) {
        f32x4 a0 = *reinterpret_cast<const f32x4*>(&araw[u][t][0]);
        f32x4 a1 = *reinterpret_cast<const f32x4*>(&araw[u][t][1]);
        af[t][0] = (bf16_t)a0.x; af[t][1] = (bf16_t)a0.y;
        af[t][2] = (bf16_t)a0.z; af[t][3] = (bf16_t)a0.w;
        af[t][4] = (bf16_t)a1.x; af[t][5] = (bf16_t)a1.y;
        af[t][6] = (bf16_t)a1.z; af[t][7] = (bf16_t)a1.w;
        sx[t] += a0.x + a0.y + a0.z + a0.w + a1.x + a1.y + a1.z + a1.w;
        sxx[t] += a0.x * a0.x + a0.y * a0.y + a0.z * a0.z + a0.w * a0.w +
                  a1.x * a1.x + a1.y * a1.y + a1.z * a1.z + a1.w * a1.w;
        f32x4 w0 = *reinterpret_cast<const f32x4*>(&wraw[u][t][0]);
        f32x4 w1 = *reinterpret_cast<const f32x4*>(&wraw[u][t][1]);
        f32x4 p0 = w0 * g0, p1 = w1 * g1;
        bfr[t][0] = (bf16_t)p0.x; bfr[t][1] = (bf16_t)p0.y;
        bfr[t][2] = (bf16_t)p0.z; bfr[t][3] = (bf16_t)p0.w;
        bfr[t][4] = (bf16_t)p1.x; bfr[t][5] = (bf16_t)p1.y;
        bfr[t][6] = (bf16_t)p1.z; bfr[t][7] = (bf16_t)p1.w;
        s1[t] += p0.x + p0.y + p0.z + p0.w + p1.x + p1.y + p1.z + p1.w;
        cc[t] += w0.x * b0.x + w0.y * b0.y + w0.z * b0.z + w0.w * b0.w +
                 w1.x * b1.x + w1.y * b1.y + w1.z * b1.z + w1.w * b1.w;
      }
#pragma unroll
      for (int i = 0; i < 2; i++)
#pragma unroll
        for (int j = 0; j < 2; j++)
          acc[i][j] = __builtin_amdgcn_mfma_f32_16x16x32_bf16(af[i], bfr[j],
                                                              acc[i][j], 0, 0, 0);
    }
  }

  // quad-reduce stats (lanes r16, r16+16, r16+32, r16+48 → same value)
#pragma unroll
  for (int t = 0; t < 2; t++) {
    sx[t] += __shfl_xor(sx[t], 16, 64);  sx[t] += __shfl_xor(sx[t], 32, 64);
    sxx[t] += __shfl_xor(sxx[t], 16, 64); sxx[t] += __shfl_xor(sxx[t], 32, 64);
    s1[t] += __shfl_xor(s1[t], 16, 64);  s1[t] += __shfl_xor(s1[t], 32, 64);
    cc[t] += __shfl_xor(cc[t], 16, 64);  cc[t] += __shfl_xor(cc[t], 32, 64);
  }
  if (quad == 0) {
#pragma unroll
    for (int t = 0; t < 2; t++) {
      rst[0][wave][t * 16 + r16] = sx[t];
      rst[1][wave][t * 16 + r16] = sxx[t];
      wst[0][wave][t * 16 + r16] = s1[t];
      wst[1][wave][t * 16 + r16] = cc[t];
    }
  }
#pragma unroll
  for (int i = 0; i < 2; i++)
#pragma unroll
    for (int j = 0; j < 2; j++)
#pragma unroll
      for (int r = 0; r < 4; r++)
        part[wave][i * 16 + quad * 4 + r][j * 16 + r16] = acc[i][j][r];
  __syncthreads();

  int row = tid >> 3, c4 = (tid & 7) * 4;
  f32x4 v = *(const f32x4*)&part[0][row][c4];
  v += *(const f32x4*)&part[1][row][c4];
  v += *(const f32x4*)&part[2][row][c4];
  v += *(const f32x4*)&part[3][row][c4];
  float sxt = rst[0][0][row] + rst[0][1][row] + rst[0][2][row] + rst[0][3][row];
  float sxxt = rst[1][0][row] + rst[1][1][row] + rst[1][2][row] + rst[1][3][row];
  float mu = sxt * (1.0f / 512.0f);
  float var = sxxt * (1.0f / 512.0f) - mu * mu;
  float rs = rsqrtf(var + 1e-5f);
  int grow = m0 + row, gcol = n0 + c4;
  bf16x4v o;
#pragma unroll
  for (int t = 0; t < 4; t++) {
    int cl = c4 + t;
    float s1v = wst[0][0][cl] + wst[0][1][cl] + wst[0][2][cl] + wst[0][3][cl];
    float ccv = wst[1][0][cl] + wst[1][1][cl] + wst[1][2][cl] + wst[1][3][cl] +
                wattnb[n0 + cl];
    o[t] = (bf16_t)(rs * (v[t] - mu * s1v) + ccv);
  }
  *(bf16x4v*)(out + (size_t)grow * 1536 + gcol) = o;
  // K tiles also write transposed copy for coalesced attn QK reads.
  if (n0 >= 512 && n0 < 1024) {
    int kd = gcol - 512;
    int h = kd >> 6, d = kd & 63;
    int dg = d >> 3, di = d & 7;
    *(bf16x4v*)(kT + (((size_t)(h * 8 + dg) * TT) + grow) * 8 + di) = o;
  }
}

// ---------------------------------------------------------------------------
// Split-K NT GEMM, 32x32 tile (R10 measured-best). 4 waves each K/4;
// K-loop hoists 4 k-steps of loads before MFMA.
// MODE 1 (PROJ): A bf16, +bias +res ->f32
// MODE 2 (FC):   A=x1 f32; row stats computed FROM OWN A-FRAGMENTS
//                (qkv_k pattern); fused-LN; gelu ->bf16
// MODE 3 (CPROJ):A bf16, +bias +res ->f32 (d_out)
// ---------------------------------------------------------------------------
template <int MODE>
__global__ __launch_bounds__(256) void gemm_k(
    const void* __restrict__ Aptr, const bf16_t* __restrict__ Wb,
    const float* __restrict__ e2, const float* __restrict__ e3,
    const float* __restrict__ res, void* __restrict__ out, int N, int K) {
  constexpr bool AF32 = (MODE == 2);
  constexpr int AW = AF32 ? 2 : 1;
  __shared__ float part[4][32][32];
  __shared__ float rst[2][4][32];  // MODE 2 row stats (1 KB, else unused)
  int tid = threadIdx.x;
  int lane = tid & 63, wave = tid >> 6;
  int m0 = blockIdx.y * 32, n0 = blockIdx.x * 32;
  int r16 = lane & 15, quad = lane >> 4;
  int kchunk = K >> 2, k0 = wave * kchunk;

  f32x4 acc[2][2];
  f32x4 zero = {0.f, 0.f, 0.f, 0.f};
#pragma unroll
  for (int i = 0; i < 2; i++)
#pragma unroll
    for (int j = 0; j < 2; j++) acc[i][j] = zero;

  const float* Af = (const float*)Aptr + (size_t)(m0 + r16) * K + k0 + quad * 8;
  const bf16_t* Ab = (const bf16_t*)Aptr + (size_t)(m0 + r16) * K + k0 + quad * 8;
  const bf16_t* Wp = Wb + (size_t)(n0 + r16) * K + k0 + quad * 8;

  float sx[2] = {0.f, 0.f}, sxx[2] = {0.f, 0.f};

  for (int kb0 = 0; kb0 < kchunk; kb0 += 128) {
    uint4 araw[4][2][AW];
    uint4 braw[4][2];
#pragma unroll
    for (int u = 0; u < 4; u++) {
      int kb = kb0 + u * 32;
#pragma unroll
      for (int t = 0; t < 2; t++) {
        if (AF32) {
          araw[u][t][0] = *(const uint4*)(Af + (size_t)t * 16 * K + kb);
          araw[u][t][1] = *(const uint4*)(Af + (size_t)t * 16 * K + kb + 4);
        } else {
          araw[u][t][0] = *(const uint4*)(Ab + (size_t)t * 16 * K + kb);
        }
        braw[u][t] = *(const uint4*)(Wp + (size_t)t * 16 * K + kb);
      }
    }
#pragma unroll
    for (int u = 0; u < 4; u++) {
      bf16x8 af[2], bfr[2];
#pragma unroll
      for (int t = 0; t < 2; t++) {
        if (AF32) {
          f32x4 a = *reinterpret_cast<const f32x4*>(&araw[u][t][0]);
          f32x4 c = *reinterpret_cast<const f32x4*>(&araw[u][t][1]);
          af[t][0] = (bf16_t)a.x; af[t][1] = (bf16_t)a.y;
          af[t][2] = (bf16_t)a.z; af[t][3] = (bf16_t)a.w;
          af[t][4] = (bf16_t)c.x; af[t][5] = (bf16_t)c.y;
          af[t][6] = (bf16_t)c.z; af[t][7] = (bf16_t)c.w;
          sx[t] += a.x + a.y + a.z + a.w + c.x + c.y + c.z + c.w;
          sxx[t] += a.x * a.x + a.y * a.y + a.z * a.z + a.w * a.w +
                    c.x * c.x + c.y * c.y + c.z * c.z + c.w * c.w;
        } else {
          af[t] = *reinterpret_cast<const bf16x8*>(&araw[u][t][0]);
        }
        bfr[t] = *reinterpret_cast<const bf16x8*>(&braw[u][t]);
      }
#pragma unroll
      for (int i = 0; i < 2; i++)
#pragma unroll
        for (int j = 0; j < 2; j++)
          acc[i][j] = __builtin_amdgcn_mfma_f32_16x16x32_bf16(af[i], bfr[j],
                                                              acc[i][j], 0, 0, 0);
    }
  }

  if (MODE == 2) {  // quad-reduce row stats, store per-wave partials
#pragma unroll
    for (int t = 0; t < 2; t++) {
      sx[t] += __shfl_xor(sx[t], 16, 64);  sx[t] += __shfl_xor(sx[t], 32, 64);
      sxx[t] += __shfl_xor(sxx[t], 16, 64); sxx[t] += __shfl_xor(sxx[t], 32, 64);
    }
    if (quad == 0) {
#pragma unroll
      for (int t = 0; t < 2; t++) {
        rst[0][wave][t * 16 + r16] = sx[t];
        rst[1][wave][t * 16 + r16] = sxx[t];
      }
    }
  }
#pragma unroll
  for (int i = 0; i < 2; i++)
#pragma unroll
    for (int j = 0; j < 2; j++)
#pragma unroll
      for (int r = 0; r < 4; r++)
        part[wave][i * 16 + quad * 4 + r][j * 16 + r16] = acc[i][j][r];
  __syncthreads();

  int row = tid >> 3, c4 = (tid & 7) * 4;
  f32x4 v = *(const f32x4*)&part[0][row][c4];
  v += *(const f32x4*)&part[1][row][c4];
  v += *(const f32x4*)&part[2][row][c4];
  v += *(const f32x4*)&part[3][row][c4];
  int grow = m0 + row, gcol = n0 + c4;

  if (MODE == 2) {
    float S = rst[0][0][row] + rst[0][1][row] + rst[0][2][row] + rst[0][3][row];
    float Q = rst[1][0][row] + rst[1][1][row] + rst[1][2][row] + rst[1][3][row];
    float mu = S * (1.0f / 512.0f);
    float var = Q * (1.0f / 512.0f) - mu * mu;
    float rs = rsqrtf(var + 1e-5f);
    f32x4 s1v = *(const f32x4*)(e2 + gcol);
    f32x4 ccv = *(const f32x4*)(e3 + gcol);
    bf16x4v o;
#pragma unroll
    for (int t = 0; t < 4; t++) {
      float xg = rs * (v[t] - mu * s1v[t]) + ccv[t];
      xg = 0.5f * xg * (1.0f + erff(xg * 0.70710678118654752f));
      o[t] = (bf16_t)xg;
    }
    *(bf16x4v*)((bf16_t*)out + (size_t)grow * N + gcol) = o;
  } else {
    v += *(const f32x4*)(e2 + gcol);  // bias
    v += *(const f32x4*)(res + (size_t)grow * N + gcol);
    *(f32x4*)((float*)out + (size_t)grow * N + gcol) = v;
  }
}

// ---------------------------------------------------------------------------
// Attention R22: PAIRED query rows (i1=b, i2=383-b), grid (192,8), kT
// coalesced QK reads (R10). PV change: 8 v-loads issued per outer iteration
// (j..j+28), consumed in two 4-wide psv groups — doubles global loads in
// flight without doubling live uint4 state (VGPR stays < 64 cliff).
// ---------------------------------------------------------------------------
__global__ __launch_bounds__(256) void attn_k(
    const bf16_t* __restrict__ qkv, const bf16_t* __restrict__ kT,
    const int* __restrict__ bias_matrix,
    const float* __restrict__ attn_bias_emb, const float* __restrict__ ek_tab,
    const float* __restrict__ ev_tab, bf16_t* __restrict__ ybuf) {
  __shared__ uint4 psv[TT];            // {e1, bits(p1), e2, bits(p2)} per j
  __shared__ float qe1[EE][68], qe2[EE][68];
  __shared__ float evh[EE * 64];
  __shared__ float red[2][4 * 64];
  __shared__ float absh[EE];
  __shared__ float scr[2][4];

  int b = blockIdx.x, h = blockIdx.y;
  int i1 = b, i2 = (TT - 1) - b;  // i1 < i2, n1 <= n2
  int n1 = i1 + 1, n2 = i2 + 1;
  int tid = threadIdx.x, lane = tid & 63, wave = tid >> 6;

  if (tid < EE) absh[tid] = attn_bias_emb[tid * HH + h];
  for (int idx = tid; idx < EE * 64; idx += 256) {
    int e = idx >> 6, d = idx & 63;
    float q1 = (float)qkv[(size_t)i1 * 1536 + h * 64 + d];
    float q2 = (float)qkv[(size_t)i2 * 1536 + h * 64 + d];
    float ek = ek_tab[e * 512 + h * 64 + d];
    qe1[e][d] = q1 * ek;
    qe2[e][d] = q2 * ek;
    evh[idx] = ev_tab[e * 512 + h * 64 + d];
  }
  __syncthreads();

  float ls1 = 0.0f, ls2 = 0.0f;
  const int* bm1 = bias_matrix + (size_t)i1 * TT;
  const int* bm2 = bias_matrix + (size_t)i2 * TT;
  const uint4* kTh = (const uint4*)(kT + (size_t)h * 8 * TT * 8);
  for (int jl = tid; jl < n2; jl += 256) {
    int e2 = bm2[jl];
    uint4 kr[8];
#pragma unroll
    for (int dg = 0; dg < 8; dg++) kr[dg] = kTh[dg * TT + jl];
    float a2 = 0.f;
#pragma unroll
    for (int dg = 0; dg < 8; dg++) {
      bf16x8 kv = *reinterpret_cast<const bf16x8*>(&kr[dg]);
      f32x4 qa = *(const f32x4*)&qe2[e2][dg * 8];
      f32x4 qb = *(const f32x4*)&qe2[e2][dg * 8 + 4];
      a2 += (float)kv[0] * qa.x + (float)kv[1] * qa.y + (float)kv[2] * qa.z +
            (float)kv[3] * qa.w + (float)kv[4] * qb.x + (float)kv[5] * qb.y +
            (float)kv[6] * qb.z + (float)kv[7] * qb.w;
    }
    float p2 = __expf(a2 * 0.125f + absh[e2]);
    uint4 pk;
    pk.x = 0u; pk.y = 0u;
    pk.z = (unsigned)e2; pk.w = __float_as_uint(p2);
    ls2 += p2;
    if (jl < n1) {
      int e1 = bm1[jl];
      float a1 = 0.f;
#pragma unroll
      for (int dg = 0; dg < 8; dg++) {
        bf16x8 kv = *reinterpret_cast<const bf16x8*>(&kr[dg]);
        f32x4 qa = *(const f32x4*)&qe1[e1][dg * 8];
        f32x4 qb = *(const f32x4*)&qe1[e1][dg * 8 + 4];
        a1 += (float)kv[0] * qa.x + (float)kv[1] * qa.y + (float)kv[2] * qa.z +
              (float)kv[3] * qa.w + (float)kv[4] * qb.x + (float)kv[5] * qb.y +
              (float)kv[6] * qb.z + (float)kv[7] * qb.w;
      }
      float p1 = __expf(a1 * 0.125f + absh[e1]);
      pk.x = (unsigned)e1;
      pk.y = __float_as_uint(p1);
      ls1 += p1;
    }
    psv[jl] = pk;
  }
  ls1 = wave_reduce_sum(ls1);
  ls2 = wave_reduce_sum(ls2);
  if (lane == 0) { scr[0][wave] = ls1; scr[1][wave] = ls2; }
  __syncthreads();
  float inv1 = 1.0f / (scr[0][0] + scr[0][1] + scr[0][2] + scr[0][3]);
  float inv2 = 1.0f / (scr[1][0] + scr[1][1] + scr[1][2] + scr[1][3]);

  const bf16_t* vb = qkv + 1024 + h * 64 + lane;  // lane's d column of v rows
  float acc1 = 0.0f, acc2 = 0.0f;
  int j = wave;
  // shared region: both rows. 8 v-loads in flight, psv consumed 4-wide.
  for (; j + 28 < n1; j += 32) {
    float v0 = (float)vb[(size_t)j * 1536];
    float v1 = (float)vb[(size_t)(j + 4) * 1536];
    float v2 = (float)vb[(size_t)(j + 8) * 1536];
    float v3 = (float)vb[(size_t)(j + 12) * 1536];
    float v4 = (float)vb[(size_t)(j + 16) * 1536];
    float v5 = (float)vb[(size_t)(j + 20) * 1536];
    float v6 = (float)vb[(size_t)(j + 24) * 1536];
    float v7 = (float)vb[(size_t)(j + 28) * 1536];
    {
      uint4 q0 = psv[j], q1 = psv[j + 4], q2 = psv[j + 8], q3 = psv[j + 12];
      acc2 = fmaf(__uint_as_float(q0.w) * v0, evh[q0.z * 64 + lane], acc2);
      acc2 = fmaf(__uint_as_float(q1.w) * v1, evh[q1.z * 64 + lane], acc2);
      acc2 = fmaf(__uint_as_float(q2.w) * v2, evh[q2.z * 64 + lane], acc2);
      acc2 = fmaf(__uint_as_float(q3.w) * v3, evh[q3.z * 64 + lane], acc2);
      acc1 = fmaf(__uint_as_float(q0.y) * v0, evh[q0.x * 64 + lane], acc1);
      acc1 = fmaf(__uint_as_float(q1.y) * v1, evh[q1.x * 64 + lane], acc1);
      acc1 = fmaf(__uint_as_float(q2.y) * v2, evh[q2.x * 64 + lane], acc1);
      acc1 = fmaf(__uint_as_float(q3.y) * v3, evh[q3.x * 64 + lane], acc1);
    }
    {
      uint4 q0 = psv[j + 16], q1 = psv[j + 20];
      uint4 q2 = psv[j + 24], q3 = psv[j + 28];
      acc2 = fmaf(__uint_as_float(q0.w) * v4, evh[q0.z * 64 + lane], acc2);
      acc2 = fmaf(__uint_as_float(q1.w) * v5, evh[q1.z * 64 + lane], acc2);
      acc2 = fmaf(__uint_as_float(q2.w) * v6, evh[q2.z * 64 + lane], acc2);
      acc2 = fmaf(__uint_as_float(q3.w) * v7, evh[q3.z * 64 + lane], acc2);
      acc1 = fmaf(__uint_as_float(q0.y) * v4, evh[q0.x * 64 + lane], acc1);
      acc1 = fmaf(__uint_as_float(q1.y) * v5, evh[q1.x * 64 + lane], acc1);
      acc1 = fmaf(__uint_as_float(q2.y) * v6, evh[q2.x * 64 + lane], acc1);
      acc1 = fmaf(__uint_as_float(q3.y) * v7, evh[q3.x * 64 + lane], acc1);
    }
  }
  for (; j + 12 < n1; j += 16) {
    float v0 = (float)vb[(size_t)j * 1536];
    float v1 = (float)vb[(size_t)(j + 4) * 1536];
    float v2 = (float)vb[(size_t)(j + 8) * 1536];
    float v3 = (float)vb[(size_t)(j + 12) * 1536];
    uint4 q0 = psv[j], q1 = psv[j + 4], q2 = psv[j + 8], q3 = psv[j + 12];
    acc2 = fmaf(__uint_as_float(q0.w) * v0, evh[q0.z * 64 + lane], acc2);
    acc2 = fmaf(__uint_as_float(q1.w) * v1, evh[q1.z * 64 + lane], acc2);
    acc2 = fmaf(__uint_as_float(q2.w) * v2, evh[q2.z * 64 + lane], acc2);
    acc2 = fmaf(__uint_as_float(q3.w) * v3, evh[q3.z * 64 + lane], acc2);
    acc1 = fmaf(__uint_as_float(q0.y) * v0, evh[q0.x * 64 + lane], acc1);
    acc1 = fmaf(__uint_as_float(q1.y) * v1, evh[q1.x * 64 + lane], acc1);
    acc1 = fmaf(__uint_as_float(q2.y) * v2, evh[q2.x * 64 + lane], acc1);
    acc1 = fmaf(__uint_as_float(q3.y) * v3, evh[q3.x * 64 + lane], acc1);
  }
  for (; j < n1; j += 4) {
    float v0 = (float)vb[(size_t)j * 1536];
    uint4 q0 = psv[j];
    acc2 = fmaf(__uint_as_float(q0.w) * v0, evh[q0.z * 64 + lane], acc2);
    acc1 = fmaf(__uint_as_float(q0.y) * v0, evh[q0.x * 64 + lane], acc1);
  }
  // tail region: row 2 only. Same 8-deep v batching, b64 psv-half reads.
  const uint2* ps2h = (const uint2*)((const char*)psv + 8);  // psv[j].zw
  for (; j + 28 < n2; j += 32) {
    float v0 = (float)vb[(size_t)j * 1536];
    float v1 = (float)vb[(size_t)(j + 4) * 1536];
    float v2 = (float)vb[(size_t)(j + 8) * 1536];
    float v3 = (float)vb[(size_t)(j + 12) * 1536];
    float v4 = (float)vb[(size_t)(j + 16) * 1536];
    float v5 = (float)vb[(size_t)(j + 20) * 1536];
    float v6 = (float)vb[(size_t)(j + 24) * 1536];
    float v7 = (float)vb[(size_t)(j + 28) * 1536];
    {
      uint2 c0 = ps2h[j * 2], c1 = ps2h[(j + 4) * 2];
      uint2 c2 = ps2h[(j + 8) * 2], c3 = ps2h[(j + 12) * 2];
      acc2 = fmaf(__uint_as_float(c0.y) * v0, evh[c0.x * 64 + lane], acc2);
      acc2 = fmaf(__uint_as_float(c1.y) * v1, evh[c1.x * 64 + lane], acc2);
      acc2 = fmaf(__uint_as_float(c2.y) * v2, evh[c2.x * 64 + lane], acc2);
      acc2 = fmaf(__uint_as_float(c3.y) * v3, evh[c3.x * 64 + lane], acc2);
    }
    {
      uint2 c0 = ps2h[(j + 16) * 2], c1 = ps2h[(j + 20) * 2];
      uint2 c2 = ps2h[(j + 24) * 2], c3 = ps2h[(j + 28) * 2];
      acc2 = fmaf(__uint_as_float(c0.y) * v4, evh[c0.x * 64 + lane], acc2);
      acc2 = fmaf(__uint_as_float(c1.y) * v5, evh[c1.x * 64 + lane], acc2);
      acc2 = fmaf(__uint_as_float(c2.y) * v6, evh[c2.x * 64 + lane], acc2);
      acc2 = fmaf(__uint_as_float(c3.y) * v7, evh[c3.x * 64 + lane], acc2);
    }
  }
  for (; j + 12 < n2; j += 16) {
    float v0 = (float)vb[(size_t)j * 1536];
    float v1 = (float)vb[(size_t)(j + 4) * 1536];
    float v2 = (float)vb[(size_t)(j + 8) * 1536];
    float v3 = (float)vb[(size_t)(j + 12) * 1536];
    uint2 c0 = ps2h[j * 2], c1 = ps2h[(j + 4) * 2];
    uint2 c2 = ps2h[(j + 8) * 2], c3 = ps2h[(j + 12) * 2];
    acc2 = fmaf(__uint_as_float(c0.y) * v0, evh[c0.x * 64 + lane], acc2);
    acc2 = fmaf(__uint_as_float(c1.y) * v1, evh[c1.x * 64 + lane], acc2);
    acc2 = fmaf(__uint_as_float(c2.y) * v2, evh[c2.x * 64 + lane], acc2);
    acc2 = fmaf(__uint_as_float(c3.y) * v3, evh[c3.x * 64 + lane], acc2);
  }
  for (; j < n2; j += 4) {
    float v0 = (float)vb[(size_t)j * 1536];
    uint2 c0 = ps2h[j * 2];
    acc2 = fmaf(__uint_as_float(c0.y) * v0, evh[c0.x * 64 + lane], acc2);
  }
  red[0][wave * 64 + lane] = acc1;
  red[1][wave * 64 + lane] = acc2;
  __syncthreads();
  if (tid < 64) {
    float y =
        (red[0][tid] + red[0][64 + tid] + red[0][128 + tid] + red[0][192 + tid]) *
        inv1;
    ybuf[(size_t)i1 * CC + h * 64 + tid] = (bf16_t)y;
  } else if (tid < 128) {
    int t = tid - 64;
    float y =
        (red[1][t] + red[1][64 + t] + red[1][128 + t] + red[1][192 + t]) * inv2;
    ybuf[(size_t)i2 * CC + h * 64 + t] = (bf16_t)y;
  }
}

// ---------------------------------------------------------------------------
extern "C" void kernel_launch(void* const* d_in, const int* in_sizes, int n_in,
                              void* d_out, int out_size, void* d_ws,
                              size_t ws_size, hipStream_t stream) {
  const float* x = (const float*)d_in[0];
  const int* bias_mat = (const int*)d_in[1];

  char* wp = (char*)d_ws;
  float* ektab = (float*)wp;  wp += 16 * 512 * 4;
  float* evtab = (float*)wp;  wp += 16 * 512 * 4;
  float* s1f = (float*)wp;    wp += 2048 * 4;
  float* cf = (float*)wp;     wp += 2048 * 4;
  float* x1 = (float*)wp;     wp += 384 * 512 * 4;
  bf16_t* wfc_bf = (bf16_t*)wp;    wp += 2048 * 512 * 2;
  bf16_t* wproj_bf = (bf16_t*)wp;  wp += 512 * 512 * 2;
  bf16_t* wcproj_bf = (bf16_t*)wp; wp += 512 * 2048 * 2;
  bf16_t* qkv = (bf16_t*)wp;  wp += 384 * 1536 * 2;
  bf16_t* kT = (bf16_t*)wp;   wp += 8 * 64 * 384 * 2;  // [h][dg][j][8]
  bf16_t* ybuf = (bf16_t*)wp; wp += 384 * 512 * 2;
  bf16_t* gbuf = (bf16_t*)wp; wp += 384 * 2048 * 2;

  PrepX X;
  X.eemb = (const float*)d_in[9];
  X.wekw = (const float*)d_in[10];
  X.wekb = (const float*)d_in[11];
  X.wevw = (const float*)d_in[12];
  X.wevb = (const float*)d_in[13];
  X.ln2w = (const float*)d_in[14];
  X.ln2b = (const float*)d_in[15];
  X.cfcw = (const float*)d_in[16];
  X.cfcb = (const float*)d_in[17];
  X.wproj = (const float*)d_in[6];
  X.wcproj = (const float*)d_in[18];
  X.ektab = ektab; X.evtab = evtab; X.s1f = s1f; X.cf = cf;
  X.wfc_bf = wfc_bf; X.wproj_bf = wproj_bf; X.wcproj_bf = wcproj_bf;

  // 1) self-contained qkv (576 gemm tiles, rows 0-11; K tiles also fill kT)
  //    + 1088 hidden prep units (rows 12-34)
  qkv_k<<<dim3(48, 35), 256, 0, stream>>>(
      x, (const float*)d_in[4], (const float*)d_in[2], (const float*)d_in[3],
      (const float*)d_in[5], qkv, kT, X);
  // 2) attention (paired rows, 192x8, kT QK reads, 8-deep PV v-batching)
  attn_k<<<dim3(TT / 2, HH), 256, 0, stream>>>(qkv, kT, bias_mat,
                                               (const float*)d_in[8], ektab,
                                               evtab, ybuf);
  // 3) x1 = x + y @ wproj^T + b
  gemm_k<1><<<dim3(16, 12), 256, 0, stream>>>(
      ybuf, wproj_bf, (const float*)d_in[7], nullptr, x, x1, 512, 512);
  // 4) g = gelu(LN2(x1) @ cfc^T + b)  (row stats from own A reads)
  gemm_k<2><<<dim3(64, 12), 256, 0, stream>>>(x1, wfc_bf, s1f, cf, nullptr,
                                              gbuf, 2048, 512);
  // 5) out = x1 + g @ cproj^T + b
  gemm_k<3><<<dim3(16, 12), 256, 0, stream>>>(
      gbuf, wcproj_bf, (const float*)d_in[19], nullptr, x1, d_out, 512, 2048);
}

// Round 12
// 159.065 us; speedup vs baseline: 2.3490x; 1.0181x over previous
//
#include <hip/hip_runtime.h>
#include <math.h>

// Problem constants: B=1, T=384, C=512, H=8, D=64, E=16. Inputs/outputs f32.
// R23 = R11 base (161.9us best: kT QK reads + 8-deep PV v-batching) with
// the TAIL region (row-2-only PV, ~2/3 of PV pairs) deepened to 16 v-loads
// in flight (4 groups of 4 b64 psv-half reads). Tail live state is only
// uint2+float per j, so 16-deep stays under the 64-VGPR cliff (R8 lesson).
// Shared region stays 8-deep (uint4 state is 2x heavier).
// Kept: 2-row paired attn, stats-fold in gemm<2>, no atomics, no
// cross-block sync (R7 lesson), 5 dispatches.
#define TT 384
#define CC 512
#define HH 8
#define EE 16

typedef __bf16 bf16_t;
typedef __bf16 bf16x8 __attribute__((ext_vector_type(8)));
typedef __bf16 bf16x4v __attribute__((ext_vector_type(4)));
typedef float f32x4 __attribute__((ext_vector_type(4)));

__device__ __forceinline__ float wave_reduce_sum(float v) {
#pragma unroll
  for (int off = 32; off >= 1; off >>= 1) v += __shfl_xor(v, off, 64);
  return v;
}

// ---------------------------------------------------------------------------
// wrow_unit: one LN-folded weight row: W'[n]=g∘W[n] (bf16), s1[n]=Σ W'[n,k],
// c[n] = Σ b_k W[n,k] + extra
// ---------------------------------------------------------------------------
__device__ __forceinline__ void wrow_unit(const float* __restrict__ wr,
                                          const float* __restrict__ g,
                                          const float* __restrict__ bb,
                                          float extra_c, bf16_t* __restrict__ orow,
                                          float* __restrict__ s1p,
                                          float* __restrict__ cp, int lane) {
  const float* p = wr + lane * 8;
  f32x4 w0 = *(const f32x4*)p, w1 = *(const f32x4*)(p + 4);
  f32x4 g0 = *(const f32x4*)(g + lane * 8), g1 = *(const f32x4*)(g + lane * 8 + 4);
  f32x4 b0 = *(const f32x4*)(bb + lane * 8), b1 = *(const f32x4*)(bb + lane * 8 + 4);
  f32x4 p0 = w0 * g0, p1 = w1 * g1;
  bf16x8 o;
  o[0] = (bf16_t)p0.x; o[1] = (bf16_t)p0.y; o[2] = (bf16_t)p0.z; o[3] = (bf16_t)p0.w;
  o[4] = (bf16_t)p1.x; o[5] = (bf16_t)p1.y; o[6] = (bf16_t)p1.z; o[7] = (bf16_t)p1.w;
  *(bf16x8*)(orow + lane * 8) = o;
  float s1 = p0.x + p0.y + p0.z + p0.w + p1.x + p1.y + p1.z + p1.w;
  float c = w0.x * b0.x + w0.y * b0.y + w0.z * b0.z + w0.w * b0.w +
            w1.x * b1.x + w1.y * b1.y + w1.z * b1.z + w1.w * b1.w;
  s1 = wave_reduce_sum(s1);
  c = wave_reduce_sum(c);
  if (lane == 0) { *s1p = s1; *cp = c + extra_c; }
}

// ---------------------------------------------------------------------------
// Prep bundle (hidden in qkv dispatch rows by>=12; 1088 units):
// 0-255 edge tables; 256-767 wfc rows; 768-1023 wcproj conv; 1024-1087
// wproj conv.
// ---------------------------------------------------------------------------
struct PrepX {
  const float *eemb, *wekw, *wekb, *wevw, *wevb;
  const float *ln2w, *ln2b, *cfcw, *cfcb;
  const float *wproj, *wcproj;
  float *ektab, *evtab, *s1f, *cf;
  bf16_t *wfc_bf, *wproj_bf, *wcproj_bf;
};

__device__ void prep_unit(int u, const PrepX& X, int tid) {
  int lane = tid & 63, wave = tid >> 6;
  if (u < 256) {
    int wid = u * 4 + wave;
    int gbase = wid * 16;
    int table = gbase >> 13;
    int e = (gbase >> 9) & 15;
    int c0 = gbase & 511;
    const float* er = X.eemb + e * 512 + lane * 8;
    f32x4 ea = *(const f32x4*)er;
    f32x4 eb = *(const f32x4*)(er + 4);
    const float* wbase = table ? X.wevw : X.wekw;
    const float* bbase = table ? X.wevb : X.wekb;
    float* obase = (table ? X.evtab : X.ektab) + e * 512;
#pragma unroll
    for (int o = 0; o < 16; o++) {
      int c = c0 + o;
      const float* wr = wbase + (size_t)c * 512 + lane * 8;
      f32x4 wa = *(const f32x4*)wr;
      f32x4 wb = *(const f32x4*)(wr + 4);
      float acc = ea.x * wa.x + ea.y * wa.y + ea.z * wa.z + ea.w * wa.w +
                  eb.x * wb.x + eb.y * wb.y + eb.z * wb.z + eb.w * wb.w;
      acc = wave_reduce_sum(acc);
      if (lane == 0) obase[c] = acc + bbase[c];
    }
  } else if (u < 768) {
    int n = (u - 256) * 4 + wave;  // 0..2047
    wrow_unit(X.cfcw + (size_t)n * 512, X.ln2w, X.ln2b, X.cfcb[n],
              X.wfc_bf + (size_t)n * 512, X.s1f + n, X.cf + n, lane);
  } else if (u < 1024) {
    int base = (u - 768) * 1024;  // wcproj: 262144 f32x4
    for (int t = tid; t < 1024; t += 256) {
      f32x4 a = *((const f32x4*)X.wcproj + base + t);
      bf16x4v o;
      o[0] = (bf16_t)a.x; o[1] = (bf16_t)a.y; o[2] = (bf16_t)a.z; o[3] = (bf16_t)a.w;
      *((bf16x4v*)X.wcproj_bf + base + t) = o;
    }
  } else if (u < 1088) {
    int base = (u - 1024) * 1024;  // wproj: 65536 f32x4
    for (int t = tid; t < 1024; t += 256) {
      f32x4 a = *((const f32x4*)X.wproj + base + t);
      bf16x4v o;
      o[0] = (bf16_t)a.x; o[1] = (bf16_t)a.y; o[2] = (bf16_t)a.z; o[3] = (bf16_t)a.w;
      *((bf16x4v*)X.wproj_bf + base + t) = o;
    }
  }
}

// ---------------------------------------------------------------------------
// qkv_k: SELF-CONTAINED qkv GEMM — no pre-pass dependency. Each 32x32 tile:
//  - loads raw f32 x and wattn, folds g∘W inline into the B fragment
//  - accumulates per-wave partials of row Σx/Σx² and col Σ(gW)/Σ(bW)
//    alongside the MFMA loop (operands already in registers)
//  - quad-shuffle + LDS reduce, epilogue applies rs·(acc−mu·s1)+c+bias.
//  - K-tile blocks (n0 in [512,1024)) also store the same bf16 values
//    transposed into kT[h][dg][j][8] for coalesced attn QK reads.
// by>=12 rows run prep units (tables, wfc, wproj/wcproj).
// ---------------------------------------------------------------------------
__global__ __launch_bounds__(256) void qkv_k(
    const float* __restrict__ x, const float* __restrict__ wattn,
    const float* __restrict__ ln1w, const float* __restrict__ ln1b,
    const float* __restrict__ wattnb, bf16_t* __restrict__ out,
    bf16_t* __restrict__ kT, PrepX X) {
  int tid = threadIdx.x;
  if (blockIdx.y >= 12) {
    prep_unit((blockIdx.y - 12) * gridDim.x + blockIdx.x, X, tid);
    return;
  }
  __shared__ float part[4][32][32];  // 16 KB
  __shared__ float rst[2][4][32];    // [sx|sxx][wave][row]  1 KB
  __shared__ float wst[2][4][32];    // [s1|c ][wave][col]  1 KB
  int lane = tid & 63, wave = tid >> 6;
  int m0 = blockIdx.y * 32, n0 = blockIdx.x * 32;
  int r16 = lane & 15, quad = lane >> 4;
  int k0 = wave * 128;  // K=512, kchunk=128

  f32x4 acc[2][2];
  f32x4 zero = {0.f, 0.f, 0.f, 0.f};
#pragma unroll
  for (int i = 0; i < 2; i++)
#pragma unroll
    for (int j = 0; j < 2; j++) acc[i][j] = zero;

  const float* Af = x + (size_t)(m0 + r16) * 512 + k0 + quad * 8;
  const float* Wf = wattn + (size_t)(n0 + r16) * 512 + k0 + quad * 8;
  const float* gp = ln1w + k0 + quad * 8;
  const float* bp = ln1b + k0 + quad * 8;

  float sx[2] = {0.f, 0.f}, sxx[2] = {0.f, 0.f};
  float s1[2] = {0.f, 0.f}, cc[2] = {0.f, 0.f};

  for (int kb0 = 0; kb0 < 128; kb0 += 64) {  // 2 k-steps hoisted
    uint4 araw[2][2][2], wraw[2][2][2];
#pragma unroll
    for (int u = 0; u < 2; u++) {
      int kb = kb0 + u * 32;
#pragma unroll
      for (int t = 0; t < 2; t++) {
        araw[u][t][0] = *(const uint4*)(Af + (size_t)t * 16 * 512 + kb);
        araw[u][t][1] = *(const uint4*)(Af + (size_t)t * 16 * 512 + kb + 4);
        wraw[u][t][0] = *(const uint4*)(Wf + (size_t)t * 16 * 512 + kb);
        wraw[u][t][1] = *(const uint4*)(Wf + (size_t)t * 16 * 512 + kb + 4);
      }
    }
#pragma unroll
    for (int u = 0; u < 2; u++) {
      int kb = kb0 + u * 32;
      f32x4 g0 = *(const f32x4*)(gp + kb), g1 = *(const f32x4*)(gp + kb + 4);
      f32x4 b0 = *(const f32x4*)(bp + kb), b1 = *(const f32x4*)(bp + kb + 4);
      bf16x8 af[2], bfr[2];
#pragma unroll
      for (int t = 0; t < 2; t++) {
        f32x4 a0 = *reinterpret_cast<const f32x4*>(&araw[u][t][0]);
        f32x4 a1 = *reinterpret_cast<const f32x4*>(&araw[u][t][1]);
        af[t][0] = (bf16_t)a0.x; af[t][1] = (bf16_t)a0.y;
        af[t][2] = (bf16_t)a0.z; af[t][3] = (bf16_t)a0.w;
        af[t][4] = (bf16_t)a1.x; af[t][5] = (bf16_t)a1.y;
        af[t][6] = (bf16_t)a1.z; af[t][7] = (bf16_t)a1.w;
        sx[t] += a0.x + a0.y + a0.z + a0.w + a1.x + a1.y + a1.z + a1.w;
        sxx[t] += a0.x * a0.x + a0.y * a0.y + a0.z * a0.z + a0.w * a0.w +
                  a1.x * a1.x + a1.y * a1.y + a1.z * a1.z + a1.w * a1.w;
        f32x4 w0 = *reinterpret_cast<const f32x4*>(&wraw[u][t][0]);
        f32x4 w1 = *reinterpret_cast<const f32x4*>(&wraw[u][t][1]);
        f32x4 p0 = w0 * g0, p1 = w1 * g1;
        bfr[t][0] = (bf16_t)p0.x; bfr[t][1] = (bf16_t)p0.y;
        bfr[t][2] = (bf16_t)p0.z; bfr[t][3] = (bf16_t)p0.w;
        bfr[t][4] = (bf16_t)p1.x; bfr[t][5] = (bf16_t)p1.y;
        bfr[t][6] = (bf16_t)p1.z; bfr[t][7] = (bf16_t)p1.w;
        s1[t] += p0.x + p0.y + p0.z + p0.w + p1.x + p1.y + p1.z + p1.w;
        cc[t] += w0.x * b0.x + w0.y * b0.y + w0.z * b0.z + w0.w * b0.w +
                 w1.x * b1.x + w1.y * b1.y + w1.z * b1.z + w1.w * b1.w;
      }
#pragma unroll
      for (int i = 0; i < 2; i++)
#pragma unroll
        for (int j = 0; j < 2; j++)
          acc[i][j] = __builtin_amdgcn_mfma_f32_16x16x32_bf16(af[i], bfr[j],
                                                              acc[i][j], 0, 0, 0);
    }
  }

  // quad-reduce stats (lanes r16, r16+16, r16+32, r16+48 → same value)
#pragma unroll
  for (int t = 0; t < 2; t++) {
    sx[t] += __shfl_xor(sx[t], 16, 64);  sx[t] += __shfl_xor(sx[t], 32, 64);
    sxx[t] += __shfl_xor(sxx[t], 16, 64); sxx[t] += __shfl_xor(sxx[t], 32, 64);
    s1[t] += __shfl_xor(s1[t], 16, 64);  s1[t] += __shfl_xor(s1[t], 32, 64);
    cc[t] += __shfl_xor(cc[t], 16, 64);  cc[t] += __shfl_xor(cc[t], 32, 64);
  }
  if (quad == 0) {
#pragma unroll
    for (int t = 0; t < 2; t++) {
      rst[0][wave][t * 16 + r16] = sx[t];
      rst[1][wave][t * 16 + r16] = sxx[t];
      wst[0][wave][t * 16 + r16] = s1[t];
      wst[1][wave][t * 16 + r16] = cc[t];
    }
  }
#pragma unroll
  for (int i = 0; i < 2; i++)
#pragma unroll
    for (int j = 0; j < 2; j++)
#pragma unroll
      for (int r = 0; r < 4; r++)
        part[wave][i * 16 + quad * 4 + r][j * 16 + r16] = acc[i][j][r];
  __syncthreads();

  int row = tid >> 3, c4 = (tid & 7) * 4;
  f32x4 v = *(const f32x4*)&part[0][row][c4];
  v += *(const f32x4*)&part[1][row][c4];
  v += *(const f32x4*)&part[2][row][c4];
  v += *(const f32x4*)&part[3][row][c4];
  float sxt = rst[0][0][row] + rst[0][1][row] + rst[0][2][row] + rst[0][3][row];
  float sxxt = rst[1][0][row] + rst[1][1][row] + rst[1][2][row] + rst[1][3][row];
  float mu = sxt * (1.0f / 512.0f);
  float var = sxxt * (1.0f / 512.0f) - mu * mu;
  float rs = rsqrtf(var + 1e-5f);
  int grow = m0 + row, gcol = n0 + c4;
  bf16x4v o;
#pragma unroll
  for (int t = 0; t < 4; t++) {
    int cl = c4 + t;
    float s1v = wst[0][0][cl] + wst[0][1][cl] + wst[0][2][cl] + wst[0][3][cl];
    float ccv = wst[1][0][cl] + wst[1][1][cl] + wst[1][2][cl] + wst[1][3][cl] +
                wattnb[n0 + cl];
    o[t] = (bf16_t)(rs * (v[t] - mu * s1v) + ccv);
  }
  *(bf16x4v*)(out + (size_t)grow * 1536 + gcol) = o;
  // K tiles also write transposed copy for coalesced attn QK reads.
  if (n0 >= 512 && n0 < 1024) {
    int kd = gcol - 512;
    int h = kd >> 6, d = kd & 63;
    int dg = d >> 3, di = d & 7;
    *(bf16x4v*)(kT + (((size_t)(h * 8 + dg) * TT) + grow) * 8 + di) = o;
  }
}

// ---------------------------------------------------------------------------
// Split-K NT GEMM, 32x32 tile (R10 measured-best). 4 waves each K/4;
// K-loop hoists 4 k-steps of loads before MFMA.
// MODE 1 (PROJ): A bf16, +bias +res ->f32
// MODE 2 (FC):   A=x1 f32; row stats computed FROM OWN A-FRAGMENTS
//                (qkv_k pattern); fused-LN; gelu ->bf16
// MODE 3 (CPROJ):A bf16, +bias +res ->f32 (d_out)
// ---------------------------------------------------------------------------
template <int MODE>
__global__ __launch_bounds__(256) void gemm_k(
    const void* __restrict__ Aptr, const bf16_t* __restrict__ Wb,
    const float* __restrict__ e2, const float* __restrict__ e3,
    const float* __restrict__ res, void* __restrict__ out, int N, int K) {
  constexpr bool AF32 = (MODE == 2);
  constexpr int AW = AF32 ? 2 : 1;
  __shared__ float part[4][32][32];
  __shared__ float rst[2][4][32];  // MODE 2 row stats (1 KB, else unused)
  int tid = threadIdx.x;
  int lane = tid & 63, wave = tid >> 6;
  int m0 = blockIdx.y * 32, n0 = blockIdx.x * 32;
  int r16 = lane & 15, quad = lane >> 4;
  int kchunk = K >> 2, k0 = wave * kchunk;

  f32x4 acc[2][2];
  f32x4 zero = {0.f, 0.f, 0.f, 0.f};
#pragma unroll
  for (int i = 0; i < 2; i++)
#pragma unroll
    for (int j = 0; j < 2; j++) acc[i][j] = zero;

  const float* Af = (const float*)Aptr + (size_t)(m0 + r16) * K + k0 + quad * 8;
  const bf16_t* Ab = (const bf16_t*)Aptr + (size_t)(m0 + r16) * K + k0 + quad * 8;
  const bf16_t* Wp = Wb + (size_t)(n0 + r16) * K + k0 + quad * 8;

  float sx[2] = {0.f, 0.f}, sxx[2] = {0.f, 0.f};

  for (int kb0 = 0; kb0 < kchunk; kb0 += 128) {
    uint4 araw[4][2][AW];
    uint4 braw[4][2];
#pragma unroll
    for (int u = 0; u < 4; u++) {
      int kb = kb0 + u * 32;
#pragma unroll
      for (int t = 0; t < 2; t++) {
        if (AF32) {
          araw[u][t][0] = *(const uint4*)(Af + (size_t)t * 16 * K + kb);
          araw[u][t][1] = *(const uint4*)(Af + (size_t)t * 16 * K + kb + 4);
        } else {
          araw[u][t][0] = *(const uint4*)(Ab + (size_t)t * 16 * K + kb);
        }
        braw[u][t] = *(const uint4*)(Wp + (size_t)t * 16 * K + kb);
      }
    }
#pragma unroll
    for (int u = 0; u < 4; u++) {
      bf16x8 af[2], bfr[2];
#pragma unroll
      for (int t = 0; t < 2; t++) {
        if (AF32) {
          f32x4 a = *reinterpret_cast<const f32x4*>(&araw[u][t][0]);
          f32x4 c = *reinterpret_cast<const f32x4*>(&araw[u][t][1]);
          af[t][0] = (bf16_t)a.x; af[t][1] = (bf16_t)a.y;
          af[t][2] = (bf16_t)a.z; af[t][3] = (bf16_t)a.w;
          af[t][4] = (bf16_t)c.x; af[t][5] = (bf16_t)c.y;
          af[t][6] = (bf16_t)c.z; af[t][7] = (bf16_t)c.w;
          sx[t] += a.x + a.y + a.z + a.w + c.x + c.y + c.z + c.w;
          sxx[t] += a.x * a.x + a.y * a.y + a.z * a.z + a.w * a.w +
                    c.x * c.x + c.y * c.y + c.z * c.z + c.w * c.w;
        } else {
          af[t] = *reinterpret_cast<const bf16x8*>(&araw[u][t][0]);
        }
        bfr[t] = *reinterpret_cast<const bf16x8*>(&braw[u][t]);
      }
#pragma unroll
      for (int i = 0; i < 2; i++)
#pragma unroll
        for (int j = 0; j < 2; j++)
          acc[i][j] = __builtin_amdgcn_mfma_f32_16x16x32_bf16(af[i], bfr[j],
                                                              acc[i][j], 0, 0, 0);
    }
  }

  if (MODE == 2) {  // quad-reduce row stats, store per-wave partials
#pragma unroll
    for (int t = 0; t < 2; t++) {
      sx[t] += __shfl_xor(sx[t], 16, 64);  sx[t] += __shfl_xor(sx[t], 32, 64);
      sxx[t] += __shfl_xor(sxx[t], 16, 64); sxx[t] += __shfl_xor(sxx[t], 32, 64);
    }
    if (quad == 0) {
#pragma unroll
      for (int t = 0; t < 2; t++) {
        rst[0][wave][t * 16 + r16] = sx[t];
        rst[1][wave][t * 16 + r16] = sxx[t];
      }
    }
  }
#pragma unroll
  for (int i = 0; i < 2; i++)
#pragma unroll
    for (int j = 0; j < 2; j++)
#pragma unroll
      for (int r = 0; r < 4; r++)
        part[wave][i * 16 + quad * 4 + r][j * 16 + r16] = acc[i][j][r];
  __syncthreads();

  int row = tid >> 3, c4 = (tid & 7) * 4;
  f32x4 v = *(const f32x4*)&part[0][row][c4];
  v += *(const f32x4*)&part[1][row][c4];
  v += *(const f32x4*)&part[2][row][c4];
  v += *(const f32x4*)&part[3][row][c4];
  int grow = m0 + row, gcol = n0 + c4;

  if (MODE == 2) {
    float S = rst[0][0][row] + rst[0][1][row] + rst[0][2][row] + rst[0][3][row];
    float Q = rst[1][0][row] + rst[1][1][row] + rst[1][2][row] + rst[1][3][row];
    float mu = S * (1.0f / 512.0f);
    float var = Q * (1.0f / 512.0f) - mu * mu;
    float rs = rsqrtf(var + 1e-5f);
    f32x4 s1v = *(const f32x4*)(e2 + gcol);
    f32x4 ccv = *(const f32x4*)(e3 + gcol);
    bf16x4v o;
#pragma unroll
    for (int t = 0; t < 4; t++) {
      float xg = rs * (v[t] - mu * s1v[t]) + ccv[t];
      xg = 0.5f * xg * (1.0f + erff(xg * 0.70710678118654752f));
      o[t] = (bf16_t)xg;
    }
    *(bf16x4v*)((bf16_t*)out + (size_t)grow * N + gcol) = o;
  } else {
    v += *(const f32x4*)(e2 + gcol);  // bias
    v += *(const f32x4*)(res + (size_t)grow * N + gcol);
    *(f32x4*)((float*)out + (size_t)grow * N + gcol) = v;
  }
}

// ---------------------------------------------------------------------------
// Attention R23: PAIRED query rows (i1=b, i2=383-b), grid (192,8), kT
// coalesced QK reads. PV: shared region 8-deep v-batching (R11 verified);
// TAIL region 16-deep (16 v-loads in flight, 4 groups of 4 b64 psv-half
// reads) — tail is ~2/3 of PV pairs and its live state is half the shared
// region's, so 16-deep fits under the VGPR cliff.
// ---------------------------------------------------------------------------
__global__ __launch_bounds__(256) void attn_k(
    const bf16_t* __restrict__ qkv, const bf16_t* __restrict__ kT,
    const int* __restrict__ bias_matrix,
    const float* __restrict__ attn_bias_emb, const float* __restrict__ ek_tab,
    const float* __restrict__ ev_tab, bf16_t* __restrict__ ybuf) {
  __shared__ uint4 psv[TT];            // {e1, bits(p1), e2, bits(p2)} per j
  __shared__ float qe1[EE][68], qe2[EE][68];
  __shared__ float evh[EE * 64];
  __shared__ float red[2][4 * 64];
  __shared__ float absh[EE];
  __shared__ float scr[2][4];

  int b = blockIdx.x, h = blockIdx.y;
  int i1 = b, i2 = (TT - 1) - b;  // i1 < i2, n1 <= n2
  int n1 = i1 + 1, n2 = i2 + 1;
  int tid = threadIdx.x, lane = tid & 63, wave = tid >> 6;

  if (tid < EE) absh[tid] = attn_bias_emb[tid * HH + h];
  for (int idx = tid; idx < EE * 64; idx += 256) {
    int e = idx >> 6, d = idx & 63;
    float q1 = (float)qkv[(size_t)i1 * 1536 + h * 64 + d];
    float q2 = (float)qkv[(size_t)i2 * 1536 + h * 64 + d];
    float ek = ek_tab[e * 512 + h * 64 + d];
    qe1[e][d] = q1 * ek;
    qe2[e][d] = q2 * ek;
    evh[idx] = ev_tab[e * 512 + h * 64 + d];
  }
  __syncthreads();

  float ls1 = 0.0f, ls2 = 0.0f;
  const int* bm1 = bias_matrix + (size_t)i1 * TT;
  const int* bm2 = bias_matrix + (size_t)i2 * TT;
  const uint4* kTh = (const uint4*)(kT + (size_t)h * 8 * TT * 8);
  for (int jl = tid; jl < n2; jl += 256) {
    int e2 = bm2[jl];
    uint4 kr[8];
#pragma unroll
    for (int dg = 0; dg < 8; dg++) kr[dg] = kTh[dg * TT + jl];
    float a2 = 0.f;
#pragma unroll
    for (int dg = 0; dg < 8; dg++) {
      bf16x8 kv = *reinterpret_cast<const bf16x8*>(&kr[dg]);
      f32x4 qa = *(const f32x4*)&qe2[e2][dg * 8];
      f32x4 qb = *(const f32x4*)&qe2[e2][dg * 8 + 4];
      a2 += (float)kv[0] * qa.x + (float)kv[1] * qa.y + (float)kv[2] * qa.z +
            (float)kv[3] * qa.w + (float)kv[4] * qb.x + (float)kv[5] * qb.y +
            (float)kv[6] * qb.z + (float)kv[7] * qb.w;
    }
    float p2 = __expf(a2 * 0.125f + absh[e2]);
    uint4 pk;
    pk.x = 0u; pk.y = 0u;
    pk.z = (unsigned)e2; pk.w = __float_as_uint(p2);
    ls2 += p2;
    if (jl < n1) {
      int e1 = bm1[jl];
      float a1 = 0.f;
#pragma unroll
      for (int dg = 0; dg < 8; dg++) {
        bf16x8 kv = *reinterpret_cast<const bf16x8*>(&kr[dg]);
        f32x4 qa = *(const f32x4*)&qe1[e1][dg * 8];
        f32x4 qb = *(const f32x4*)&qe1[e1][dg * 8 + 4];
        a1 += (float)kv[0] * qa.x + (float)kv[1] * qa.y + (float)kv[2] * qa.z +
              (float)kv[3] * qa.w + (float)kv[4] * qb.x + (float)kv[5] * qb.y +
              (float)kv[6] * qb.z + (float)kv[7] * qb.w;
      }
      float p1 = __expf(a1 * 0.125f + absh[e1]);
      pk.x = (unsigned)e1;
      pk.y = __float_as_uint(p1);
      ls1 += p1;
    }
    psv[jl] = pk;
  }
  ls1 = wave_reduce_sum(ls1);
  ls2 = wave_reduce_sum(ls2);
  if (lane == 0) { scr[0][wave] = ls1; scr[1][wave] = ls2; }
  __syncthreads();
  float inv1 = 1.0f / (scr[0][0] + scr[0][1] + scr[0][2] + scr[0][3]);
  float inv2 = 1.0f / (scr[1][0] + scr[1][1] + scr[1][2] + scr[1][3]);

  const bf16_t* vb = qkv + 1024 + h * 64 + lane;  // lane's d column of v rows
  float acc1 = 0.0f, acc2 = 0.0f;
  int j = wave;
  // shared region: both rows. 8 v-loads in flight, psv consumed 4-wide.
  for (; j + 28 < n1; j += 32) {
    float v0 = (float)vb[(size_t)j * 1536];
    float v1 = (float)vb[(size_t)(j + 4) * 1536];
    float v2 = (float)vb[(size_t)(j + 8) * 1536];
    float v3 = (float)vb[(size_t)(j + 12) * 1536];
    float v4 = (float)vb[(size_t)(j + 16) * 1536];
    float v5 = (float)vb[(size_t)(j + 20) * 1536];
    float v6 = (float)vb[(size_t)(j + 24) * 1536];
    float v7 = (float)vb[(size_t)(j + 28) * 1536];
    {
      uint4 q0 = psv[j], q1 = psv[j + 4], q2 = psv[j + 8], q3 = psv[j + 12];
      acc2 = fmaf(__uint_as_float(q0.w) * v0, evh[q0.z * 64 + lane], acc2);
      acc2 = fmaf(__uint_as_float(q1.w) * v1, evh[q1.z * 64 + lane], acc2);
      acc2 = fmaf(__uint_as_float(q2.w) * v2, evh[q2.z * 64 + lane], acc2);
      acc2 = fmaf(__uint_as_float(q3.w) * v3, evh[q3.z * 64 + lane], acc2);
      acc1 = fmaf(__uint_as_float(q0.y) * v0, evh[q0.x * 64 + lane], acc1);
      acc1 = fmaf(__uint_as_float(q1.y) * v1, evh[q1.x * 64 + lane], acc1);
      acc1 = fmaf(__uint_as_float(q2.y) * v2, evh[q2.x * 64 + lane], acc1);
      acc1 = fmaf(__uint_as_float(q3.y) * v3, evh[q3.x * 64 + lane], acc1);
    }
    {
      uint4 q0 = psv[j + 16], q1 = psv[j + 20];
      uint4 q2 = psv[j + 24], q3 = psv[j + 28];
      acc2 = fmaf(__uint_as_float(q0.w) * v4, evh[q0.z * 64 + lane], acc2);
      acc2 = fmaf(__uint_as_float(q1.w) * v5, evh[q1.z * 64 + lane], acc2);
      acc2 = fmaf(__uint_as_float(q2.w) * v6, evh[q2.z * 64 + lane], acc2);
      acc2 = fmaf(__uint_as_float(q3.w) * v7, evh[q3.z * 64 + lane], acc2);
      acc1 = fmaf(__uint_as_float(q0.y) * v4, evh[q0.x * 64 + lane], acc1);
      acc1 = fmaf(__uint_as_float(q1.y) * v5, evh[q1.x * 64 + lane], acc1);
      acc1 = fmaf(__uint_as_float(q2.y) * v6, evh[q2.x * 64 + lane], acc1);
      acc1 = fmaf(__uint_as_float(q3.y) * v7, evh[q3.x * 64 + lane], acc1);
    }
  }
  for (; j + 12 < n1; j += 16) {
    float v0 = (float)vb[(size_t)j * 1536];
    float v1 = (float)vb[(size_t)(j + 4) * 1536];
    float v2 = (float)vb[(size_t)(j + 8) * 1536];
    float v3 = (float)vb[(size_t)(j + 12) * 1536];
    uint4 q0 = psv[j], q1 = psv[j + 4], q2 = psv[j + 8], q3 = psv[j + 12];
    acc2 = fmaf(__uint_as_float(q0.w) * v0, evh[q0.z * 64 + lane], acc2);
    acc2 = fmaf(__uint_as_float(q1.w) * v1, evh[q1.z * 64 + lane], acc2);
    acc2 = fmaf(__uint_as_float(q2.w) * v2, evh[q2.z * 64 + lane], acc2);
    acc2 = fmaf(__uint_as_float(q3.w) * v3, evh[q3.z * 64 + lane], acc2);
    acc1 = fmaf(__uint_as_float(q0.y) * v0, evh[q0.x * 64 + lane], acc1);
    acc1 = fmaf(__uint_as_float(q1.y) * v1, evh[q1.x * 64 + lane], acc1);
    acc1 = fmaf(__uint_as_float(q2.y) * v2, evh[q2.x * 64 + lane], acc1);
    acc1 = fmaf(__uint_as_float(q3.y) * v3, evh[q3.x * 64 + lane], acc1);
  }
  for (; j < n1; j += 4) {
    float v0 = (float)vb[(size_t)j * 1536];
    uint4 q0 = psv[j];
    acc2 = fmaf(__uint_as_float(q0.w) * v0, evh[q0.z * 64 + lane], acc2);
    acc1 = fmaf(__uint_as_float(q0.y) * v0, evh[q0.x * 64 + lane], acc1);
  }
  // tail region: row 2 only. 16-deep v batching, b64 psv-half reads.
  const uint2* ps2h = (const uint2*)((const char*)psv + 8);  // psv[j].zw
  for (; j + 60 < n2; j += 64) {
    float vv[16];
#pragma unroll
    for (int t = 0; t < 16; t++)
      vv[t] = (float)vb[(size_t)(j + t * 4) * 1536];
#pragma unroll
    for (int g = 0; g < 4; g++) {
      uint2 c0 = ps2h[(j + g * 16) * 2], c1 = ps2h[(j + g * 16 + 4) * 2];
      uint2 c2 = ps2h[(j + g * 16 + 8) * 2], c3 = ps2h[(j + g * 16 + 12) * 2];
      acc2 = fmaf(__uint_as_float(c0.y) * vv[g * 4], evh[c0.x * 64 + lane], acc2);
      acc2 = fmaf(__uint_as_float(c1.y) * vv[g * 4 + 1], evh[c1.x * 64 + lane], acc2);
      acc2 = fmaf(__uint_as_float(c2.y) * vv[g * 4 + 2], evh[c2.x * 64 + lane], acc2);
      acc2 = fmaf(__uint_as_float(c3.y) * vv[g * 4 + 3], evh[c3.x * 64 + lane], acc2);
    }
  }
  for (; j + 28 < n2; j += 32) {
    float v0 = (float)vb[(size_t)j * 1536];
    float v1 = (float)vb[(size_t)(j + 4) * 1536];
    float v2 = (float)vb[(size_t)(j + 8) * 1536];
    float v3 = (float)vb[(size_t)(j + 12) * 1536];
    float v4 = (float)vb[(size_t)(j + 16) * 1536];
    float v5 = (float)vb[(size_t)(j + 20) * 1536];
    float v6 = (float)vb[(size_t)(j + 24) * 1536];
    float v7 = (float)vb[(size_t)(j + 28) * 1536];
    {
      uint2 c0 = ps2h[j * 2], c1 = ps2h[(j + 4) * 2];
      uint2 c2 = ps2h[(j + 8) * 2], c3 = ps2h[(j + 12) * 2];
      acc2 = fmaf(__uint_as_float(c0.y) * v0, evh[c0.x * 64 + lane], acc2);
      acc2 = fmaf(__uint_as_float(c1.y) * v1, evh[c1.x * 64 + lane], acc2);
      acc2 = fmaf(__uint_as_float(c2.y) * v2, evh[c2.x * 64 + lane], acc2);
      acc2 = fmaf(__uint_as_float(c3.y) * v3, evh[c3.x * 64 + lane], acc2);
    }
    {
      uint2 c0 = ps2h[(j + 16) * 2], c1 = ps2h[(j + 20) * 2];
      uint2 c2 = ps2h[(j + 24) * 2], c3 = ps2h[(j + 28) * 2];
      acc2 = fmaf(__uint_as_float(c0.y) * v4, evh[c0.x * 64 + lane], acc2);
      acc2 = fmaf(__uint_as_float(c1.y) * v5, evh[c1.x * 64 + lane], acc2);
      acc2 = fmaf(__uint_as_float(c2.y) * v6, evh[c2.x * 64 + lane], acc2);
      acc2 = fmaf(__uint_as_float(c3.y) * v7, evh[c3.x * 64 + lane], acc2);
    }
  }
  for (; j + 12 < n2; j += 16) {
    float v0 = (float)vb[(size_t)j * 1536];
    float v1 = (float)vb[(size_t)(j + 4) * 1536];
    float v2 = (float)vb[(size_t)(j + 8) * 1536];
    float v3 = (float)vb[(size_t)(j + 12) * 1536];
    uint2 c0 = ps2h[j * 2], c1 = ps2h[(j + 4) * 2];
    uint2 c2 = ps2h[(j + 8) * 2], c3 = ps2h[(j + 12) * 2];
    acc2 = fmaf(__uint_as_float(c0.y) * v0, evh[c0.x * 64 + lane], acc2);
    acc2 = fmaf(__uint_as_float(c1.y) * v1, evh[c1.x * 64 + lane], acc2);
    acc2 = fmaf(__uint_as_float(c2.y) * v2, evh[c2.x * 64 + lane], acc2);
    acc2 = fmaf(__uint_as_float(c3.y) * v3, evh[c3.x * 64 + lane], acc2);
  }
  for (; j < n2; j += 4) {
    float v0 = (float)vb[(size_t)j * 1536];
    uint2 c0 = ps2h[j * 2];
    acc2 = fmaf(__uint_as_float(c0.y) * v0, evh[c0.x * 64 + lane], acc2);
  }
  red[0][wave * 64 + lane] = acc1;
  red[1][wave * 64 + lane] = acc2;
  __syncthreads();
  if (tid < 64) {
    float y =
        (red[0][tid] + red[0][64 + tid] + red[0][128 + tid] + red[0][192 + tid]) *
        inv1;
    ybuf[(size_t)i1 * CC + h * 64 + tid] = (bf16_t)y;
  } else if (tid < 128) {
    int t = tid - 64;
    float y =
        (red[1][t] + red[1][64 + t] + red[1][128 + t] + red[1][192 + t]) * inv2;
    ybuf[(size_t)i2 * CC + h * 64 + t] = (bf16_t)y;
  }
}

// ---------------------------------------------------------------------------
extern "C" void kernel_launch(void* const* d_in, const int* in_sizes, int n_in,
                              void* d_out, int out_size, void* d_ws,
                              size_t ws_size, hipStream_t stream) {
  const float* x = (const float*)d_in[0];
  const int* bias_mat = (const int*)d_in[1];

  char* wp = (char*)d_ws;
  float* ektab = (float*)wp;  wp += 16 * 512 * 4;
  float* evtab = (float*)wp;  wp += 16 * 512 * 4;
  float* s1f = (float*)wp;    wp += 2048 * 4;
  float* cf = (float*)wp;     wp += 2048 * 4;
  float* x1 = (float*)wp;     wp += 384 * 512 * 4;
  bf16_t* wfc_bf = (bf16_t*)wp;    wp += 2048 * 512 * 2;
  bf16_t* wproj_bf = (bf16_t*)wp;  wp += 512 * 512 * 2;
  bf16_t* wcproj_bf = (bf16_t*)wp; wp += 512 * 2048 * 2;
  bf16_t* qkv = (bf16_t*)wp;  wp += 384 * 1536 * 2;
  bf16_t* kT = (bf16_t*)wp;   wp += 8 * 64 * 384 * 2;  // [h][dg][j][8]
  bf16_t* ybuf = (bf16_t*)wp; wp += 384 * 512 * 2;
  bf16_t* gbuf = (bf16_t*)wp; wp += 384 * 2048 * 2;

  PrepX X;
  X.eemb = (const float*)d_in[9];
  X.wekw = (const float*)d_in[10];
  X.wekb = (const float*)d_in[11];
  X.wevw = (const float*)d_in[12];
  X.wevb = (const float*)d_in[13];
  X.ln2w = (const float*)d_in[14];
  X.ln2b = (const float*)d_in[15];
  X.cfcw = (const float*)d_in[16];
  X.cfcb = (const float*)d_in[17];
  X.wproj = (const float*)d_in[6];
  X.wcproj = (const float*)d_in[18];
  X.ektab = ektab; X.evtab = evtab; X.s1f = s1f; X.cf = cf;
  X.wfc_bf = wfc_bf; X.wproj_bf = wproj_bf; X.wcproj_bf = wcproj_bf;

  // 1) self-contained qkv (576 gemm tiles, rows 0-11; K tiles also fill kT)
  //    + 1088 hidden prep units (rows 12-34)
  qkv_k<<<dim3(48, 35), 256, 0, stream>>>(
      x, (const float*)d_in[4], (const float*)d_in[2], (const float*)d_in[3],
      (const float*)d_in[5], qkv, kT, X);
  // 2) attention (paired rows, 192x8, kT QK reads, 8/16-deep PV v-batching)
  attn_k<<<dim3(TT / 2, HH), 256, 0, stream>>>(qkv, kT, bias_mat,
                                               (const float*)d_in[8], ektab,
                                               evtab, ybuf);
  // 3) x1 = x + y @ wproj^T + b
  gemm_k<1><<<dim3(16, 12), 256, 0, stream>>>(
      ybuf, wproj_bf, (const float*)d_in[7], nullptr, x, x1, 512, 512);
  // 4) g = gelu(LN2(x1) @ cfc^T + b)  (row stats from own A reads)
  gemm_k<2><<<dim3(64, 12), 256, 0, stream>>>(x1, wfc_bf, s1f, cf, nullptr,
                                              gbuf, 2048, 512);
  // 5) out = x1 + g @ cproj^T + b
  gemm_k<3><<<dim3(16, 12), 256, 0, stream>>>(
      gbuf, wcproj_bf, (const float*)d_in[19], nullptr, x1, d_out, 512, 2048);
}